// Round 14
// baseline (3180.061 us; speedup 1.0000x reference)
//
#include <hip/hip_runtime.h>

typedef __attribute__((ext_vector_type(4))) float f32x4;
typedef __attribute__((ext_vector_type(8))) short short8;
typedef unsigned int u32;
typedef unsigned short u16;
typedef __attribute__((ext_vector_type(2))) u32 u32x2;
typedef __attribute__((ext_vector_type(4))) u32 u32x4;

#define DEV __device__ __forceinline__
#define SB0  __builtin_amdgcn_sched_barrier(0)
#define HBAR asm volatile("s_barrier" ::: "memory")

DEV u16 f2b(float f){
  u32 u = __builtin_bit_cast(u32, f);
  u32 r = u + 0x7fffu + ((u >> 16) & 1u);
  return (u16)(r >> 16);
}
DEV u32 pk2(float a, float b){ return (u32)f2b(a) | ((u32)f2b(b) << 16); }

DEV void gload16(const void* g, void* l){
  __builtin_amdgcn_global_load_lds((const __attribute__((address_space(1))) void*)g,
                                   (__attribute__((address_space(3))) void*)l, 16, 0, 0);
}
DEV u32 lds_addr(void* p){
  return (u32)(unsigned long long)(__attribute__((address_space(3))) char*)p;
}

// ---------------- consolidated fp32 -> bf16 conversion (segment per block.y) -
struct CvtSegs { const float* src[11]; u32 cum[12]; };

__global__ __launch_bounds__(256) void cvtall2_k(CvtSegs segs,
    u16* __restrict__ dst)
{
  const int s = blockIdx.y;                 // segment id: uniform per block
  const u32 lo = segs.cum[s], hi = segs.cum[s+1];
  const float* __restrict__ sp = segs.src[s];
  const u32 stride = gridDim.x * 256;
  for (u32 j = lo + blockIdx.x*256 + threadIdx.x; j < hi; j += stride){
    const float* p = sp + (size_t)(j - lo)*8;
    const float4 a = ((const float4*)p)[0];
    const float4 b = ((const float4*)p)[1];
    u32x4 r;
    r.x = pk2(a.x,a.y); r.y = pk2(a.z,a.w);
    r.z = pk2(b.x,b.y); r.w = pk2(b.z,b.w);
    ((u32x4*)dst)[j] = r;
  }
}

// ---------------- LayerNorm --------------------------------------------------
template<int OUT_F32>
__global__ __launch_bounds__(256) void ln_k(const float* __restrict__ x,
    const float* __restrict__ gam, const float* __restrict__ bet,
    void* __restrict__ out)
{
  const int row = blockIdx.x, tid = threadIdx.x;
  const float4 v = ((const float4*)(x + row*1024))[tid];
  float s = (v.x + v.y) + (v.z + v.w);
  float q = (v.x*v.x + v.y*v.y) + (v.z*v.z + v.w*v.w);
  #pragma unroll
  for (int m = 1; m < 64; m <<= 1){ s += __shfl_xor(s, m); q += __shfl_xor(q, m); }
  __shared__ float ps[4], pq[4];
  if ((tid & 63) == 0){ ps[tid>>6] = s; pq[tid>>6] = q; }
  __syncthreads();
  s = (ps[0]+ps[1]) + (ps[2]+ps[3]);
  q = (pq[0]+pq[1]) + (pq[2]+pq[3]);
  const float mean = s * (1.f/1024.f);
  const float var  = q * (1.f/1024.f) - mean*mean;
  const float rstd = rsqrtf(var + 1e-5f);
  const float4 gg = ((const float4*)gam)[tid];
  const float4 bb = ((const float4*)bet)[tid];
  const float o0 = (v.x-mean)*rstd*gg.x + bb.x;
  const float o1 = (v.y-mean)*rstd*gg.y + bb.y;
  const float o2 = (v.z-mean)*rstd*gg.z + bb.z;
  const float o3 = (v.w-mean)*rstd*gg.w + bb.w;
  if (OUT_F32){
    float4 r; r.x=o0; r.y=o1; r.z=o2; r.w=o3;
    ((float4*)out)[row*256 + tid] = r;
  } else {
    u32x2 r; r.x = pk2(o0,o1); r.y = pk2(o2,o3);
    ((u32x2*)out)[row*256 + tid] = r;
  }
}

// ---------------- GEMM 256x256 8-wave, 4-phase pipelined (fat shapes) --------
template<int DO_GELU>
__global__ __launch_bounds__(512,2) void gemm256_k(
    const u16* __restrict__ A, const u16* __restrict__ W,
    const float* __restrict__ bias, u16* __restrict__ Cout,
    int M, int N, int K)
{
  __shared__ char lds[131072];
  const int tid = threadIdx.x;
  const int lane = tid & 63, wid = tid >> 6;
  const int wr = wid >> 2, wc = wid & 3;
  const int g = lane >> 4, c16 = lane & 15;

  const u32 nwg = gridDim.x * gridDim.y;
  u32 flat = blockIdx.x + gridDim.x * blockIdx.y;
  {
    const u32 q = nwg >> 3, r = nwg & 7;
    const u32 xcd = flat & 7, idx = flat >> 3;
    flat = (xcd < r ? xcd*(q+1) : r*(q+1) + (xcd-r)*q) + idx;
  }
  const int m0 = (int)(flat % gridDim.x) * 256;
  const int n0 = (int)(flat / gridDim.x) * 256;

  f32x4 acc[8][4];
  #pragma unroll
  for (int m = 0; m < 8; m++)
    #pragma unroll
    for (int n = 0; n < 4; n++) acc[m][n] = (f32x4){0.f,0.f,0.f,0.f};

  const int srow = tid >> 3, schk = tid & 7;
  const int scg = schk ^ (srow & 7);
  const u16* aS = A + (size_t)(m0 + srow)*K + scg*8;
  const u16* wS = W + (size_t)(n0 + srow)*K + scg*8;

  auto SG = [&](const u16* base, int regionOff, int sb, int half, int i, int kk){
    gload16(base + (size_t)(half*128 + i*64)*K + kk,
            lds + sb*65536 + regionOff + half*16384 + i*8192 + tid*16);
  };
  short8 af[4][2], bf[4][2];
  auto LDA4 = [&](char* bufA, int mbase){
    #pragma unroll
    for (int i = 0; i < 4; i++){
      const int r = (mbase + i)*16 + c16;
      const int rx = r & 7;
      af[i][0] = *(const short8*)(bufA + r*128 + ((g ^ rx) << 4));
      af[i][1] = *(const short8*)(bufA + r*128 + (((4 + g) ^ rx) << 4));
    }
  };
  auto LDB2 = [&](char* bufB, int nbase){
    #pragma unroll
    for (int i = 0; i < 2; i++){
      const int r = (wc & 1)*64 + (nbase + i)*16 + c16;
      const int rx = r & 7;
      bf[nbase+i][0] = *(const short8*)(bufB + r*128 + ((g ^ rx) << 4));
      bf[nbase+i][1] = *(const short8*)(bufB + r*128 + (((4 + g) ^ rx) << 4));
    }
  };

  const int NT = K >> 6;
  SG(wS, 32768, 0, 0, 0, 0); SG(wS, 32768, 0, 0, 1, 0);
  SG(wS, 32768, 0, 1, 0, 0); SG(wS, 32768, 0, 1, 1, 0);
  SG(aS, 0,     0, 0, 0, 0); SG(aS, 0,     0, 0, 1, 0);
  SG(aS, 0,     0, 1, 0, 0); SG(aS, 0,     0, 1, 1, 0);
  asm volatile("s_waitcnt vmcnt(1)" ::: "memory");
  HBAR;

  for (int t = 0; t < NT; ++t){
    const int b = t & 1, sb = b ^ 1;
    const int skk = (t+1) << 6;
    const bool st = (t+1 < NT);
    char* bufA = lds + b*65536 + wr*16384;
    char* bufB = lds + b*65536 + 32768 + (wc >> 1)*16384;

    LDA4(bufA, 0); LDB2(bufB, 0);
    if (st){ SG(wS, 32768, sb, 0, 0, skk); SG(wS, 32768, sb, 0, 1, skk); }
    HBAR;
    asm volatile("s_waitcnt lgkmcnt(0)" ::: "memory"); SB0;
    __builtin_amdgcn_s_setprio(1);
    #pragma unroll
    for (int ks = 0; ks < 2; ks++)
      #pragma unroll
      for (int i = 0; i < 4; i++)
        #pragma unroll
        for (int j = 0; j < 2; j++)
          acc[i][j] = __builtin_amdgcn_mfma_f32_16x16x32_bf16(af[i][ks], bf[j][ks], acc[i][j], 0,0,0);
    __builtin_amdgcn_s_setprio(0);
    LDB2(bufB, 2);
    if (st){ SG(wS, 32768, sb, 1, 0, skk); SG(wS, 32768, sb, 1, 1, skk); }
    HBAR;
    asm volatile("s_waitcnt lgkmcnt(0)" ::: "memory"); SB0;
    __builtin_amdgcn_s_setprio(1);
    #pragma unroll
    for (int ks = 0; ks < 2; ks++)
      #pragma unroll
      for (int i = 0; i < 4; i++)
        #pragma unroll
        for (int j = 2; j < 4; j++)
          acc[i][j] = __builtin_amdgcn_mfma_f32_16x16x32_bf16(af[i][ks], bf[j][ks], acc[i][j], 0,0,0);
    __builtin_amdgcn_s_setprio(0);
    if (st) asm volatile("s_waitcnt vmcnt(4)" ::: "memory");
    else    asm volatile("s_waitcnt vmcnt(0)" ::: "memory");
    HBAR;
    LDA4(bufA, 4);
    if (st){ SG(aS, 0, sb, 0, 0, skk); SG(aS, 0, sb, 0, 1, skk); }
    asm volatile("s_waitcnt lgkmcnt(0)" ::: "memory"); SB0;
    __builtin_amdgcn_s_setprio(1);
    #pragma unroll
    for (int ks = 0; ks < 2; ks++)
      #pragma unroll
      for (int i = 0; i < 4; i++)
        #pragma unroll
        for (int j = 0; j < 2; j++)
          acc[4+i][j] = __builtin_amdgcn_mfma_f32_16x16x32_bf16(af[i][ks], bf[j][ks], acc[4+i][j], 0,0,0);
    __builtin_amdgcn_s_setprio(0);
    if (st){ SG(aS, 0, sb, 1, 0, skk); SG(aS, 0, sb, 1, 1, skk); }
    HBAR;
    __builtin_amdgcn_s_setprio(1);
    #pragma unroll
    for (int ks = 0; ks < 2; ks++)
      #pragma unroll
      for (int i = 0; i < 4; i++)
        #pragma unroll
        for (int j = 2; j < 4; j++)
          acc[4+i][j] = __builtin_amdgcn_mfma_f32_16x16x32_bf16(af[i][ks], bf[j][ks], acc[4+i][j], 0,0,0);
    __builtin_amdgcn_s_setprio(0);
    if (st) asm volatile("s_waitcnt vmcnt(1)" ::: "memory");
    HBAR;
  }

  #pragma unroll
  for (int n = 0; n < 4; n++){
    const int col = n0 + wc*64 + n*16 + c16;
    const float bv = bias[col];
    #pragma unroll
    for (int m = 0; m < 8; m++){
      const int rbase = m0 + wr*128 + m*16 + g*4;
      #pragma unroll
      for (int r = 0; r < 4; r++){
        float v = acc[m][n][r] + bv;
        if (DO_GELU) v = 0.5f*v*(1.f + erff(v*0.70710678118654752f));
        Cout[(size_t)(rbase + r)*N + col] = f2b(v);
      }
    }
  }
}

// ---------------- GEMM 128x128 8-wave, 2-phase pipelined (narrow-N) ----------
template<int DO_GELU, int DO_RES, int OUT_F32>
__global__ __launch_bounds__(512,2) void gemm128p_k(
    const u16* __restrict__ A, const u16* __restrict__ W,
    const float* __restrict__ bias, const float* __restrict__ res,
    void* __restrict__ Cout, int M, int N, int K)
{
  __shared__ char lds[65536];
  const int tid = threadIdx.x;
  const int lane = tid & 63, wid = tid >> 6;
  const int wr = wid >> 2, wc = wid & 3;
  const int g = lane >> 4, c16 = lane & 15;

  const u32 nwg = gridDim.x * gridDim.y;
  u32 flat = blockIdx.x + gridDim.x * blockIdx.y;
  {
    const u32 q = nwg >> 3, r = nwg & 7;
    const u32 xcd = flat & 7, idx = flat >> 3;
    flat = (xcd < r ? xcd*(q+1) : r*(q+1) + (xcd-r)*q) + idx;
  }
  const int n0 = (int)(flat % gridDim.x) * 128;   // N fastest
  const int m0 = (int)(flat / gridDim.x) * 128;

  f32x4 acc[4][2];
  #pragma unroll
  for (int m = 0; m < 4; m++)
    #pragma unroll
    for (int n = 0; n < 2; n++) acc[m][n] = (f32x4){0.f,0.f,0.f,0.f};

  const int srow = tid >> 3, schk = tid & 7;
  const int scg = schk ^ (srow & 7);
  const u16* aS = A + (size_t)(m0 + srow)*K + scg*8;
  const u16* wS = W + (size_t)(n0 + srow)*K + scg*8;

  auto SG = [&](const u16* base, int regionOff, int sb, int i, int kk){
    gload16(base + (size_t)(i*64)*K + kk,
            lds + sb*32768 + regionOff + i*8192 + tid*16);
  };
  short8 af[2][2], af2[2][2], bf[2][2];
  auto LDA = [&](short8 (*dst)[2], char* bufA, int mbase){
    #pragma unroll
    for (int i = 0; i < 2; i++){
      const int r = wr*64 + (mbase + i)*16 + c16;
      const int rx = r & 7;
      dst[i][0] = *(const short8*)(bufA + r*128 + ((g ^ rx) << 4));
      dst[i][1] = *(const short8*)(bufA + r*128 + (((4 + g) ^ rx) << 4));
    }
  };
  auto LDB = [&](char* bufB){
    #pragma unroll
    for (int i = 0; i < 2; i++){
      const int r = wc*32 + i*16 + c16;
      const int rx = r & 7;
      bf[i][0] = *(const short8*)(bufB + r*128 + ((g ^ rx) << 4));
      bf[i][1] = *(const short8*)(bufB + r*128 + (((4 + g) ^ rx) << 4));
    }
  };

  const int NT = K >> 6;
  SG(wS, 16384, 0, 0, 0); SG(wS, 16384, 0, 1, 0);
  SG(aS, 0,     0, 0, 0); SG(aS, 0,     0, 1, 0);

  for (int t = 0; t < NT; ++t){
    const int b = t & 1, sb = b ^ 1;
    const int skk = (t+1) << 6;
    const bool st = (t+1 < NT);
    char* bufA = lds + b*32768;
    char* bufB = lds + b*32768 + 16384;

    if (st){ SG(wS, 16384, sb, 0, skk); SG(wS, 16384, sb, 1, skk); }
    if (st) asm volatile("s_waitcnt vmcnt(2)" ::: "memory");
    else    asm volatile("s_waitcnt vmcnt(0)" ::: "memory");
    HBAR;
    LDA(af, bufA, 0); LDB(bufB);
    if (st){ SG(aS, 0, sb, 0, skk); SG(aS, 0, sb, 1, skk); }
    asm volatile("s_waitcnt lgkmcnt(0)" ::: "memory"); SB0;
    __builtin_amdgcn_s_setprio(1);
    #pragma unroll
    for (int ks = 0; ks < 2; ks++)
      #pragma unroll
      for (int i = 0; i < 2; i++)
        #pragma unroll
        for (int j = 0; j < 2; j++)
          acc[i][j] = __builtin_amdgcn_mfma_f32_16x16x32_bf16(af[i][ks], bf[j][ks], acc[i][j], 0,0,0);
    __builtin_amdgcn_s_setprio(0);
    LDA(af2, bufA, 2);
    asm volatile("s_waitcnt lgkmcnt(0)" ::: "memory"); SB0;
    __builtin_amdgcn_s_setprio(1);
    #pragma unroll
    for (int ks = 0; ks < 2; ks++)
      #pragma unroll
      for (int i = 0; i < 2; i++)
        #pragma unroll
        for (int j = 0; j < 2; j++)
          acc[2+i][j] = __builtin_amdgcn_mfma_f32_16x16x32_bf16(af2[i][ks], bf[j][ks], acc[2+i][j], 0,0,0);
    __builtin_amdgcn_s_setprio(0);
    HBAR;
  }

  #pragma unroll
  for (int n = 0; n < 2; n++){
    const int col = n0 + wc*32 + n*16 + c16;
    const float bv = bias[col];
    #pragma unroll
    for (int m = 0; m < 4; m++){
      const int rbase = m0 + wr*64 + m*16 + g*4;
      #pragma unroll
      for (int r = 0; r < 4; r++){
        float v = acc[m][n][r] + bv;
        if (DO_GELU) v = 0.5f*v*(1.f + erff(v*0.70710678118654752f));
        if (DO_RES)  v += res[(size_t)(rbase + r)*N + col];
        if (OUT_F32) ((float*)Cout)[(size_t)(rbase + r)*N + col] = v;
        else         ((u16*)Cout)[(size_t)(rbase + r)*N + col] = f2b(v);
      }
    }
  }
}

// ---------------- Flash attention, HD=64, KVBLK=64 ---------------------------
template<int CAUSAL>
__global__ __launch_bounds__(256,4) void attn_k(
    const u16* __restrict__ Qb, int qB, int qS,
    const u16* __restrict__ Kb, int kB, int kS,
    const u16* __restrict__ Vb, int vB, int vS,
    u16* __restrict__ Ob, int oB, int oS, float scale)
{
  __shared__ char smem[32768];   // K: [2][8192] @0, V: [2][8192] @16384
  const int tid = threadIdx.x;
  const int lane = tid & 63, w = tid >> 6;
  const int g = lane >> 4, c16 = lane & 15;
  const int qt = blockIdx.x, bh = blockIdx.y;
  const int b = bh >> 4, h = bh & 15;
  const u16* Q  = Qb + b*qB + h*64;
  const u16* Kp = Kb + b*kB + h*64;
  const u16* Vp = Vb + b*vB + h*64;
  u16*       Op = Ob + b*oB + h*64;

  const int qrow = qt*64 + w*16 + c16;
  const short8 bq0 = *(const short8*)(Q + qrow*qS + g*8);
  const short8 bq1 = *(const short8*)(Q + qrow*qS + 32 + g*8);

  f32x4 o[4];
  #pragma unroll
  for (int d = 0; d < 4; d++) o[d] = (f32x4){0.f,0.f,0.f,0.f};
  float mrun = -__builtin_inff(), lrun = 0.f;

  const int srow = tid >> 3, schk = tid & 7;
  const u16* kSrc = Kp + (size_t)srow*kS + (schk ^ (srow & 7))*8;
  const u16* vSrc = Vp + (size_t)srow*vS + schk*8;
  const u32 vtr0 = lds_addr(smem) + 16384 + (8*g + (c16 >> 2))*128 + (c16 & 3)*8;

  auto STAGE = [&](int p, int j0){
    char* kb = smem + p*8192 + w*1024;
    char* vb = smem + 16384 + p*8192 + w*1024;
    gload16(kSrc + (size_t)j0*kS, kb);
    gload16(kSrc + (size_t)(j0+32)*kS, kb + 4096);
    gload16(vSrc + (size_t)j0*vS, vb);
    gload16(vSrc + (size_t)(j0+32)*vS, vb + 4096);
  };
  auto COMPUTE = [&](int p, int j0){
    char* Ks = smem + p*8192;
    f32x4 st[4];
    #pragma unroll
    for (int t = 0; t < 4; t++){
      const int row = t*16 + c16;
      const int rx = row & 7;
      const short8 ka0 = *(const short8*)(Ks + row*128 + ((g ^ rx) << 4));
      const short8 ka1 = *(const short8*)(Ks + row*128 + (((4 + g) ^ rx) << 4));
      f32x4 z = (f32x4){0.f,0.f,0.f,0.f};
      z = __builtin_amdgcn_mfma_f32_16x16x32_bf16(ka0, bq0, z, 0,0,0);
      z = __builtin_amdgcn_mfma_f32_16x16x32_bf16(ka1, bq1, z, 0,0,0);
      st[t] = z;
    }
    float mloc = -__builtin_inff();
    #pragma unroll
    for (int t = 0; t < 4; t++)
      #pragma unroll
      for (int r = 0; r < 4; r++){
        float sv = st[t][r]*scale;
        if (CAUSAL){ if (j0 + t*16 + g*4 + r > qrow) sv = -__builtin_inff(); }
        st[t][r] = sv;
        mloc = fmaxf(mloc, sv);
      }
    mloc = fmaxf(mloc, __shfl_xor(mloc, 16));
    mloc = fmaxf(mloc, __shfl_xor(mloc, 32));
    const float mnew = fmaxf(mrun, mloc);
    const float corr = __expf(mrun - mnew);
    float psum = 0.f;
    u32 pk[4][2];
    #pragma unroll
    for (int t = 0; t < 4; t++){
      const float p0 = __expf(st[t][0]-mnew), p1 = __expf(st[t][1]-mnew);
      const float p2 = __expf(st[t][2]-mnew), p3 = __expf(st[t][3]-mnew);
      psum += (p0+p1) + (p2+p3);
      pk[t][0] = pk2(p0,p1); pk[t][1] = pk2(p2,p3);
    }
    psum += __shfl_xor(psum, 16);
    psum += __shfl_xor(psum, 32);
    lrun = lrun*corr + psum;
    mrun = mnew;
    #pragma unroll
    for (int d = 0; d < 4; d++){
      o[d][0]*=corr; o[d][1]*=corr; o[d][2]*=corr; o[d][3]*=corr;
    }
    const int sl0 = c16 | (((g << 1)     & 3) << 4);
    const int sl1 = c16 | ((((g << 1)+1) & 3) << 4);
    const bool hi = g >= 2;
    union { short8 s; u32 u[4]; } pb, pb2;
    {
      const u32 a00 = (u32)__shfl((int)pk[0][0], sl0), a01 = (u32)__shfl((int)pk[0][1], sl0);
      const u32 a02 = (u32)__shfl((int)pk[0][0], sl1), a03 = (u32)__shfl((int)pk[0][1], sl1);
      const u32 a10 = (u32)__shfl((int)pk[1][0], sl0), a11 = (u32)__shfl((int)pk[1][1], sl0);
      const u32 a12 = (u32)__shfl((int)pk[1][0], sl1), a13 = (u32)__shfl((int)pk[1][1], sl1);
      pb.u[0] = hi ? a10 : a00;
      pb.u[1] = hi ? a11 : a01;
      pb.u[2] = hi ? a12 : a02;
      pb.u[3] = hi ? a13 : a03;
    }
    {
      const u32 a00 = (u32)__shfl((int)pk[2][0], sl0), a01 = (u32)__shfl((int)pk[2][1], sl0);
      const u32 a02 = (u32)__shfl((int)pk[2][0], sl1), a03 = (u32)__shfl((int)pk[2][1], sl1);
      const u32 a10 = (u32)__shfl((int)pk[3][0], sl0), a11 = (u32)__shfl((int)pk[3][1], sl0);
      const u32 a12 = (u32)__shfl((int)pk[3][0], sl1), a13 = (u32)__shfl((int)pk[3][1], sl1);
      pb2.u[0] = hi ? a10 : a00;
      pb2.u[1] = hi ? a11 : a01;
      pb2.u[2] = hi ? a12 : a02;
      pb2.u[3] = hi ? a13 : a03;
    }

    const u32 vtr = vtr0 + p*8192;
    u32x2 t00,t01,t10,t11,t20,t21,t30,t31;
    asm volatile("ds_read_b64_tr_b16 %0, %1 offset:0"   : "=v"(t00) : "v"(vtr));
    asm volatile("ds_read_b64_tr_b16 %0, %1 offset:512" : "=v"(t01) : "v"(vtr));
    asm volatile("ds_read_b64_tr_b16 %0, %1 offset:32"  : "=v"(t10) : "v"(vtr));
    asm volatile("ds_read_b64_tr_b16 %0, %1 offset:544" : "=v"(t11) : "v"(vtr));
    asm volatile("ds_read_b64_tr_b16 %0, %1 offset:64"  : "=v"(t20) : "v"(vtr));
    asm volatile("ds_read_b64_tr_b16 %0, %1 offset:576" : "=v"(t21) : "v"(vtr));
    asm volatile("ds_read_b64_tr_b16 %0, %1 offset:96"  : "=v"(t30) : "v"(vtr));
    asm volatile("ds_read_b64_tr_b16 %0, %1 offset:608" : "=v"(t31) : "v"(vtr));
    asm volatile("s_waitcnt lgkmcnt(0)" ::: "memory");
    __builtin_amdgcn_sched_barrier(0);
    {
      union { short8 s; u32x2 d[2]; } v0u, v1u, v2u, v3u;
      v0u.d[0]=t00; v0u.d[1]=t01;
      v1u.d[0]=t10; v1u.d[1]=t11;
      v2u.d[0]=t20; v2u.d[1]=t21;
      v3u.d[0]=t30; v3u.d[1]=t31;
      o[0] = __builtin_amdgcn_mfma_f32_16x16x32_bf16(v0u.s, pb.s, o[0], 0,0,0);
      o[1] = __builtin_amdgcn_mfma_f32_16x16x32_bf16(v1u.s, pb.s, o[1], 0,0,0);
      o[2] = __builtin_amdgcn_mfma_f32_16x16x32_bf16(v2u.s, pb.s, o[2], 0,0,0);
      o[3] = __builtin_amdgcn_mfma_f32_16x16x32_bf16(v3u.s, pb.s, o[3], 0,0,0);
    }
    asm volatile("ds_read_b64_tr_b16 %0, %1 offset:4096" : "=v"(t00) : "v"(vtr));
    asm volatile("ds_read_b64_tr_b16 %0, %1 offset:4608" : "=v"(t01) : "v"(vtr));
    asm volatile("ds_read_b64_tr_b16 %0, %1 offset:4128" : "=v"(t10) : "v"(vtr));
    asm volatile("ds_read_b64_tr_b16 %0, %1 offset:4640" : "=v"(t11) : "v"(vtr));
    asm volatile("ds_read_b64_tr_b16 %0, %1 offset:4160" : "=v"(t20) : "v"(vtr));
    asm volatile("ds_read_b64_tr_b16 %0, %1 offset:4672" : "=v"(t21) : "v"(vtr));
    asm volatile("ds_read_b64_tr_b16 %0, %1 offset:4192" : "=v"(t30) : "v"(vtr));
    asm volatile("ds_read_b64_tr_b16 %0, %1 offset:4704" : "=v"(t31) : "v"(vtr));
    asm volatile("s_waitcnt lgkmcnt(0)" ::: "memory");
    __builtin_amdgcn_sched_barrier(0);
    {
      union { short8 s; u32x2 d[2]; } v0u, v1u, v2u, v3u;
      v0u.d[0]=t00; v0u.d[1]=t01;
      v1u.d[0]=t10; v1u.d[1]=t11;
      v2u.d[0]=t20; v2u.d[1]=t21;
      v3u.d[0]=t30; v3u.d[1]=t31;
      o[0] = __builtin_amdgcn_mfma_f32_16x16x32_bf16(v0u.s, pb2.s, o[0], 0,0,0);
      o[1] = __builtin_amdgcn_mfma_f32_16x16x32_bf16(v1u.s, pb2.s, o[1], 0,0,0);
      o[2] = __builtin_amdgcn_mfma_f32_16x16x32_bf16(v2u.s, pb2.s, o[2], 0,0,0);
      o[3] = __builtin_amdgcn_mfma_f32_16x16x32_bf16(v3u.s, pb2.s, o[3], 0,0,0);
    }
  };

  const int nCh = CAUSAL ? (qt + 1) : 8;
  STAGE(0, 0);
  for (int jc = 0; jc < nCh - 1; ++jc){
    STAGE((jc+1) & 1, (jc+1)*64);
    asm volatile("s_waitcnt vmcnt(4)" ::: "memory");
    HBAR; SB0;
    COMPUTE(jc & 1, jc*64);
    SB0; HBAR;
  }
  asm volatile("s_waitcnt vmcnt(0)" ::: "memory");
  HBAR; SB0;
  COMPUTE((nCh-1) & 1, (nCh-1)*64);
  SB0; HBAR;

  const float inv = 1.f / lrun;
  char* Olds = smem;
  #pragma unroll
  for (int dd = 0; dd < 4; dd++){
    u32x2 val;
    val.x = pk2(o[dd][0]*inv, o[dd][1]*inv);
    val.y = pk2(o[dd][2]*inv, o[dd][3]*inv);
    const int row = w*16 + c16;
    const int off = 32*dd + 8*g;
    const int chunk = off >> 4, rem = off & 15;
    *(u32x2*)(Olds + row*128 + ((chunk ^ (row & 7)) << 4) + rem) = val;
  }
  __syncthreads();
  const int orow = tid >> 2, oc = tid & 3;
  #pragma unroll
  for (int i = 0; i < 2; i++){
    const int ch = oc*2 + i;
    const u32x4 vv = *(const u32x4*)(Olds + orow*128 + ((ch ^ (orow & 7)) << 4));
    *(u32x4*)(Op + (qt*64 + orow)*oS + ch*8) = vv;
  }
}

// ----------------------------------------------------------------------------
extern "C" void kernel_launch(void* const* d_in, const int* in_sizes, int n_in,
                              void* d_out, int out_size, void* d_ws, size_t ws_size,
                              hipStream_t stream)
{
  (void)in_sizes; (void)n_in; (void)out_size; (void)ws_size;
  const float* src      = (const float*)d_in[0];
  const float* tgt      = (const float*)d_in[1];
  const float* e_qkv_w  = (const float*)d_in[2];
  const float* e_qkv_b  = (const float*)d_in[3];
  const float* e_out_w  = (const float*)d_in[4];
  const float* e_out_b  = (const float*)d_in[5];
  const float* e_ln1_g  = (const float*)d_in[6];
  const float* e_ln1_b  = (const float*)d_in[7];
  const float* e_fc1_w  = (const float*)d_in[8];
  const float* e_fc1_b  = (const float*)d_in[9];
  const float* e_fc2_w  = (const float*)d_in[10];
  const float* e_fc2_b  = (const float*)d_in[11];
  const float* e_ln2_g  = (const float*)d_in[12];
  const float* e_ln2_b  = (const float*)d_in[13];
  const float* e_nrm_g  = (const float*)d_in[14];
  const float* e_nrm_b  = (const float*)d_in[15];
  const float* dc_qkv_w = (const float*)d_in[16];
  const float* dc_qkv_b = (const float*)d_in[17];
  const float* dc_sout_w= (const float*)d_in[18];
  const float* dc_sout_b= (const float*)d_in[19];
  const float* dc_ln1_g = (const float*)d_in[20];
  const float* dc_ln1_b = (const float*)d_in[21];
  const float* dc_q_w   = (const float*)d_in[22];
  const float* dc_q_b   = (const float*)d_in[23];
  const float* dc_kv_w  = (const float*)d_in[24];
  const float* dc_kv_b  = (const float*)d_in[25];
  const float* dc_cout_w= (const float*)d_in[26];
  const float* dc_cout_b= (const float*)d_in[27];
  const float* dc_ln2_g = (const float*)d_in[28];
  const float* dc_ln2_b = (const float*)d_in[29];
  const float* dc_fc1_w = (const float*)d_in[30];
  const float* dc_fc1_b = (const float*)d_in[31];
  const float* dc_fc2_w = (const float*)d_in[32];
  const float* dc_fc2_b = (const float*)d_in[33];
  const float* dc_ln3_g = (const float*)d_in[34];
  const float* dc_ln3_b = (const float*)d_in[35];
  const float* dc_nrm_g = (const float*)d_in[36];
  const float* dc_nrm_b = (const float*)d_in[37];

  char* ws = (char*)d_ws;
  u16*  ln_out = (u16*)(ws);                    //  8 MB
  u16*  attn_o = (u16*)(ws + (8u<<20));         //  8 MB
  u16*  membuf = (u16*)(ws + (16u<<20));        //  8 MB
  float* xres  = (float*)(ws + (24u<<20));      // 16 MB
  u16*  region = (u16*)(ws + (40u<<20));        // 32 MB
  u16*  qkv   = region;
  u16*  hbuf  = region;
  u16*  qbuf  = region;
  u16*  wb    = (u16*)(ws + (72u<<20));         // 352 MB bf16 weights
  u16*  kvall = (u16*)(ws + (424ull<<20));      // 96 MB batched decoder KV

  const dim3 blk(256);
  const dim3 blk512(512);
  const int M = 4096;

  // ---------- upfront: convert ALL weights to bf16, segment-per-block.y ------
  CvtSegs segs;
  size_t woff = 0;
  u32 cum8 = 0;
  int nseg = 0;
  auto REG = [&](const float* srcp, size_t n)->u16* {
    u16* p = wb + woff;
    segs.src[nseg] = srcp;
    segs.cum[nseg] = cum8;
    nseg++;
    woff += n; cum8 += (u32)(n >> 3);
    return p;
  };
  u16* Weqkv = REG(e_qkv_w,  6ull*3072*1024);
  u16* Weout = REG(e_out_w,  6ull*1024*1024);
  u16* Wefc1 = REG(e_fc1_w,  6ull*4096*1024);
  u16* Wefc2 = REG(e_fc2_w,  6ull*4096*1024);
  u16* Wdqkv = REG(dc_qkv_w, 6ull*3072*1024);
  u16* Wdsout= REG(dc_sout_w,6ull*1024*1024);
  u16* Wdq   = REG(dc_q_w,   6ull*1024*1024);
  u16* Wdkv  = REG(dc_kv_w,  6ull*2048*1024);
  u16* Wdcout= REG(dc_cout_w,6ull*1024*1024);
  u16* Wdfc1 = REG(dc_fc1_w, 6ull*4096*1024);
  u16* Wdfc2 = REG(dc_fc2_w, 6ull*4096*1024);
  segs.cum[11] = cum8;
  cvtall2_k<<<dim3(192, 11), blk, 0, stream>>>(segs, wb);

  // ----------------- encoder -----------------
  for (int i = 0; i < 6; i++){
    const float* xin = i ? xres : src;
    ln_k<0><<<4096, blk, 0, stream>>>(xin, e_ln1_g + i*1024, e_ln1_b + i*1024, ln_out);
    gemm256_k<0><<<dim3(16, 12), blk512, 0, stream>>>(ln_out,
        Weqkv + (size_t)i*3145728, e_qkv_b + i*3072, qkv, M, 3072, 1024);
    attn_k<0><<<dim3(8,128), blk, 0, stream>>>(qkv, 3072, 24576,
        qkv+1024, 3072, 24576, qkv+2048, 3072, 24576, attn_o, 1024, 8192, 0.125f);
    gemm128p_k<0,1,1><<<dim3(8, 32), blk512, 0, stream>>>(attn_o,
        Weout + (size_t)i*1048576, e_out_b + i*1024, xin, xres, M, 1024, 1024);
    ln_k<0><<<4096, blk, 0, stream>>>(xres, e_ln2_g + i*1024, e_ln2_b + i*1024, ln_out);
    gemm256_k<1><<<dim3(16, 16), blk512, 0, stream>>>(ln_out,
        Wefc1 + (size_t)i*4194304, e_fc1_b + i*4096, hbuf, M, 4096, 1024);
    gemm128p_k<0,1,1><<<dim3(8, 32), blk512, 0, stream>>>(hbuf,
        Wefc2 + (size_t)i*4194304, e_fc2_b + i*1024, xres, xres, M, 1024, 4096);
  }
  ln_k<0><<<4096, blk, 0, stream>>>(xres, e_nrm_g, e_nrm_b, membuf);

  // batched decoder cross-attn KV: one GEMM over all 6 layers (N = 6*2048)
  gemm256_k<0><<<dim3(16, 48), blk512, 0, stream>>>(membuf,
      Wdkv, dc_kv_b, kvall, M, 12288, 1024);

  // ----------------- decoder -----------------
  for (int i = 0; i < 6; i++){
    const float* yin = i ? xres : tgt;
    ln_k<0><<<4096, blk, 0, stream>>>(yin, dc_ln1_g + i*1024, dc_ln1_b + i*1024, ln_out);
    gemm256_k<0><<<dim3(16, 12), blk512, 0, stream>>>(ln_out,
        Wdqkv + (size_t)i*3145728, dc_qkv_b + i*3072, qkv, M, 3072, 1024);
    attn_k<1><<<dim3(8,128), blk, 0, stream>>>(qkv, 3072, 24576,
        qkv+1024, 3072, 24576, qkv+2048, 3072, 24576, attn_o, 1024, 8192, 0.125f);
    gemm128p_k<0,1,1><<<dim3(8, 32), blk512, 0, stream>>>(attn_o,
        Wdsout + (size_t)i*1048576, dc_sout_b + i*1024, yin, xres, M, 1024, 1024);
    ln_k<0><<<4096, blk, 0, stream>>>(xres, dc_ln2_g + i*1024, dc_ln2_b + i*1024, ln_out);
    gemm128p_k<0,0,0><<<dim3(8, 32), blk512, 0, stream>>>(ln_out,
        Wdq + (size_t)i*1048576, dc_q_b + i*1024, nullptr, qbuf, M, 1024, 1024);
    attn_k<0><<<dim3(8,128), blk, 0, stream>>>(qbuf, 1024, 8192,
        kvall + i*2048, 12288, 98304, kvall + i*2048 + 1024, 12288, 98304,
        attn_o, 1024, 8192, 0.125f);
    gemm128p_k<0,1,1><<<dim3(8, 32), blk512, 0, stream>>>(attn_o,
        Wdcout + (size_t)i*1048576, dc_cout_b + i*1024, xres, xres, M, 1024, 1024);
    ln_k<0><<<4096, blk, 0, stream>>>(xres, dc_ln3_g + i*1024, dc_ln3_b + i*1024, ln_out);
    gemm256_k<1><<<dim3(16, 16), blk512, 0, stream>>>(ln_out,
        Wdfc1 + (size_t)i*4194304, dc_fc1_b + i*4096, hbuf, M, 4096, 1024);
    gemm128p_k<0,1,1><<<dim3(8, 32), blk512, 0, stream>>>(hbuf,
        Wdfc2 + (size_t)i*4194304, dc_fc2_b + i*1024, xres, xres, M, 1024, 4096);
  }
  ln_k<1><<<4096, blk, 0, stream>>>(xres, dc_nrm_g, dc_nrm_b, d_out);
}

// Round 15
// 3176.082 us; speedup vs baseline: 1.0013x; 1.0013x over previous
//
#include <hip/hip_runtime.h>

typedef __attribute__((ext_vector_type(4))) float f32x4;
typedef __attribute__((ext_vector_type(8))) short short8;
typedef unsigned int u32;
typedef unsigned short u16;
typedef __attribute__((ext_vector_type(2))) u32 u32x2;
typedef __attribute__((ext_vector_type(4))) u32 u32x4;

#define DEV __device__ __forceinline__
#define SB0  __builtin_amdgcn_sched_barrier(0)
#define HBAR asm volatile("s_barrier" ::: "memory")

DEV u16 f2b(float f){
  u32 u = __builtin_bit_cast(u32, f);
  u32 r = u + 0x7fffu + ((u >> 16) & 1u);
  return (u16)(r >> 16);
}
DEV u32 pk2(float a, float b){ return (u32)f2b(a) | ((u32)f2b(b) << 16); }

DEV void gload16(const void* g, void* l){
  __builtin_amdgcn_global_load_lds((const __attribute__((address_space(1))) void*)g,
                                   (__attribute__((address_space(3))) void*)l, 16, 0, 0);
}
DEV u32 lds_addr(void* p){
  return (u32)(unsigned long long)(__attribute__((address_space(3))) char*)p;
}

// ---------------- fp32 -> bf16 conversion (one launch per weight) ------------
__global__ __launch_bounds__(256) void cvt_k(const float* __restrict__ in,
                                             u16* __restrict__ out, int n8)
{
  int i = blockIdx.x*256 + threadIdx.x;
  const int stride = gridDim.x*256;
  for (; i < n8; i += stride){
    const float4 a = ((const float4*)in)[2*i];
    const float4 b = ((const float4*)in)[2*i+1];
    u32x4 r;
    r.x = pk2(a.x,a.y); r.y = pk2(a.z,a.w);
    r.z = pk2(b.x,b.y); r.w = pk2(b.z,b.w);
    ((u32x4*)out)[i] = r;
  }
}

// ---------------- LayerNorm --------------------------------------------------
template<int OUT_F32>
__global__ __launch_bounds__(256) void ln_k(const float* __restrict__ x,
    const float* __restrict__ gam, const float* __restrict__ bet,
    void* __restrict__ out)
{
  const int row = blockIdx.x, tid = threadIdx.x;
  const float4 v = ((const float4*)(x + row*1024))[tid];
  float s = (v.x + v.y) + (v.z + v.w);
  float q = (v.x*v.x + v.y*v.y) + (v.z*v.z + v.w*v.w);
  #pragma unroll
  for (int m = 1; m < 64; m <<= 1){ s += __shfl_xor(s, m); q += __shfl_xor(q, m); }
  __shared__ float ps[4], pq[4];
  if ((tid & 63) == 0){ ps[tid>>6] = s; pq[tid>>6] = q; }
  __syncthreads();
  s = (ps[0]+ps[1]) + (ps[2]+ps[3]);
  q = (pq[0]+pq[1]) + (pq[2]+pq[3]);
  const float mean = s * (1.f/1024.f);
  const float var  = q * (1.f/1024.f) - mean*mean;
  const float rstd = rsqrtf(var + 1e-5f);
  const float4 gg = ((const float4*)gam)[tid];
  const float4 bb = ((const float4*)bet)[tid];
  const float o0 = (v.x-mean)*rstd*gg.x + bb.x;
  const float o1 = (v.y-mean)*rstd*gg.y + bb.y;
  const float o2 = (v.z-mean)*rstd*gg.z + bb.z;
  const float o3 = (v.w-mean)*rstd*gg.w + bb.w;
  if (OUT_F32){
    float4 r; r.x=o0; r.y=o1; r.z=o2; r.w=o3;
    ((float4*)out)[row*256 + tid] = r;
  } else {
    u32x2 r; r.x = pk2(o0,o1); r.y = pk2(o2,o3);
    ((u32x2*)out)[row*256 + tid] = r;
  }
}

// ---------------- GEMM 256x256 8-wave, 4-phase pipelined (fat shapes) --------
template<int DO_GELU>
__global__ __launch_bounds__(512,2) void gemm256_k(
    const u16* __restrict__ A, const u16* __restrict__ W,
    const float* __restrict__ bias, u16* __restrict__ Cout,
    int M, int N, int K)
{
  __shared__ char lds[131072];
  const int tid = threadIdx.x;
  const int lane = tid & 63, wid = tid >> 6;
  const int wr = wid >> 2, wc = wid & 3;
  const int g = lane >> 4, c16 = lane & 15;

  const u32 nwg = gridDim.x * gridDim.y;
  u32 flat = blockIdx.x + gridDim.x * blockIdx.y;
  {
    const u32 q = nwg >> 3, r = nwg & 7;
    const u32 xcd = flat & 7, idx = flat >> 3;
    flat = (xcd < r ? xcd*(q+1) : r*(q+1) + (xcd-r)*q) + idx;
  }
  const int m0 = (int)(flat % gridDim.x) * 256;
  const int n0 = (int)(flat / gridDim.x) * 256;

  f32x4 acc[8][4];
  #pragma unroll
  for (int m = 0; m < 8; m++)
    #pragma unroll
    for (int n = 0; n < 4; n++) acc[m][n] = (f32x4){0.f,0.f,0.f,0.f};

  const int srow = tid >> 3, schk = tid & 7;
  const int scg = schk ^ (srow & 7);
  const u16* aS = A + (size_t)(m0 + srow)*K + scg*8;
  const u16* wS = W + (size_t)(n0 + srow)*K + scg*8;

  auto SG = [&](const u16* base, int regionOff, int sb, int half, int i, int kk){
    gload16(base + (size_t)(half*128 + i*64)*K + kk,
            lds + sb*65536 + regionOff + half*16384 + i*8192 + tid*16);
  };
  short8 af[4][2], bf[4][2];
  auto LDA4 = [&](char* bufA, int mbase){
    #pragma unroll
    for (int i = 0; i < 4; i++){
      const int r = (mbase + i)*16 + c16;
      const int rx = r & 7;
      af[i][0] = *(const short8*)(bufA + r*128 + ((g ^ rx) << 4));
      af[i][1] = *(const short8*)(bufA + r*128 + (((4 + g) ^ rx) << 4));
    }
  };
  auto LDB2 = [&](char* bufB, int nbase){
    #pragma unroll
    for (int i = 0; i < 2; i++){
      const int r = (wc & 1)*64 + (nbase + i)*16 + c16;
      const int rx = r & 7;
      bf[nbase+i][0] = *(const short8*)(bufB + r*128 + ((g ^ rx) << 4));
      bf[nbase+i][1] = *(const short8*)(bufB + r*128 + (((4 + g) ^ rx) << 4));
    }
  };

  const int NT = K >> 6;
  SG(wS, 32768, 0, 0, 0, 0); SG(wS, 32768, 0, 0, 1, 0);
  SG(wS, 32768, 0, 1, 0, 0); SG(wS, 32768, 0, 1, 1, 0);
  SG(aS, 0,     0, 0, 0, 0); SG(aS, 0,     0, 0, 1, 0);
  SG(aS, 0,     0, 1, 0, 0); SG(aS, 0,     0, 1, 1, 0);
  asm volatile("s_waitcnt vmcnt(1)" ::: "memory");
  HBAR;

  for (int t = 0; t < NT; ++t){
    const int b = t & 1, sb = b ^ 1;
    const int skk = (t+1) << 6;
    const bool st = (t+1 < NT);
    char* bufA = lds + b*65536 + wr*16384;
    char* bufB = lds + b*65536 + 32768 + (wc >> 1)*16384;

    LDA4(bufA, 0); LDB2(bufB, 0);
    if (st){ SG(wS, 32768, sb, 0, 0, skk); SG(wS, 32768, sb, 0, 1, skk); }
    HBAR;
    asm volatile("s_waitcnt lgkmcnt(0)" ::: "memory"); SB0;
    __builtin_amdgcn_s_setprio(1);
    #pragma unroll
    for (int ks = 0; ks < 2; ks++)
      #pragma unroll
      for (int i = 0; i < 4; i++)
        #pragma unroll
        for (int j = 0; j < 2; j++)
          acc[i][j] = __builtin_amdgcn_mfma_f32_16x16x32_bf16(af[i][ks], bf[j][ks], acc[i][j], 0,0,0);
    __builtin_amdgcn_s_setprio(0);
    LDB2(bufB, 2);
    if (st){ SG(wS, 32768, sb, 1, 0, skk); SG(wS, 32768, sb, 1, 1, skk); }
    HBAR;
    asm volatile("s_waitcnt lgkmcnt(0)" ::: "memory"); SB0;
    __builtin_amdgcn_s_setprio(1);
    #pragma unroll
    for (int ks = 0; ks < 2; ks++)
      #pragma unroll
      for (int i = 0; i < 4; i++)
        #pragma unroll
        for (int j = 2; j < 4; j++)
          acc[i][j] = __builtin_amdgcn_mfma_f32_16x16x32_bf16(af[i][ks], bf[j][ks], acc[i][j], 0,0,0);
    __builtin_amdgcn_s_setprio(0);
    if (st) asm volatile("s_waitcnt vmcnt(4)" ::: "memory");
    else    asm volatile("s_waitcnt vmcnt(0)" ::: "memory");
    HBAR;
    LDA4(bufA, 4);
    if (st){ SG(aS, 0, sb, 0, 0, skk); SG(aS, 0, sb, 0, 1, skk); }
    asm volatile("s_waitcnt lgkmcnt(0)" ::: "memory"); SB0;
    __builtin_amdgcn_s_setprio(1);
    #pragma unroll
    for (int ks = 0; ks < 2; ks++)
      #pragma unroll
      for (int i = 0; i < 4; i++)
        #pragma unroll
        for (int j = 0; j < 2; j++)
          acc[4+i][j] = __builtin_amdgcn_mfma_f32_16x16x32_bf16(af[i][ks], bf[j][ks], acc[4+i][j], 0,0,0);
    __builtin_amdgcn_s_setprio(0);
    if (st){ SG(aS, 0, sb, 1, 0, skk); SG(aS, 0, sb, 1, 1, skk); }
    HBAR;
    __builtin_amdgcn_s_setprio(1);
    #pragma unroll
    for (int ks = 0; ks < 2; ks++)
      #pragma unroll
      for (int i = 0; i < 4; i++)
        #pragma unroll
        for (int j = 2; j < 4; j++)
          acc[4+i][j] = __builtin_amdgcn_mfma_f32_16x16x32_bf16(af[i][ks], bf[j][ks], acc[4+i][j], 0,0,0);
    __builtin_amdgcn_s_setprio(0);
    if (st) asm volatile("s_waitcnt vmcnt(1)" ::: "memory");
    HBAR;
  }

  #pragma unroll
  for (int n = 0; n < 4; n++){
    const int col = n0 + wc*64 + n*16 + c16;
    const float bv = bias[col];
    #pragma unroll
    for (int m = 0; m < 8; m++){
      const int rbase = m0 + wr*128 + m*16 + g*4;
      #pragma unroll
      for (int r = 0; r < 4; r++){
        float v = acc[m][n][r] + bv;
        if (DO_GELU) v = 0.5f*v*(1.f + erff(v*0.70710678118654752f));
        Cout[(size_t)(rbase + r)*N + col] = f2b(v);
      }
    }
  }
}

// ---------------- GEMM 128x128 8-wave, 2-phase pipelined (narrow-N) ----------
template<int DO_GELU, int DO_RES, int OUT_F32>
__global__ __launch_bounds__(512,2) void gemm128p_k(
    const u16* __restrict__ A, const u16* __restrict__ W,
    const float* __restrict__ bias, const float* __restrict__ res,
    void* __restrict__ Cout, int M, int N, int K)
{
  __shared__ char lds[65536];
  const int tid = threadIdx.x;
  const int lane = tid & 63, wid = tid >> 6;
  const int wr = wid >> 2, wc = wid & 3;
  const int g = lane >> 4, c16 = lane & 15;

  const u32 nwg = gridDim.x * gridDim.y;
  u32 flat = blockIdx.x + gridDim.x * blockIdx.y;
  {
    const u32 q = nwg >> 3, r = nwg & 7;
    const u32 xcd = flat & 7, idx = flat >> 3;
    flat = (xcd < r ? xcd*(q+1) : r*(q+1) + (xcd-r)*q) + idx;
  }
  const int n0 = (int)(flat % gridDim.x) * 128;   // N fastest
  const int m0 = (int)(flat / gridDim.x) * 128;

  f32x4 acc[4][2];
  #pragma unroll
  for (int m = 0; m < 4; m++)
    #pragma unroll
    for (int n = 0; n < 2; n++) acc[m][n] = (f32x4){0.f,0.f,0.f,0.f};

  const int srow = tid >> 3, schk = tid & 7;
  const int scg = schk ^ (srow & 7);
  const u16* aS = A + (size_t)(m0 + srow)*K + scg*8;
  const u16* wS = W + (size_t)(n0 + srow)*K + scg*8;

  auto SG = [&](const u16* base, int regionOff, int sb, int i, int kk){
    gload16(base + (size_t)(i*64)*K + kk,
            lds + sb*32768 + regionOff + i*8192 + tid*16);
  };
  short8 af[2][2], af2[2][2], bf[2][2];
  auto LDA = [&](short8 (*dst)[2], char* bufA, int mbase){
    #pragma unroll
    for (int i = 0; i < 2; i++){
      const int r = wr*64 + (mbase + i)*16 + c16;
      const int rx = r & 7;
      dst[i][0] = *(const short8*)(bufA + r*128 + ((g ^ rx) << 4));
      dst[i][1] = *(const short8*)(bufA + r*128 + (((4 + g) ^ rx) << 4));
    }
  };
  auto LDB = [&](char* bufB){
    #pragma unroll
    for (int i = 0; i < 2; i++){
      const int r = wc*32 + i*16 + c16;
      const int rx = r & 7;
      bf[i][0] = *(const short8*)(bufB + r*128 + ((g ^ rx) << 4));
      bf[i][1] = *(const short8*)(bufB + r*128 + (((4 + g) ^ rx) << 4));
    }
  };

  const int NT = K >> 6;
  SG(wS, 16384, 0, 0, 0); SG(wS, 16384, 0, 1, 0);
  SG(aS, 0,     0, 0, 0); SG(aS, 0,     0, 1, 0);

  for (int t = 0; t < NT; ++t){
    const int b = t & 1, sb = b ^ 1;
    const int skk = (t+1) << 6;
    const bool st = (t+1 < NT);
    char* bufA = lds + b*32768;
    char* bufB = lds + b*32768 + 16384;

    if (st){ SG(wS, 16384, sb, 0, skk); SG(wS, 16384, sb, 1, skk); }
    if (st) asm volatile("s_waitcnt vmcnt(2)" ::: "memory");
    else    asm volatile("s_waitcnt vmcnt(0)" ::: "memory");
    HBAR;
    LDA(af, bufA, 0); LDB(bufB);
    if (st){ SG(aS, 0, sb, 0, skk); SG(aS, 0, sb, 1, skk); }
    asm volatile("s_waitcnt lgkmcnt(0)" ::: "memory"); SB0;
    __builtin_amdgcn_s_setprio(1);
    #pragma unroll
    for (int ks = 0; ks < 2; ks++)
      #pragma unroll
      for (int i = 0; i < 2; i++)
        #pragma unroll
        for (int j = 0; j < 2; j++)
          acc[i][j] = __builtin_amdgcn_mfma_f32_16x16x32_bf16(af[i][ks], bf[j][ks], acc[i][j], 0,0,0);
    __builtin_amdgcn_s_setprio(0);
    LDA(af2, bufA, 2);
    asm volatile("s_waitcnt lgkmcnt(0)" ::: "memory"); SB0;
    __builtin_amdgcn_s_setprio(1);
    #pragma unroll
    for (int ks = 0; ks < 2; ks++)
      #pragma unroll
      for (int i = 0; i < 2; i++)
        #pragma unroll
        for (int j = 0; j < 2; j++)
          acc[2+i][j] = __builtin_amdgcn_mfma_f32_16x16x32_bf16(af2[i][ks], bf[j][ks], acc[2+i][j], 0,0,0);
    __builtin_amdgcn_s_setprio(0);
    HBAR;
  }

  #pragma unroll
  for (int n = 0; n < 2; n++){
    const int col = n0 + wc*32 + n*16 + c16;
    const float bv = bias[col];
    #pragma unroll
    for (int m = 0; m < 4; m++){
      const int rbase = m0 + wr*64 + m*16 + g*4;
      #pragma unroll
      for (int r = 0; r < 4; r++){
        float v = acc[m][n][r] + bv;
        if (DO_GELU) v = 0.5f*v*(1.f + erff(v*0.70710678118654752f));
        if (DO_RES)  v += res[(size_t)(rbase + r)*N + col];
        if (OUT_F32) ((float*)Cout)[(size_t)(rbase + r)*N + col] = v;
        else         ((u16*)Cout)[(size_t)(rbase + r)*N + col] = f2b(v);
      }
    }
  }
}

// ---------------- Flash attention, HD=64, KVBLK=64 ---------------------------
template<int CAUSAL>
__global__ __launch_bounds__(256,4) void attn_k(
    const u16* __restrict__ Qb, int qB, int qS,
    const u16* __restrict__ Kb, int kB, int kS,
    const u16* __restrict__ Vb, int vB, int vS,
    u16* __restrict__ Ob, int oB, int oS, float scale)
{
  __shared__ char smem[32768];   // K: [2][8192] @0, V: [2][8192] @16384
  const int tid = threadIdx.x;
  const int lane = tid & 63, w = tid >> 6;
  const int g = lane >> 4, c16 = lane & 15;
  const int qt = blockIdx.x, bh = blockIdx.y;
  const int b = bh >> 4, h = bh & 15;
  const u16* Q  = Qb + b*qB + h*64;
  const u16* Kp = Kb + b*kB + h*64;
  const u16* Vp = Vb + b*vB + h*64;
  u16*       Op = Ob + b*oB + h*64;

  const int qrow = qt*64 + w*16 + c16;
  const short8 bq0 = *(const short8*)(Q + qrow*qS + g*8);
  const short8 bq1 = *(const short8*)(Q + qrow*qS + 32 + g*8);

  f32x4 o[4];
  #pragma unroll
  for (int d = 0; d < 4; d++) o[d] = (f32x4){0.f,0.f,0.f,0.f};
  float mrun = -__builtin_inff(), lrun = 0.f;

  const int srow = tid >> 3, schk = tid & 7;
  const u16* kSrc = Kp + (size_t)srow*kS + (schk ^ (srow & 7))*8;
  const u16* vSrc = Vp + (size_t)srow*vS + schk*8;
  const u32 vtr0 = lds_addr(smem) + 16384 + (8*g + (c16 >> 2))*128 + (c16 & 3)*8;

  auto STAGE = [&](int p, int j0){
    char* kb = smem + p*8192 + w*1024;
    char* vb = smem + 16384 + p*8192 + w*1024;
    gload16(kSrc + (size_t)j0*kS, kb);
    gload16(kSrc + (size_t)(j0+32)*kS, kb + 4096);
    gload16(vSrc + (size_t)j0*vS, vb);
    gload16(vSrc + (size_t)(j0+32)*vS, vb + 4096);
  };
  auto COMPUTE = [&](int p, int j0){
    char* Ks = smem + p*8192;
    f32x4 st[4];
    #pragma unroll
    for (int t = 0; t < 4; t++){
      const int row = t*16 + c16;
      const int rx = row & 7;
      const short8 ka0 = *(const short8*)(Ks + row*128 + ((g ^ rx) << 4));
      const short8 ka1 = *(const short8*)(Ks + row*128 + (((4 + g) ^ rx) << 4));
      f32x4 z = (f32x4){0.f,0.f,0.f,0.f};
      z = __builtin_amdgcn_mfma_f32_16x16x32_bf16(ka0, bq0, z, 0,0,0);
      z = __builtin_amdgcn_mfma_f32_16x16x32_bf16(ka1, bq1, z, 0,0,0);
      st[t] = z;
    }
    float mloc = -__builtin_inff();
    #pragma unroll
    for (int t = 0; t < 4; t++)
      #pragma unroll
      for (int r = 0; r < 4; r++){
        float sv = st[t][r]*scale;
        if (CAUSAL){ if (j0 + t*16 + g*4 + r > qrow) sv = -__builtin_inff(); }
        st[t][r] = sv;
        mloc = fmaxf(mloc, sv);
      }
    mloc = fmaxf(mloc, __shfl_xor(mloc, 16));
    mloc = fmaxf(mloc, __shfl_xor(mloc, 32));
    const float mnew = fmaxf(mrun, mloc);
    const float corr = __expf(mrun - mnew);
    float psum = 0.f;
    u32 pk[4][2];
    #pragma unroll
    for (int t = 0; t < 4; t++){
      const float p0 = __expf(st[t][0]-mnew), p1 = __expf(st[t][1]-mnew);
      const float p2 = __expf(st[t][2]-mnew), p3 = __expf(st[t][3]-mnew);
      psum += (p0+p1) + (p2+p3);
      pk[t][0] = pk2(p0,p1); pk[t][1] = pk2(p2,p3);
    }
    psum += __shfl_xor(psum, 16);
    psum += __shfl_xor(psum, 32);
    lrun = lrun*corr + psum;
    mrun = mnew;
    #pragma unroll
    for (int d = 0; d < 4; d++){
      o[d][0]*=corr; o[d][1]*=corr; o[d][2]*=corr; o[d][3]*=corr;
    }
    const int sl0 = c16 | (((g << 1)     & 3) << 4);
    const int sl1 = c16 | ((((g << 1)+1) & 3) << 4);
    const bool hi = g >= 2;
    union { short8 s; u32 u[4]; } pb, pb2;
    {
      const u32 a00 = (u32)__shfl((int)pk[0][0], sl0), a01 = (u32)__shfl((int)pk[0][1], sl0);
      const u32 a02 = (u32)__shfl((int)pk[0][0], sl1), a03 = (u32)__shfl((int)pk[0][1], sl1);
      const u32 a10 = (u32)__shfl((int)pk[1][0], sl0), a11 = (u32)__shfl((int)pk[1][1], sl0);
      const u32 a12 = (u32)__shfl((int)pk[1][0], sl1), a13 = (u32)__shfl((int)pk[1][1], sl1);
      pb.u[0] = hi ? a10 : a00;
      pb.u[1] = hi ? a11 : a01;
      pb.u[2] = hi ? a12 : a02;
      pb.u[3] = hi ? a13 : a03;
    }
    {
      const u32 a00 = (u32)__shfl((int)pk[2][0], sl0), a01 = (u32)__shfl((int)pk[2][1], sl0);
      const u32 a02 = (u32)__shfl((int)pk[2][0], sl1), a03 = (u32)__shfl((int)pk[2][1], sl1);
      const u32 a10 = (u32)__shfl((int)pk[3][0], sl0), a11 = (u32)__shfl((int)pk[3][1], sl0);
      const u32 a12 = (u32)__shfl((int)pk[3][0], sl1), a13 = (u32)__shfl((int)pk[3][1], sl1);
      pb2.u[0] = hi ? a10 : a00;
      pb2.u[1] = hi ? a11 : a01;
      pb2.u[2] = hi ? a12 : a02;
      pb2.u[3] = hi ? a13 : a03;
    }

    const u32 vtr = vtr0 + p*8192;
    u32x2 t00,t01,t10,t11,t20,t21,t30,t31;
    asm volatile("ds_read_b64_tr_b16 %0, %1 offset:0"   : "=v"(t00) : "v"(vtr));
    asm volatile("ds_read_b64_tr_b16 %0, %1 offset:512" : "=v"(t01) : "v"(vtr));
    asm volatile("ds_read_b64_tr_b16 %0, %1 offset:32"  : "=v"(t10) : "v"(vtr));
    asm volatile("ds_read_b64_tr_b16 %0, %1 offset:544" : "=v"(t11) : "v"(vtr));
    asm volatile("ds_read_b64_tr_b16 %0, %1 offset:64"  : "=v"(t20) : "v"(vtr));
    asm volatile("ds_read_b64_tr_b16 %0, %1 offset:576" : "=v"(t21) : "v"(vtr));
    asm volatile("ds_read_b64_tr_b16 %0, %1 offset:96"  : "=v"(t30) : "v"(vtr));
    asm volatile("ds_read_b64_tr_b16 %0, %1 offset:608" : "=v"(t31) : "v"(vtr));
    asm volatile("s_waitcnt lgkmcnt(0)" ::: "memory");
    __builtin_amdgcn_sched_barrier(0);
    {
      union { short8 s; u32x2 d[2]; } v0u, v1u, v2u, v3u;
      v0u.d[0]=t00; v0u.d[1]=t01;
      v1u.d[0]=t10; v1u.d[1]=t11;
      v2u.d[0]=t20; v2u.d[1]=t21;
      v3u.d[0]=t30; v3u.d[1]=t31;
      o[0] = __builtin_amdgcn_mfma_f32_16x16x32_bf16(v0u.s, pb.s, o[0], 0,0,0);
      o[1] = __builtin_amdgcn_mfma_f32_16x16x32_bf16(v1u.s, pb.s, o[1], 0,0,0);
      o[2] = __builtin_amdgcn_mfma_f32_16x16x32_bf16(v2u.s, pb.s, o[2], 0,0,0);
      o[3] = __builtin_amdgcn_mfma_f32_16x16x32_bf16(v3u.s, pb.s, o[3], 0,0,0);
    }
    asm volatile("ds_read_b64_tr_b16 %0, %1 offset:4096" : "=v"(t00) : "v"(vtr));
    asm volatile("ds_read_b64_tr_b16 %0, %1 offset:4608" : "=v"(t01) : "v"(vtr));
    asm volatile("ds_read_b64_tr_b16 %0, %1 offset:4128" : "=v"(t10) : "v"(vtr));
    asm volatile("ds_read_b64_tr_b16 %0, %1 offset:4640" : "=v"(t11) : "v"(vtr));
    asm volatile("ds_read_b64_tr_b16 %0, %1 offset:4160" : "=v"(t20) : "v"(vtr));
    asm volatile("ds_read_b64_tr_b16 %0, %1 offset:4672" : "=v"(t21) : "v"(vtr));
    asm volatile("ds_read_b64_tr_b16 %0, %1 offset:4192" : "=v"(t30) : "v"(vtr));
    asm volatile("ds_read_b64_tr_b16 %0, %1 offset:4704" : "=v"(t31) : "v"(vtr));
    asm volatile("s_waitcnt lgkmcnt(0)" ::: "memory");
    __builtin_amdgcn_sched_barrier(0);
    {
      union { short8 s; u32x2 d[2]; } v0u, v1u, v2u, v3u;
      v0u.d[0]=t00; v0u.d[1]=t01;
      v1u.d[0]=t10; v1u.d[1]=t11;
      v2u.d[0]=t20; v2u.d[1]=t21;
      v3u.d[0]=t30; v3u.d[1]=t31;
      o[0] = __builtin_amdgcn_mfma_f32_16x16x32_bf16(v0u.s, pb2.s, o[0], 0,0,0);
      o[1] = __builtin_amdgcn_mfma_f32_16x16x32_bf16(v1u.s, pb2.s, o[1], 0,0,0);
      o[2] = __builtin_amdgcn_mfma_f32_16x16x32_bf16(v2u.s, pb2.s, o[2], 0,0,0);
      o[3] = __builtin_amdgcn_mfma_f32_16x16x32_bf16(v3u.s, pb2.s, o[3], 0,0,0);
    }
  };

  const int nCh = CAUSAL ? (qt + 1) : 8;
  STAGE(0, 0);
  for (int jc = 0; jc < nCh - 1; ++jc){
    STAGE((jc+1) & 1, (jc+1)*64);
    asm volatile("s_waitcnt vmcnt(4)" ::: "memory");
    HBAR; SB0;
    COMPUTE(jc & 1, jc*64);
    SB0; HBAR;
  }
  asm volatile("s_waitcnt vmcnt(0)" ::: "memory");
  HBAR; SB0;
  COMPUTE((nCh-1) & 1, (nCh-1)*64);
  SB0; HBAR;

  const float inv = 1.f / lrun;
  char* Olds = smem;
  #pragma unroll
  for (int dd = 0; dd < 4; dd++){
    u32x2 val;
    val.x = pk2(o[dd][0]*inv, o[dd][1]*inv);
    val.y = pk2(o[dd][2]*inv, o[dd][3]*inv);
    const int row = w*16 + c16;
    const int off = 32*dd + 8*g;
    const int chunk = off >> 4, rem = off & 15;
    *(u32x2*)(Olds + row*128 + ((chunk ^ (row & 7)) << 4) + rem) = val;
  }
  __syncthreads();
  const int orow = tid >> 2, oc = tid & 3;
  #pragma unroll
  for (int i = 0; i < 2; i++){
    const int ch = oc*2 + i;
    const u32x4 vv = *(const u32x4*)(Olds + orow*128 + ((ch ^ (orow & 7)) << 4));
    *(u32x4*)(Op + (qt*64 + orow)*oS + ch*8) = vv;
  }
}

// ----------------------------------------------------------------------------
static inline int cvt_grid(int n8){ int g = (n8 + 255) / 256; return g > 2048 ? 2048 : g; }

extern "C" void kernel_launch(void* const* d_in, const int* in_sizes, int n_in,
                              void* d_out, int out_size, void* d_ws, size_t ws_size,
                              hipStream_t stream)
{
  (void)in_sizes; (void)n_in; (void)out_size; (void)ws_size;
  const float* src      = (const float*)d_in[0];
  const float* tgt      = (const float*)d_in[1];
  const float* e_qkv_w  = (const float*)d_in[2];
  const float* e_qkv_b  = (const float*)d_in[3];
  const float* e_out_w  = (const float*)d_in[4];
  const float* e_out_b  = (const float*)d_in[5];
  const float* e_ln1_g  = (const float*)d_in[6];
  const float* e_ln1_b  = (const float*)d_in[7];
  const float* e_fc1_w  = (const float*)d_in[8];
  const float* e_fc1_b  = (const float*)d_in[9];
  const float* e_fc2_w  = (const float*)d_in[10];
  const float* e_fc2_b  = (const float*)d_in[11];
  const float* e_ln2_g  = (const float*)d_in[12];
  const float* e_ln2_b  = (const float*)d_in[13];
  const float* e_nrm_g  = (const float*)d_in[14];
  const float* e_nrm_b  = (const float*)d_in[15];
  const float* dc_qkv_w = (const float*)d_in[16];
  const float* dc_qkv_b = (const float*)d_in[17];
  const float* dc_sout_w= (const float*)d_in[18];
  const float* dc_sout_b= (const float*)d_in[19];
  const float* dc_ln1_g = (const float*)d_in[20];
  const float* dc_ln1_b = (const float*)d_in[21];
  const float* dc_q_w   = (const float*)d_in[22];
  const float* dc_q_b   = (const float*)d_in[23];
  const float* dc_kv_w  = (const float*)d_in[24];
  const float* dc_kv_b  = (const float*)d_in[25];
  const float* dc_cout_w= (const float*)d_in[26];
  const float* dc_cout_b= (const float*)d_in[27];
  const float* dc_ln2_g = (const float*)d_in[28];
  const float* dc_ln2_b = (const float*)d_in[29];
  const float* dc_fc1_w = (const float*)d_in[30];
  const float* dc_fc1_b = (const float*)d_in[31];
  const float* dc_fc2_w = (const float*)d_in[32];
  const float* dc_fc2_b = (const float*)d_in[33];
  const float* dc_ln3_g = (const float*)d_in[34];
  const float* dc_ln3_b = (const float*)d_in[35];
  const float* dc_nrm_g = (const float*)d_in[36];
  const float* dc_nrm_b = (const float*)d_in[37];

  char* ws = (char*)d_ws;
  u16*  ln_out = (u16*)(ws);                    //  8 MB
  u16*  attn_o = (u16*)(ws + (8u<<20));         //  8 MB
  u16*  membuf = (u16*)(ws + (16u<<20));        //  8 MB
  float* xres  = (float*)(ws + (24u<<20));      // 16 MB
  u16*  region = (u16*)(ws + (40u<<20));        // 32 MB
  u16*  qkv   = region;
  u16*  hbuf  = region;
  u16*  qbuf  = region;
  u16*  wb    = (u16*)(ws + (72u<<20));         // 352 MB bf16 weights
  u16*  kvall = (u16*)(ws + (424ull<<20));      // 96 MB batched decoder KV

  const dim3 blk(256);
  const dim3 blk512(512);
  const int M = 4096;

  // ---------- upfront: convert ALL weights to bf16 (11 launches) ----------
  size_t woff = 0;
  auto CV = [&](const float* wsrc, size_t n)->u16* {
    u16* p = wb + woff; woff += n;
    cvt_k<<<cvt_grid((int)(n >> 3)), blk, 0, stream>>>(wsrc, p, (int)(n >> 3));
    return p;
  };
  u16* Weqkv = CV(e_qkv_w,  6ull*3072*1024);
  u16* Weout = CV(e_out_w,  6ull*1024*1024);
  u16* Wefc1 = CV(e_fc1_w,  6ull*4096*1024);
  u16* Wefc2 = CV(e_fc2_w,  6ull*4096*1024);
  u16* Wdqkv = CV(dc_qkv_w, 6ull*3072*1024);
  u16* Wdsout= CV(dc_sout_w,6ull*1024*1024);
  u16* Wdq   = CV(dc_q_w,   6ull*1024*1024);
  u16* Wdkv  = CV(dc_kv_w,  6ull*2048*1024);
  u16* Wdcout= CV(dc_cout_w,6ull*1024*1024);
  u16* Wdfc1 = CV(dc_fc1_w, 6ull*4096*1024);
  u16* Wdfc2 = CV(dc_fc2_w, 6ull*4096*1024);

  // ----------------- encoder -----------------
  for (int i = 0; i < 6; i++){
    const float* xin = i ? xres : src;
    ln_k<0><<<4096, blk, 0, stream>>>(xin, e_ln1_g + i*1024, e_ln1_b + i*1024, ln_out);
    gemm256_k<0><<<dim3(16, 12), blk512, 0, stream>>>(ln_out,
        Weqkv + (size_t)i*3145728, e_qkv_b + i*3072, qkv, M, 3072, 1024);
    attn_k<0><<<dim3(8,128), blk, 0, stream>>>(qkv, 3072, 24576,
        qkv+1024, 3072, 24576, qkv+2048, 3072, 24576, attn_o, 1024, 8192, 0.125f);
    gemm128p_k<0,1,1><<<dim3(8, 32), blk512, 0, stream>>>(attn_o,
        Weout + (size_t)i*1048576, e_out_b + i*1024, xin, xres, M, 1024, 1024);
    ln_k<0><<<4096, blk, 0, stream>>>(xres, e_ln2_g + i*1024, e_ln2_b + i*1024, ln_out);
    gemm256_k<1><<<dim3(16, 16), blk512, 0, stream>>>(ln_out,
        Wefc1 + (size_t)i*4194304, e_fc1_b + i*4096, hbuf, M, 4096, 1024);
    gemm128p_k<0,1,1><<<dim3(8, 32), blk512, 0, stream>>>(hbuf,
        Wefc2 + (size_t)i*4194304, e_fc2_b + i*1024, xres, xres, M, 1024, 4096);
  }
  ln_k<0><<<4096, blk, 0, stream>>>(xres, e_nrm_g, e_nrm_b, membuf);

  // batched decoder cross-attn KV: one GEMM over all 6 layers (N = 6*2048)
  gemm256_k<0><<<dim3(16, 48), blk512, 0, stream>>>(membuf,
      Wdkv, dc_kv_b, kvall, M, 12288, 1024);

  // ----------------- decoder -----------------
  for (int i = 0; i < 6; i++){
    const float* yin = i ? xres : tgt;
    ln_k<0><<<4096, blk, 0, stream>>>(yin, dc_ln1_g + i*1024, dc_ln1_b + i*1024, ln_out);
    gemm256_k<0><<<dim3(16, 12), blk512, 0, stream>>>(ln_out,
        Wdqkv + (size_t)i*3145728, dc_qkv_b + i*3072, qkv, M, 3072, 1024);
    attn_k<1><<<dim3(8,128), blk, 0, stream>>>(qkv, 3072, 24576,
        qkv+1024, 3072, 24576, qkv+2048, 3072, 24576, attn_o, 1024, 8192, 0.125f);
    gemm128p_k<0,1,1><<<dim3(8, 32), blk512, 0, stream>>>(attn_o,
        Wdsout + (size_t)i*1048576, dc_sout_b + i*1024, yin, xres, M, 1024, 1024);
    ln_k<0><<<4096, blk, 0, stream>>>(xres, dc_ln2_g + i*1024, dc_ln2_b + i*1024, ln_out);
    gemm128p_k<0,0,0><<<dim3(8, 32), blk512, 0, stream>>>(ln_out,
        Wdq + (size_t)i*1048576, dc_q_b + i*1024, nullptr, qbuf, M, 1024, 1024);
    attn_k<0><<<dim3(8,128), blk, 0, stream>>>(qbuf, 1024, 8192,
        kvall + i*2048, 12288, 98304, kvall + i*2048 + 1024, 12288, 98304,
        attn_o, 1024, 8192, 0.125f);
    gemm128p_k<0,1,1><<<dim3(8, 32), blk512, 0, stream>>>(attn_o,
        Wdcout + (size_t)i*1048576, dc_cout_b + i*1024, xres, xres, M, 1024, 1024);
    ln_k<0><<<4096, blk, 0, stream>>>(xres, dc_ln3_g + i*1024, dc_ln3_b + i*1024, ln_out);
    gemm256_k<1><<<dim3(16, 16), blk512, 0, stream>>>(ln_out,
        Wdfc1 + (size_t)i*4194304, dc_fc1_b + i*4096, hbuf, M, 4096, 1024);
    gemm128p_k<0,1,1><<<dim3(8, 32), blk512, 0, stream>>>(hbuf,
        Wdfc2 + (size_t)i*4194304, dc_fc2_b + i*1024, xres, xres, M, 1024, 4096);
  }
  ln_k<1><<<4096, blk, 0, stream>>>(xres, dc_nrm_g, dc_nrm_b, d_out);
}

// Round 16
// 3137.020 us; speedup vs baseline: 1.0137x; 1.0125x over previous
//
#include <hip/hip_runtime.h>

typedef __attribute__((ext_vector_type(4))) float f32x4;
typedef __attribute__((ext_vector_type(8))) short short8;
typedef unsigned int u32;
typedef unsigned short u16;
typedef __attribute__((ext_vector_type(2))) u32 u32x2;
typedef __attribute__((ext_vector_type(4))) u32 u32x4;

#define DEV __device__ __forceinline__
#define SB0  __builtin_amdgcn_sched_barrier(0)
#define HBAR asm volatile("s_barrier" ::: "memory")

DEV u16 f2b(float f){
  u32 u = __builtin_bit_cast(u32, f);
  u32 r = u + 0x7fffu + ((u >> 16) & 1u);
  return (u16)(r >> 16);
}
DEV u32 pk2(float a, float b){ return (u32)f2b(a) | ((u32)f2b(b) << 16); }

DEV void gload16(const void* g, void* l){
  __builtin_amdgcn_global_load_lds((const __attribute__((address_space(1))) void*)g,
                                   (__attribute__((address_space(3))) void*)l, 16, 0, 0);
}
DEV u32 lds_addr(void* p){
  return (u32)(unsigned long long)(__attribute__((address_space(3))) char*)p;
}

// ---------------- fp32 -> bf16 conversion (one launch per weight) ------------
__global__ __launch_bounds__(256) void cvt_k(const float* __restrict__ in,
                                             u16* __restrict__ out, int n8)
{
  int i = blockIdx.x*256 + threadIdx.x;
  const int stride = gridDim.x*256;
  for (; i < n8; i += stride){
    const float4 a = ((const float4*)in)[2*i];
    const float4 b = ((const float4*)in)[2*i+1];
    u32x4 r;
    r.x = pk2(a.x,a.y); r.y = pk2(a.z,a.w);
    r.z = pk2(b.x,b.y); r.w = pk2(b.z,b.w);
    ((u32x4*)out)[i] = r;
  }
}

// ---------------- LayerNorm --------------------------------------------------
template<int OUT_F32>
__global__ __launch_bounds__(256) void ln_k(const float* __restrict__ x,
    const float* __restrict__ gam, const float* __restrict__ bet,
    void* __restrict__ out)
{
  const int row = blockIdx.x, tid = threadIdx.x;
  const float4 v = ((const float4*)(x + row*1024))[tid];
  float s = (v.x + v.y) + (v.z + v.w);
  float q = (v.x*v.x + v.y*v.y) + (v.z*v.z + v.w*v.w);
  #pragma unroll
  for (int m = 1; m < 64; m <<= 1){ s += __shfl_xor(s, m); q += __shfl_xor(q, m); }
  __shared__ float ps[4], pq[4];
  if ((tid & 63) == 0){ ps[tid>>6] = s; pq[tid>>6] = q; }
  __syncthreads();
  s = (ps[0]+ps[1]) + (ps[2]+ps[3]);
  q = (pq[0]+pq[1]) + (pq[2]+pq[3]);
  const float mean = s * (1.f/1024.f);
  const float var  = q * (1.f/1024.f) - mean*mean;
  const float rstd = rsqrtf(var + 1e-5f);
  const float4 gg = ((const float4*)gam)[tid];
  const float4 bb = ((const float4*)bet)[tid];
  const float o0 = (v.x-mean)*rstd*gg.x + bb.x;
  const float o1 = (v.y-mean)*rstd*gg.y + bb.y;
  const float o2 = (v.z-mean)*rstd*gg.z + bb.z;
  const float o3 = (v.w-mean)*rstd*gg.w + bb.w;
  if (OUT_F32){
    float4 r; r.x=o0; r.y=o1; r.z=o2; r.w=o3;
    ((float4*)out)[row*256 + tid] = r;
  } else {
    u32x2 r; r.x = pk2(o0,o1); r.y = pk2(o2,o3);
    ((u32x2*)out)[row*256 + tid] = r;
  }
}

// ---------------- GEMM 256x256 8-wave, 4-phase pipelined (fat shapes) --------
// Epilogue: acc -> LDS (bf16 tile, chunk-XOR swizzle) -> fully coalesced
// 512B-row stores. Kills the 5x write-RMW amplification seen in counters.
template<int DO_GELU>
__global__ __launch_bounds__(512,2) void gemm256_k(
    const u16* __restrict__ A, const u16* __restrict__ W,
    const float* __restrict__ bias, u16* __restrict__ Cout,
    int M, int N, int K)
{
  __shared__ char lds[131072];
  const int tid = threadIdx.x;
  const int lane = tid & 63, wid = tid >> 6;
  const int wr = wid >> 2, wc = wid & 3;
  const int g = lane >> 4, c16 = lane & 15;

  const u32 nwg = gridDim.x * gridDim.y;
  u32 flat = blockIdx.x + gridDim.x * blockIdx.y;
  {
    const u32 q = nwg >> 3, r = nwg & 7;
    const u32 xcd = flat & 7, idx = flat >> 3;
    flat = (xcd < r ? xcd*(q+1) : r*(q+1) + (xcd-r)*q) + idx;
  }
  const int m0 = (int)(flat % gridDim.x) * 256;
  const int n0 = (int)(flat / gridDim.x) * 256;

  f32x4 acc[8][4];
  #pragma unroll
  for (int m = 0; m < 8; m++)
    #pragma unroll
    for (int n = 0; n < 4; n++) acc[m][n] = (f32x4){0.f,0.f,0.f,0.f};

  const int srow = tid >> 3, schk = tid & 7;
  const int scg = schk ^ (srow & 7);
  const u16* aS = A + (size_t)(m0 + srow)*K + scg*8;
  const u16* wS = W + (size_t)(n0 + srow)*K + scg*8;

  auto SG = [&](const u16* base, int regionOff, int sb, int half, int i, int kk){
    gload16(base + (size_t)(half*128 + i*64)*K + kk,
            lds + sb*65536 + regionOff + half*16384 + i*8192 + tid*16);
  };
  short8 af[4][2], bf[4][2];
  auto LDA4 = [&](char* bufA, int mbase){
    #pragma unroll
    for (int i = 0; i < 4; i++){
      const int r = (mbase + i)*16 + c16;
      const int rx = r & 7;
      af[i][0] = *(const short8*)(bufA + r*128 + ((g ^ rx) << 4));
      af[i][1] = *(const short8*)(bufA + r*128 + (((4 + g) ^ rx) << 4));
    }
  };
  auto LDB2 = [&](char* bufB, int nbase){
    #pragma unroll
    for (int i = 0; i < 2; i++){
      const int r = (wc & 1)*64 + (nbase + i)*16 + c16;
      const int rx = r & 7;
      bf[nbase+i][0] = *(const short8*)(bufB + r*128 + ((g ^ rx) << 4));
      bf[nbase+i][1] = *(const short8*)(bufB + r*128 + (((4 + g) ^ rx) << 4));
    }
  };

  const int NT = K >> 6;
  SG(wS, 32768, 0, 0, 0, 0); SG(wS, 32768, 0, 0, 1, 0);
  SG(wS, 32768, 0, 1, 0, 0); SG(wS, 32768, 0, 1, 1, 0);
  SG(aS, 0,     0, 0, 0, 0); SG(aS, 0,     0, 0, 1, 0);
  SG(aS, 0,     0, 1, 0, 0); SG(aS, 0,     0, 1, 1, 0);
  asm volatile("s_waitcnt vmcnt(1)" ::: "memory");
  HBAR;

  for (int t = 0; t < NT; ++t){
    const int b = t & 1, sb = b ^ 1;
    const int skk = (t+1) << 6;
    const bool st = (t+1 < NT);
    char* bufA = lds + b*65536 + wr*16384;
    char* bufB = lds + b*65536 + 32768 + (wc >> 1)*16384;

    LDA4(bufA, 0); LDB2(bufB, 0);
    if (st){ SG(wS, 32768, sb, 0, 0, skk); SG(wS, 32768, sb, 0, 1, skk); }
    HBAR;
    asm volatile("s_waitcnt lgkmcnt(0)" ::: "memory"); SB0;
    __builtin_amdgcn_s_setprio(1);
    #pragma unroll
    for (int ks = 0; ks < 2; ks++)
      #pragma unroll
      for (int i = 0; i < 4; i++)
        #pragma unroll
        for (int j = 0; j < 2; j++)
          acc[i][j] = __builtin_amdgcn_mfma_f32_16x16x32_bf16(af[i][ks], bf[j][ks], acc[i][j], 0,0,0);
    __builtin_amdgcn_s_setprio(0);
    LDB2(bufB, 2);
    if (st){ SG(wS, 32768, sb, 1, 0, skk); SG(wS, 32768, sb, 1, 1, skk); }
    HBAR;
    asm volatile("s_waitcnt lgkmcnt(0)" ::: "memory"); SB0;
    __builtin_amdgcn_s_setprio(1);
    #pragma unroll
    for (int ks = 0; ks < 2; ks++)
      #pragma unroll
      for (int i = 0; i < 4; i++)
        #pragma unroll
        for (int j = 2; j < 4; j++)
          acc[i][j] = __builtin_amdgcn_mfma_f32_16x16x32_bf16(af[i][ks], bf[j][ks], acc[i][j], 0,0,0);
    __builtin_amdgcn_s_setprio(0);
    if (st) asm volatile("s_waitcnt vmcnt(4)" ::: "memory");
    else    asm volatile("s_waitcnt vmcnt(0)" ::: "memory");
    HBAR;
    LDA4(bufA, 4);
    if (st){ SG(aS, 0, sb, 0, 0, skk); SG(aS, 0, sb, 0, 1, skk); }
    asm volatile("s_waitcnt lgkmcnt(0)" ::: "memory"); SB0;
    __builtin_amdgcn_s_setprio(1);
    #pragma unroll
    for (int ks = 0; ks < 2; ks++)
      #pragma unroll
      for (int i = 0; i < 4; i++)
        #pragma unroll
        for (int j = 0; j < 2; j++)
          acc[4+i][j] = __builtin_amdgcn_mfma_f32_16x16x32_bf16(af[i][ks], bf[j][ks], acc[4+i][j], 0,0,0);
    __builtin_amdgcn_s_setprio(0);
    if (st){ SG(aS, 0, sb, 1, 0, skk); SG(aS, 0, sb, 1, 1, skk); }
    HBAR;
    __builtin_amdgcn_s_setprio(1);
    #pragma unroll
    for (int ks = 0; ks < 2; ks++)
      #pragma unroll
      for (int i = 0; i < 4; i++)
        #pragma unroll
        for (int j = 2; j < 4; j++)
          acc[4+i][j] = __builtin_amdgcn_mfma_f32_16x16x32_bf16(af[i][ks], bf[j][ks], acc[4+i][j], 0,0,0);
    __builtin_amdgcn_s_setprio(0);
    if (st) asm volatile("s_waitcnt vmcnt(1)" ::: "memory");
    HBAR;
  }
  // after final HBAR all waves are done with K-loop LDS reads; LDS is free.

  // ---- epilogue phase 1: acc (+bias,+GELU) -> LDS bf16 tile [256][512B],
  //      16B-chunk XOR swizzle by (row&31) to spread banks -----------------
  #pragma unroll
  for (int n = 0; n < 4; n++){
    const int col = wc*64 + n*16 + c16;          // tile-local col 0..255
    const float bv = bias[n0 + col];
    #pragma unroll
    for (int m = 0; m < 8; m++){
      const int rbase = wr*128 + m*16 + g*4;     // tile-local row
      #pragma unroll
      for (int r = 0; r < 4; r++){
        float v = acc[m][n][r] + bv;
        if (DO_GELU) v = 0.5f*v*(1.f + erff(v*0.70710678118654752f));
        const int row = rbase + r;
        const int byte = col*2;
        const int ch = byte >> 4, rem = byte & 15;
        *(u16*)(lds + row*512 + ((ch ^ (row & 31)) << 4) + rem) = f2b(v);
      }
    }
  }
  HBAR;
  // ---- epilogue phase 2: coalesced sweep, 512B per row, dwordx4 stores ----
  #pragma unroll
  for (int it = 0; it < 16; ++it){
    const int idx = it*512 + tid;                // 8192 x 16B chunks
    const int row = idx >> 5;
    const int ch  = idx & 31;
    const u32x4 v = *(const u32x4*)(lds + row*512 + ((ch ^ (row & 31)) << 4));
    *(u32x4*)(Cout + (size_t)(m0 + row)*N + n0 + ch*8) = v;
  }
}

// ---------------- GEMM 128x128 8-wave, 2-phase pipelined (narrow-N) ----------
template<int DO_GELU, int DO_RES, int OUT_F32>
__global__ __launch_bounds__(512,2) void gemm128p_k(
    const u16* __restrict__ A, const u16* __restrict__ W,
    const float* __restrict__ bias, const float* __restrict__ res,
    void* __restrict__ Cout, int M, int N, int K)
{
  __shared__ char lds[65536];
  const int tid = threadIdx.x;
  const int lane = tid & 63, wid = tid >> 6;
  const int wr = wid >> 2, wc = wid & 3;
  const int g = lane >> 4, c16 = lane & 15;

  const u32 nwg = gridDim.x * gridDim.y;
  u32 flat = blockIdx.x + gridDim.x * blockIdx.y;
  {
    const u32 q = nwg >> 3, r = nwg & 7;
    const u32 xcd = flat & 7, idx = flat >> 3;
    flat = (xcd < r ? xcd*(q+1) : r*(q+1) + (xcd-r)*q) + idx;
  }
  const int n0 = (int)(flat % gridDim.x) * 128;   // N fastest
  const int m0 = (int)(flat / gridDim.x) * 128;

  f32x4 acc[4][2];
  #pragma unroll
  for (int m = 0; m < 4; m++)
    #pragma unroll
    for (int n = 0; n < 2; n++) acc[m][n] = (f32x4){0.f,0.f,0.f,0.f};

  const int srow = tid >> 3, schk = tid & 7;
  const int scg = schk ^ (srow & 7);
  const u16* aS = A + (size_t)(m0 + srow)*K + scg*8;
  const u16* wS = W + (size_t)(n0 + srow)*K + scg*8;

  auto SG = [&](const u16* base, int regionOff, int sb, int i, int kk){
    gload16(base + (size_t)(i*64)*K + kk,
            lds + sb*32768 + regionOff + i*8192 + tid*16);
  };
  short8 af[2][2], af2[2][2], bf[2][2];
  auto LDA = [&](short8 (*dst)[2], char* bufA, int mbase){
    #pragma unroll
    for (int i = 0; i < 2; i++){
      const int r = wr*64 + (mbase + i)*16 + c16;
      const int rx = r & 7;
      dst[i][0] = *(const short8*)(bufA + r*128 + ((g ^ rx) << 4));
      dst[i][1] = *(const short8*)(bufA + r*128 + (((4 + g) ^ rx) << 4));
    }
  };
  auto LDB = [&](char* bufB){
    #pragma unroll
    for (int i = 0; i < 2; i++){
      const int r = wc*32 + i*16 + c16;
      const int rx = r & 7;
      bf[i][0] = *(const short8*)(bufB + r*128 + ((g ^ rx) << 4));
      bf[i][1] = *(const short8*)(bufB + r*128 + (((4 + g) ^ rx) << 4));
    }
  };

  const int NT = K >> 6;
  SG(wS, 16384, 0, 0, 0); SG(wS, 16384, 0, 1, 0);
  SG(aS, 0,     0, 0, 0); SG(aS, 0,     0, 1, 0);

  for (int t = 0; t < NT; ++t){
    const int b = t & 1, sb = b ^ 1;
    const int skk = (t+1) << 6;
    const bool st = (t+1 < NT);
    char* bufA = lds + b*32768;
    char* bufB = lds + b*32768 + 16384;

    if (st){ SG(wS, 16384, sb, 0, skk); SG(wS, 16384, sb, 1, skk); }
    if (st) asm volatile("s_waitcnt vmcnt(2)" ::: "memory");
    else    asm volatile("s_waitcnt vmcnt(0)" ::: "memory");
    HBAR;
    LDA(af, bufA, 0); LDB(bufB);
    if (st){ SG(aS, 0, sb, 0, skk); SG(aS, 0, sb, 1, skk); }
    asm volatile("s_waitcnt lgkmcnt(0)" ::: "memory"); SB0;
    __builtin_amdgcn_s_setprio(1);
    #pragma unroll
    for (int ks = 0; ks < 2; ks++)
      #pragma unroll
      for (int i = 0; i < 2; i++)
        #pragma unroll
        for (int j = 0; j < 2; j++)
          acc[i][j] = __builtin_amdgcn_mfma_f32_16x16x32_bf16(af[i][ks], bf[j][ks], acc[i][j], 0,0,0);
    __builtin_amdgcn_s_setprio(0);
    LDA(af2, bufA, 2);
    asm volatile("s_waitcnt lgkmcnt(0)" ::: "memory"); SB0;
    __builtin_amdgcn_s_setprio(1);
    #pragma unroll
    for (int ks = 0; ks < 2; ks++)
      #pragma unroll
      for (int i = 0; i < 2; i++)
        #pragma unroll
        for (int j = 0; j < 2; j++)
          acc[2+i][j] = __builtin_amdgcn_mfma_f32_16x16x32_bf16(af2[i][ks], bf[j][ks], acc[2+i][j], 0,0,0);
    __builtin_amdgcn_s_setprio(0);
    HBAR;
  }

  #pragma unroll
  for (int n = 0; n < 2; n++){
    const int col = n0 + wc*32 + n*16 + c16;
    const float bv = bias[col];
    #pragma unroll
    for (int m = 0; m < 4; m++){
      const int rbase = m0 + wr*64 + m*16 + g*4;
      #pragma unroll
      for (int r = 0; r < 4; r++){
        float v = acc[m][n][r] + bv;
        if (DO_GELU) v = 0.5f*v*(1.f + erff(v*0.70710678118654752f));
        if (DO_RES)  v += res[(size_t)(rbase + r)*N + col];
        if (OUT_F32) ((float*)Cout)[(size_t)(rbase + r)*N + col] = v;
        else         ((u16*)Cout)[(size_t)(rbase + r)*N + col] = f2b(v);
      }
    }
  }
}

// ---------------- Flash attention, HD=64, KVBLK=64 ---------------------------
template<int CAUSAL>
__global__ __launch_bounds__(256,4) void attn_k(
    const u16* __restrict__ Qb, int qB, int qS,
    const u16* __restrict__ Kb, int kB, int kS,
    const u16* __restrict__ Vb, int vB, int vS,
    u16* __restrict__ Ob, int oB, int oS, float scale)
{
  __shared__ char smem[32768];   // K: [2][8192] @0, V: [2][8192] @16384
  const int tid = threadIdx.x;
  const int lane = tid & 63, w = tid >> 6;
  const int g = lane >> 4, c16 = lane & 15;
  const int qt = blockIdx.x, bh = blockIdx.y;
  const int b = bh >> 4, h = bh & 15;
  const u16* Q  = Qb + b*qB + h*64;
  const u16* Kp = Kb + b*kB + h*64;
  const u16* Vp = Vb + b*vB + h*64;
  u16*       Op = Ob + b*oB + h*64;

  const int qrow = qt*64 + w*16 + c16;
  const short8 bq0 = *(const short8*)(Q + qrow*qS + g*8);
  const short8 bq1 = *(const short8*)(Q + qrow*qS + 32 + g*8);

  f32x4 o[4];
  #pragma unroll
  for (int d = 0; d < 4; d++) o[d] = (f32x4){0.f,0.f,0.f,0.f};
  float mrun = -__builtin_inff(), lrun = 0.f;

  const int srow = tid >> 3, schk = tid & 7;
  const u16* kSrc = Kp + (size_t)srow*kS + (schk ^ (srow & 7))*8;
  const u16* vSrc = Vp + (size_t)srow*vS + schk*8;
  const u32 vtr0 = lds_addr(smem) + 16384 + (8*g + (c16 >> 2))*128 + (c16 & 3)*8;

  auto STAGE = [&](int p, int j0){
    char* kb = smem + p*8192 + w*1024;
    char* vb = smem + 16384 + p*8192 + w*1024;
    gload16(kSrc + (size_t)j0*kS, kb);
    gload16(kSrc + (size_t)(j0+32)*kS, kb + 4096);
    gload16(vSrc + (size_t)j0*vS, vb);
    gload16(vSrc + (size_t)(j0+32)*vS, vb + 4096);
  };
  auto COMPUTE = [&](int p, int j0){
    char* Ks = smem + p*8192;
    f32x4 st[4];
    #pragma unroll
    for (int t = 0; t < 4; t++){
      const int row = t*16 + c16;
      const int rx = row & 7;
      const short8 ka0 = *(const short8*)(Ks + row*128 + ((g ^ rx) << 4));
      const short8 ka1 = *(const short8*)(Ks + row*128 + (((4 + g) ^ rx) << 4));
      f32x4 z = (f32x4){0.f,0.f,0.f,0.f};
      z = __builtin_amdgcn_mfma_f32_16x16x32_bf16(ka0, bq0, z, 0,0,0);
      z = __builtin_amdgcn_mfma_f32_16x16x32_bf16(ka1, bq1, z, 0,0,0);
      st[t] = z;
    }
    float mloc = -__builtin_inff();
    #pragma unroll
    for (int t = 0; t < 4; t++)
      #pragma unroll
      for (int r = 0; r < 4; r++){
        float sv = st[t][r]*scale;
        if (CAUSAL){ if (j0 + t*16 + g*4 + r > qrow) sv = -__builtin_inff(); }
        st[t][r] = sv;
        mloc = fmaxf(mloc, sv);
      }
    mloc = fmaxf(mloc, __shfl_xor(mloc, 16));
    mloc = fmaxf(mloc, __shfl_xor(mloc, 32));
    const float mnew = fmaxf(mrun, mloc);
    const float corr = __expf(mrun - mnew);
    float psum = 0.f;
    u32 pk[4][2];
    #pragma unroll
    for (int t = 0; t < 4; t++){
      const float p0 = __expf(st[t][0]-mnew), p1 = __expf(st[t][1]-mnew);
      const float p2 = __expf(st[t][2]-mnew), p3 = __expf(st[t][3]-mnew);
      psum += (p0+p1) + (p2+p3);
      pk[t][0] = pk2(p0,p1); pk[t][1] = pk2(p2,p3);
    }
    psum += __shfl_xor(psum, 16);
    psum += __shfl_xor(psum, 32);
    lrun = lrun*corr + psum;
    mrun = mnew;
    #pragma unroll
    for (int d = 0; d < 4; d++){
      o[d][0]*=corr; o[d][1]*=corr; o[d][2]*=corr; o[d][3]*=corr;
    }
    const int sl0 = c16 | (((g << 1)     & 3) << 4);
    const int sl1 = c16 | ((((g << 1)+1) & 3) << 4);
    const bool hi = g >= 2;
    union { short8 s; u32 u[4]; } pb, pb2;
    {
      const u32 a00 = (u32)__shfl((int)pk[0][0], sl0), a01 = (u32)__shfl((int)pk[0][1], sl0);
      const u32 a02 = (u32)__shfl((int)pk[0][0], sl1), a03 = (u32)__shfl((int)pk[0][1], sl1);
      const u32 a10 = (u32)__shfl((int)pk[1][0], sl0), a11 = (u32)__shfl((int)pk[1][1], sl0);
      const u32 a12 = (u32)__shfl((int)pk[1][0], sl1), a13 = (u32)__shfl((int)pk[1][1], sl1);
      pb.u[0] = hi ? a10 : a00;
      pb.u[1] = hi ? a11 : a01;
      pb.u[2] = hi ? a12 : a02;
      pb.u[3] = hi ? a13 : a03;
    }
    {
      const u32 a00 = (u32)__shfl((int)pk[2][0], sl0), a01 = (u32)__shfl((int)pk[2][1], sl0);
      const u32 a02 = (u32)__shfl((int)pk[2][0], sl1), a03 = (u32)__shfl((int)pk[2][1], sl1);
      const u32 a10 = (u32)__shfl((int)pk[3][0], sl0), a11 = (u32)__shfl((int)pk[3][1], sl0);
      const u32 a12 = (u32)__shfl((int)pk[3][0], sl1), a13 = (u32)__shfl((int)pk[3][1], sl1);
      pb2.u[0] = hi ? a10 : a00;
      pb2.u[1] = hi ? a11 : a01;
      pb2.u[2] = hi ? a12 : a02;
      pb2.u[3] = hi ? a13 : a03;
    }

    const u32 vtr = vtr0 + p*8192;
    u32x2 t00,t01,t10,t11,t20,t21,t30,t31;
    asm volatile("ds_read_b64_tr_b16 %0, %1 offset:0"   : "=v"(t00) : "v"(vtr));
    asm volatile("ds_read_b64_tr_b16 %0, %1 offset:512" : "=v"(t01) : "v"(vtr));
    asm volatile("ds_read_b64_tr_b16 %0, %1 offset:32"  : "=v"(t10) : "v"(vtr));
    asm volatile("ds_read_b64_tr_b16 %0, %1 offset:544" : "=v"(t11) : "v"(vtr));
    asm volatile("ds_read_b64_tr_b16 %0, %1 offset:64"  : "=v"(t20) : "v"(vtr));
    asm volatile("ds_read_b64_tr_b16 %0, %1 offset:576" : "=v"(t21) : "v"(vtr));
    asm volatile("ds_read_b64_tr_b16 %0, %1 offset:96"  : "=v"(t30) : "v"(vtr));
    asm volatile("ds_read_b64_tr_b16 %0, %1 offset:608" : "=v"(t31) : "v"(vtr));
    asm volatile("s_waitcnt lgkmcnt(0)" ::: "memory");
    __builtin_amdgcn_sched_barrier(0);
    {
      union { short8 s; u32x2 d[2]; } v0u, v1u, v2u, v3u;
      v0u.d[0]=t00; v0u.d[1]=t01;
      v1u.d[0]=t10; v1u.d[1]=t11;
      v2u.d[0]=t20; v2u.d[1]=t21;
      v3u.d[0]=t30; v3u.d[1]=t31;
      o[0] = __builtin_amdgcn_mfma_f32_16x16x32_bf16(v0u.s, pb.s, o[0], 0,0,0);
      o[1] = __builtin_amdgcn_mfma_f32_16x16x32_bf16(v1u.s, pb.s, o[1], 0,0,0);
      o[2] = __builtin_amdgcn_mfma_f32_16x16x32_bf16(v2u.s, pb.s, o[2], 0,0,0);
      o[3] = __builtin_amdgcn_mfma_f32_16x16x32_bf16(v3u.s, pb.s, o[3], 0,0,0);
    }
    asm volatile("ds_read_b64_tr_b16 %0, %1 offset:4096" : "=v"(t00) : "v"(vtr));
    asm volatile("ds_read_b64_tr_b16 %0, %1 offset:4608" : "=v"(t01) : "v"(vtr));
    asm volatile("ds_read_b64_tr_b16 %0, %1 offset:4128" : "=v"(t10) : "v"(vtr));
    asm volatile("ds_read_b64_tr_b16 %0, %1 offset:4640" : "=v"(t11) : "v"(vtr));
    asm volatile("ds_read_b64_tr_b16 %0, %1 offset:4160" : "=v"(t20) : "v"(vtr));
    asm volatile("ds_read_b64_tr_b16 %0, %1 offset:4672" : "=v"(t21) : "v"(vtr));
    asm volatile("ds_read_b64_tr_b16 %0, %1 offset:4192" : "=v"(t30) : "v"(vtr));
    asm volatile("ds_read_b64_tr_b16 %0, %1 offset:4704" : "=v"(t31) : "v"(vtr));
    asm volatile("s_waitcnt lgkmcnt(0)" ::: "memory");
    __builtin_amdgcn_sched_barrier(0);
    {
      union { short8 s; u32x2 d[2]; } v0u, v1u, v2u, v3u;
      v0u.d[0]=t00; v0u.d[1]=t01;
      v1u.d[0]=t10; v1u.d[1]=t11;
      v2u.d[0]=t20; v2u.d[1]=t21;
      v3u.d[0]=t30; v3u.d[1]=t31;
      o[0] = __builtin_amdgcn_mfma_f32_16x16x32_bf16(v0u.s, pb2.s, o[0], 0,0,0);
      o[1] = __builtin_amdgcn_mfma_f32_16x16x32_bf16(v1u.s, pb2.s, o[1], 0,0,0);
      o[2] = __builtin_amdgcn_mfma_f32_16x16x32_bf16(v2u.s, pb2.s, o[2], 0,0,0);
      o[3] = __builtin_amdgcn_mfma_f32_16x16x32_bf16(v3u.s, pb2.s, o[3], 0,0,0);
    }
  };

  const int nCh = CAUSAL ? (qt + 1) : 8;
  STAGE(0, 0);
  for (int jc = 0; jc < nCh - 1; ++jc){
    STAGE((jc+1) & 1, (jc+1)*64);
    asm volatile("s_waitcnt vmcnt(4)" ::: "memory");
    HBAR; SB0;
    COMPUTE(jc & 1, jc*64);
    SB0; HBAR;
  }
  asm volatile("s_waitcnt vmcnt(0)" ::: "memory");
  HBAR; SB0;
  COMPUTE((nCh-1) & 1, (nCh-1)*64);
  SB0; HBAR;

  const float inv = 1.f / lrun;
  char* Olds = smem;
  #pragma unroll
  for (int dd = 0; dd < 4; dd++){
    u32x2 val;
    val.x = pk2(o[dd][0]*inv, o[dd][1]*inv);
    val.y = pk2(o[dd][2]*inv, o[dd][3]*inv);
    const int row = w*16 + c16;
    const int off = 32*dd + 8*g;
    const int chunk = off >> 4, rem = off & 15;
    *(u32x2*)(Olds + row*128 + ((chunk ^ (row & 7)) << 4) + rem) = val;
  }
  __syncthreads();
  const int orow = tid >> 2, oc = tid & 3;
  #pragma unroll
  for (int i = 0; i < 2; i++){
    const int ch = oc*2 + i;
    const u32x4 vv = *(const u32x4*)(Olds + orow*128 + ((ch ^ (orow & 7)) << 4));
    *(u32x4*)(Op + (qt*64 + orow)*oS + ch*8) = vv;
  }
}

// ----------------------------------------------------------------------------
static inline int cvt_grid(int n8){ int g = (n8 + 255) / 256; return g > 2048 ? 2048 : g; }

extern "C" void kernel_launch(void* const* d_in, const int* in_sizes, int n_in,
                              void* d_out, int out_size, void* d_ws, size_t ws_size,
                              hipStream_t stream)
{
  (void)in_sizes; (void)n_in; (void)out_size; (void)ws_size;
  const float* src      = (const float*)d_in[0];
  const float* tgt      = (const float*)d_in[1];
  const float* e_qkv_w  = (const float*)d_in[2];
  const float* e_qkv_b  = (const float*)d_in[3];
  const float* e_out_w  = (const float*)d_in[4];
  const float* e_out_b  = (const float*)d_in[5];
  const float* e_ln1_g  = (const float*)d_in[6];
  const float* e_ln1_b  = (const float*)d_in[7];
  const float* e_fc1_w  = (const float*)d_in[8];
  const float* e_fc1_b  = (const float*)d_in[9];
  const float* e_fc2_w  = (const float*)d_in[10];
  const float* e_fc2_b  = (const float*)d_in[11];
  const float* e_ln2_g  = (const float*)d_in[12];
  const float* e_ln2_b  = (const float*)d_in[13];
  const float* e_nrm_g  = (const float*)d_in[14];
  const float* e_nrm_b  = (const float*)d_in[15];
  const float* dc_qkv_w = (const float*)d_in[16];
  const float* dc_qkv_b = (const float*)d_in[17];
  const float* dc_sout_w= (const float*)d_in[18];
  const float* dc_sout_b= (const float*)d_in[19];
  const float* dc_ln1_g = (const float*)d_in[20];
  const float* dc_ln1_b = (const float*)d_in[21];
  const float* dc_q_w   = (const float*)d_in[22];
  const float* dc_q_b   = (const float*)d_in[23];
  const float* dc_kv_w  = (const float*)d_in[24];
  const float* dc_kv_b  = (const float*)d_in[25];
  const float* dc_cout_w= (const float*)d_in[26];
  const float* dc_cout_b= (const float*)d_in[27];
  const float* dc_ln2_g = (const float*)d_in[28];
  const float* dc_ln2_b = (const float*)d_in[29];
  const float* dc_fc1_w = (const float*)d_in[30];
  const float* dc_fc1_b = (const float*)d_in[31];
  const float* dc_fc2_w = (const float*)d_in[32];
  const float* dc_fc2_b = (const float*)d_in[33];
  const float* dc_ln3_g = (const float*)d_in[34];
  const float* dc_ln3_b = (const float*)d_in[35];
  const float* dc_nrm_g = (const float*)d_in[36];
  const float* dc_nrm_b = (const float*)d_in[37];

  char* ws = (char*)d_ws;
  u16*  ln_out = (u16*)(ws);                    //  8 MB
  u16*  attn_o = (u16*)(ws + (8u<<20));         //  8 MB
  u16*  membuf = (u16*)(ws + (16u<<20));        //  8 MB
  float* xres  = (float*)(ws + (24u<<20));      // 16 MB
  u16*  region = (u16*)(ws + (40u<<20));        // 32 MB
  u16*  qkv   = region;
  u16*  hbuf  = region;
  u16*  qbuf  = region;
  u16*  wb    = (u16*)(ws + (72u<<20));         // 352 MB bf16 weights
  u16*  kvall = (u16*)(ws + (424ull<<20));      // 96 MB batched decoder KV

  const dim3 blk(256);
  const dim3 blk512(512);
  const int M = 4096;

  // ---------- upfront: convert ALL weights to bf16 (11 launches) ----------
  size_t woff = 0;
  auto CV = [&](const float* wsrc, size_t n)->u16* {
    u16* p = wb + woff; woff += n;
    cvt_k<<<cvt_grid((int)(n >> 3)), blk, 0, stream>>>(wsrc, p, (int)(n >> 3));
    return p;
  };
  u16* Weqkv = CV(e_qkv_w,  6ull*3072*1024);
  u16* Weout = CV(e_out_w,  6ull*1024*1024);
  u16* Wefc1 = CV(e_fc1_w,  6ull*4096*1024);
  u16* Wefc2 = CV(e_fc2_w,  6ull*4096*1024);
  u16* Wdqkv = CV(dc_qkv_w, 6ull*3072*1024);
  u16* Wdsout= CV(dc_sout_w,6ull*1024*1024);
  u16* Wdq   = CV(dc_q_w,   6ull*1024*1024);
  u16* Wdkv  = CV(dc_kv_w,  6ull*2048*1024);
  u16* Wdcout= CV(dc_cout_w,6ull*1024*1024);
  u16* Wdfc1 = CV(dc_fc1_w, 6ull*4096*1024);
  u16* Wdfc2 = CV(dc_fc2_w, 6ull*4096*1024);

  // ----------------- encoder -----------------
  for (int i = 0; i < 6; i++){
    const float* xin = i ? xres : src;
    ln_k<0><<<4096, blk, 0, stream>>>(xin, e_ln1_g + i*1024, e_ln1_b + i*1024, ln_out);
    gemm256_k<0><<<dim3(16, 12), blk512, 0, stream>>>(ln_out,
        Weqkv + (size_t)i*3145728, e_qkv_b + i*3072, qkv, M, 3072, 1024);
    attn_k<0><<<dim3(8,128), blk, 0, stream>>>(qkv, 3072, 24576,
        qkv+1024, 3072, 24576, qkv+2048, 3072, 24576, attn_o, 1024, 8192, 0.125f);
    gemm128p_k<0,1,1><<<dim3(8, 32), blk512, 0, stream>>>(attn_o,
        Weout + (size_t)i*1048576, e_out_b + i*1024, xin, xres, M, 1024, 1024);
    ln_k<0><<<4096, blk, 0, stream>>>(xres, e_ln2_g + i*1024, e_ln2_b + i*1024, ln_out);
    gemm256_k<1><<<dim3(16, 16), blk512, 0, stream>>>(ln_out,
        Wefc1 + (size_t)i*4194304, e_fc1_b + i*4096, hbuf, M, 4096, 1024);
    gemm128p_k<0,1,1><<<dim3(8, 32), blk512, 0, stream>>>(hbuf,
        Wefc2 + (size_t)i*4194304, e_fc2_b + i*1024, xres, xres, M, 1024, 4096);
  }
  ln_k<0><<<4096, blk, 0, stream>>>(xres, e_nrm_g, e_nrm_b, membuf);

  // batched decoder cross-attn KV: one GEMM over all 6 layers (N = 6*2048)
  gemm256_k<0><<<dim3(16, 48), blk512, 0, stream>>>(membuf,
      Wdkv, dc_kv_b, kvall, M, 12288, 1024);

  // ----------------- decoder -----------------
  for (int i = 0; i < 6; i++){
    const float* yin = i ? xres : tgt;
    ln_k<0><<<4096, blk, 0, stream>>>(yin, dc_ln1_g + i*1024, dc_ln1_b + i*1024, ln_out);
    gemm256_k<0><<<dim3(16, 12), blk512, 0, stream>>>(ln_out,
        Wdqkv + (size_t)i*3145728, dc_qkv_b + i*3072, qkv, M, 3072, 1024);
    attn_k<1><<<dim3(8,128), blk, 0, stream>>>(qkv, 3072, 24576,
        qkv+1024, 3072, 24576, qkv+2048, 3072, 24576, attn_o, 1024, 8192, 0.125f);
    gemm128p_k<0,1,1><<<dim3(8, 32), blk512, 0, stream>>>(attn_o,
        Wdsout + (size_t)i*1048576, dc_sout_b + i*1024, yin, xres, M, 1024, 1024);
    ln_k<0><<<4096, blk, 0, stream>>>(xres, dc_ln2_g + i*1024, dc_ln2_b + i*1024, ln_out);
    gemm128p_k<0,0,0><<<dim3(8, 32), blk512, 0, stream>>>(ln_out,
        Wdq + (size_t)i*1048576, dc_q_b + i*1024, nullptr, qbuf, M, 1024, 1024);
    attn_k<0><<<dim3(8,128), blk, 0, stream>>>(qbuf, 1024, 8192,
        kvall + i*2048, 12288, 98304, kvall + i*2048 + 1024, 12288, 98304,
        attn_o, 1024, 8192, 0.125f);
    gemm128p_k<0,1,1><<<dim3(8, 32), blk512, 0, stream>>>(attn_o,
        Wdcout + (size_t)i*1048576, dc_cout_b + i*1024, xres, xres, M, 1024, 1024);
    ln_k<0><<<4096, blk, 0, stream>>>(xres, dc_ln3_g + i*1024, dc_ln3_b + i*1024, ln_out);
    gemm256_k<1><<<dim3(16, 16), blk512, 0, stream>>>(ln_out,
        Wdfc1 + (size_t)i*4194304, dc_fc1_b + i*4096, hbuf, M, 4096, 1024);
    gemm128p_k<0,1,1><<<dim3(8, 32), blk512, 0, stream>>>(hbuf,
        Wdfc2 + (size_t)i*4194304, dc_fc2_b + i*1024, xres, xres, M, 1024, 4096);
  }
  ln_k<1><<<4096, blk, 0, stream>>>(xres, dc_nrm_g, dc_nrm_b, d_out);
}

// Round 17
// 3108.357 us; speedup vs baseline: 1.0231x; 1.0092x over previous
//
#include <hip/hip_runtime.h>

typedef __attribute__((ext_vector_type(4))) float f32x4;
typedef __attribute__((ext_vector_type(8))) short short8;
typedef unsigned int u32;
typedef unsigned short u16;
typedef __attribute__((ext_vector_type(2))) u32 u32x2;
typedef __attribute__((ext_vector_type(4))) u32 u32x4;

#define DEV __device__ __forceinline__
#define SB0  __builtin_amdgcn_sched_barrier(0)
#define HBAR asm volatile("s_barrier" ::: "memory")

DEV u16 f2b(float f){
  u32 u = __builtin_bit_cast(u32, f);
  u32 r = u + 0x7fffu + ((u >> 16) & 1u);
  return (u16)(r >> 16);
}
DEV u32 pk2(float a, float b){ return (u32)f2b(a) | ((u32)f2b(b) << 16); }

DEV void gload16(const void* g, void* l){
  __builtin_amdgcn_global_load_lds((const __attribute__((address_space(1))) void*)g,
                                   (__attribute__((address_space(3))) void*)l, 16, 0, 0);
}
DEV u32 lds_addr(void* p){
  return (u32)(unsigned long long)(__attribute__((address_space(3))) char*)p;
}

// ---------------- fp32 -> bf16 conversion (one launch per weight) ------------
__global__ __launch_bounds__(256) void cvt_k(const float* __restrict__ in,
                                             u16* __restrict__ out, int n8)
{
  int i = blockIdx.x*256 + threadIdx.x;
  const int stride = gridDim.x*256;
  for (; i < n8; i += stride){
    const float4 a = ((const float4*)in)[2*i];
    const float4 b = ((const float4*)in)[2*i+1];
    u32x4 r;
    r.x = pk2(a.x,a.y); r.y = pk2(a.z,a.w);
    r.z = pk2(b.x,b.y); r.w = pk2(b.z,b.w);
    ((u32x4*)out)[i] = r;
  }
}

// ---------------- LayerNorm --------------------------------------------------
template<int OUT_F32>
__global__ __launch_bounds__(256) void ln_k(const float* __restrict__ x,
    const float* __restrict__ gam, const float* __restrict__ bet,
    void* __restrict__ out)
{
  const int row = blockIdx.x, tid = threadIdx.x;
  const float4 v = ((const float4*)(x + row*1024))[tid];
  float s = (v.x + v.y) + (v.z + v.w);
  float q = (v.x*v.x + v.y*v.y) + (v.z*v.z + v.w*v.w);
  #pragma unroll
  for (int m = 1; m < 64; m <<= 1){ s += __shfl_xor(s, m); q += __shfl_xor(q, m); }
  __shared__ float ps[4], pq[4];
  if ((tid & 63) == 0){ ps[tid>>6] = s; pq[tid>>6] = q; }
  __syncthreads();
  s = (ps[0]+ps[1]) + (ps[2]+ps[3]);
  q = (pq[0]+pq[1]) + (pq[2]+pq[3]);
  const float mean = s * (1.f/1024.f);
  const float var  = q * (1.f/1024.f) - mean*mean;
  const float rstd = rsqrtf(var + 1e-5f);
  const float4 gg = ((const float4*)gam)[tid];
  const float4 bb = ((const float4*)bet)[tid];
  const float o0 = (v.x-mean)*rstd*gg.x + bb.x;
  const float o1 = (v.y-mean)*rstd*gg.y + bb.y;
  const float o2 = (v.z-mean)*rstd*gg.z + bb.z;
  const float o3 = (v.w-mean)*rstd*gg.w + bb.w;
  if (OUT_F32){
    float4 r; r.x=o0; r.y=o1; r.z=o2; r.w=o3;
    ((float4*)out)[row*256 + tid] = r;
  } else {
    u32x2 r; r.x = pk2(o0,o1); r.y = pk2(o2,o3);
    ((u32x2*)out)[row*256 + tid] = r;
  }
}

// ---------------- GEMM 256x256 8-wave, 4-phase pipelined (fat shapes) --------
// Supertiled block order: 8-M-block panels (A-panel 4MB = per-XCD L2),
// msub-fastest then N within panel -> A stays L2-resident across N sweeps.
// Epilogue: acc -> LDS bf16 tile -> fully coalesced 512B-row stores.
template<int DO_GELU>
__global__ __launch_bounds__(512,2) void gemm256_k(
    const u16* __restrict__ A, const u16* __restrict__ W,
    const float* __restrict__ bias, u16* __restrict__ Cout,
    int M, int N, int K)
{
  __shared__ char lds[131072];
  const int tid = threadIdx.x;
  const int lane = tid & 63, wid = tid >> 6;
  const int wr = wid >> 2, wc = wid & 3;
  const int g = lane >> 4, c16 = lane & 15;

  const u32 nwg = gridDim.x * gridDim.y;
  u32 flat = blockIdx.x + gridDim.x * blockIdx.y;
  {
    const u32 q = nwg >> 3, r = nwg & 7;
    const u32 xcd = flat & 7, idx = flat >> 3;
    flat = (xcd < r ? xcd*(q+1) : r*(q+1) + (xcd-r)*q) + idx;
  }
  // supertile decode: panels of 8 M-blocks; msub fastest, then N, then panel
  const u32 span = 8u * gridDim.y;
  const int panel = (int)(flat / span);
  const int rem   = (int)(flat % span);
  const int m0 = (panel*8 + (rem & 7)) * 256;
  const int n0 = (rem >> 3) * 256;

  f32x4 acc[8][4];
  #pragma unroll
  for (int m = 0; m < 8; m++)
    #pragma unroll
    for (int n = 0; n < 4; n++) acc[m][n] = (f32x4){0.f,0.f,0.f,0.f};

  const int srow = tid >> 3, schk = tid & 7;
  const int scg = schk ^ (srow & 7);
  const u16* aS = A + (size_t)(m0 + srow)*K + scg*8;
  const u16* wS = W + (size_t)(n0 + srow)*K + scg*8;

  auto SG = [&](const u16* base, int regionOff, int sb, int half, int i, int kk){
    gload16(base + (size_t)(half*128 + i*64)*K + kk,
            lds + sb*65536 + regionOff + half*16384 + i*8192 + tid*16);
  };
  short8 af[4][2], bf[4][2];
  auto LDA4 = [&](char* bufA, int mbase){
    #pragma unroll
    for (int i = 0; i < 4; i++){
      const int r = (mbase + i)*16 + c16;
      const int rx = r & 7;
      af[i][0] = *(const short8*)(bufA + r*128 + ((g ^ rx) << 4));
      af[i][1] = *(const short8*)(bufA + r*128 + (((4 + g) ^ rx) << 4));
    }
  };
  auto LDB2 = [&](char* bufB, int nbase){
    #pragma unroll
    for (int i = 0; i < 2; i++){
      const int r = (wc & 1)*64 + (nbase + i)*16 + c16;
      const int rx = r & 7;
      bf[nbase+i][0] = *(const short8*)(bufB + r*128 + ((g ^ rx) << 4));
      bf[nbase+i][1] = *(const short8*)(bufB + r*128 + (((4 + g) ^ rx) << 4));
    }
  };

  const int NT = K >> 6;
  SG(wS, 32768, 0, 0, 0, 0); SG(wS, 32768, 0, 0, 1, 0);
  SG(wS, 32768, 0, 1, 0, 0); SG(wS, 32768, 0, 1, 1, 0);
  SG(aS, 0,     0, 0, 0, 0); SG(aS, 0,     0, 0, 1, 0);
  SG(aS, 0,     0, 1, 0, 0); SG(aS, 0,     0, 1, 1, 0);
  asm volatile("s_waitcnt vmcnt(1)" ::: "memory");
  HBAR;

  for (int t = 0; t < NT; ++t){
    const int b = t & 1, sb = b ^ 1;
    const int skk = (t+1) << 6;
    const bool st = (t+1 < NT);
    char* bufA = lds + b*65536 + wr*16384;
    char* bufB = lds + b*65536 + 32768 + (wc >> 1)*16384;

    LDA4(bufA, 0); LDB2(bufB, 0);
    if (st){ SG(wS, 32768, sb, 0, 0, skk); SG(wS, 32768, sb, 0, 1, skk); }
    HBAR;
    asm volatile("s_waitcnt lgkmcnt(0)" ::: "memory"); SB0;
    __builtin_amdgcn_s_setprio(1);
    #pragma unroll
    for (int ks = 0; ks < 2; ks++)
      #pragma unroll
      for (int i = 0; i < 4; i++)
        #pragma unroll
        for (int j = 0; j < 2; j++)
          acc[i][j] = __builtin_amdgcn_mfma_f32_16x16x32_bf16(af[i][ks], bf[j][ks], acc[i][j], 0,0,0);
    __builtin_amdgcn_s_setprio(0);
    LDB2(bufB, 2);
    if (st){ SG(wS, 32768, sb, 1, 0, skk); SG(wS, 32768, sb, 1, 1, skk); }
    HBAR;
    asm volatile("s_waitcnt lgkmcnt(0)" ::: "memory"); SB0;
    __builtin_amdgcn_s_setprio(1);
    #pragma unroll
    for (int ks = 0; ks < 2; ks++)
      #pragma unroll
      for (int i = 0; i < 4; i++)
        #pragma unroll
        for (int j = 2; j < 4; j++)
          acc[i][j] = __builtin_amdgcn_mfma_f32_16x16x32_bf16(af[i][ks], bf[j][ks], acc[i][j], 0,0,0);
    __builtin_amdgcn_s_setprio(0);
    if (st) asm volatile("s_waitcnt vmcnt(4)" ::: "memory");
    else    asm volatile("s_waitcnt vmcnt(0)" ::: "memory");
    HBAR;
    LDA4(bufA, 4);
    if (st){ SG(aS, 0, sb, 0, 0, skk); SG(aS, 0, sb, 0, 1, skk); }
    asm volatile("s_waitcnt lgkmcnt(0)" ::: "memory"); SB0;
    __builtin_amdgcn_s_setprio(1);
    #pragma unroll
    for (int ks = 0; ks < 2; ks++)
      #pragma unroll
      for (int i = 0; i < 4; i++)
        #pragma unroll
        for (int j = 0; j < 2; j++)
          acc[4+i][j] = __builtin_amdgcn_mfma_f32_16x16x32_bf16(af[i][ks], bf[j][ks], acc[4+i][j], 0,0,0);
    __builtin_amdgcn_s_setprio(0);
    if (st){ SG(aS, 0, sb, 1, 0, skk); SG(aS, 0, sb, 1, 1, skk); }
    HBAR;
    __builtin_amdgcn_s_setprio(1);
    #pragma unroll
    for (int ks = 0; ks < 2; ks++)
      #pragma unroll
      for (int i = 0; i < 4; i++)
        #pragma unroll
        for (int j = 2; j < 4; j++)
          acc[4+i][j] = __builtin_amdgcn_mfma_f32_16x16x32_bf16(af[i][ks], bf[j][ks], acc[4+i][j], 0,0,0);
    __builtin_amdgcn_s_setprio(0);
    if (st) asm volatile("s_waitcnt vmcnt(1)" ::: "memory");
    HBAR;
  }
  // after final HBAR all waves are done with K-loop LDS reads; LDS is free.

  // ---- epilogue phase 1: acc (+bias,+GELU) -> LDS bf16 tile [256][512B] ----
  #pragma unroll
  for (int n = 0; n < 4; n++){
    const int col = wc*64 + n*16 + c16;
    const float bv = bias[n0 + col];
    #pragma unroll
    for (int m = 0; m < 8; m++){
      const int rbase = wr*128 + m*16 + g*4;
      #pragma unroll
      for (int r = 0; r < 4; r++){
        float v = acc[m][n][r] + bv;
        if (DO_GELU) v = 0.5f*v*(1.f + erff(v*0.70710678118654752f));
        const int row = rbase + r;
        const int byte = col*2;
        const int ch = byte >> 4, rem2 = byte & 15;
        *(u16*)(lds + row*512 + ((ch ^ (row & 31)) << 4) + rem2) = f2b(v);
      }
    }
  }
  HBAR;
  // ---- epilogue phase 2: coalesced sweep, 512B per row, dwordx4 stores ----
  #pragma unroll
  for (int it = 0; it < 16; ++it){
    const int idx = it*512 + tid;
    const int row = idx >> 5;
    const int ch  = idx & 31;
    const u32x4 v = *(const u32x4*)(lds + row*512 + ((ch ^ (row & 31)) << 4));
    *(u32x4*)(Cout + (size_t)(m0 + row)*N + n0 + ch*8) = v;
  }
}

// ---------------- GEMM 128x128 8-wave, 2-phase pipelined (narrow-N) ----------
template<int DO_GELU, int DO_RES, int OUT_F32>
__global__ __launch_bounds__(512,2) void gemm128p_k(
    const u16* __restrict__ A, const u16* __restrict__ W,
    const float* __restrict__ bias, const float* __restrict__ res,
    void* __restrict__ Cout, int M, int N, int K)
{
  __shared__ char lds[65536];
  const int tid = threadIdx.x;
  const int lane = tid & 63, wid = tid >> 6;
  const int wr = wid >> 2, wc = wid & 3;
  const int g = lane >> 4, c16 = lane & 15;

  const u32 nwg = gridDim.x * gridDim.y;
  u32 flat = blockIdx.x + gridDim.x * blockIdx.y;
  {
    const u32 q = nwg >> 3, r = nwg & 7;
    const u32 xcd = flat & 7, idx = flat >> 3;
    flat = (xcd < r ? xcd*(q+1) : r*(q+1) + (xcd-r)*q) + idx;
  }
  const int n0 = (int)(flat % gridDim.x) * 128;   // N fastest
  const int m0 = (int)(flat / gridDim.x) * 128;

  f32x4 acc[4][2];
  #pragma unroll
  for (int m = 0; m < 4; m++)
    #pragma unroll
    for (int n = 0; n < 2; n++) acc[m][n] = (f32x4){0.f,0.f,0.f,0.f};

  const int srow = tid >> 3, schk = tid & 7;
  const int scg = schk ^ (srow & 7);
  const u16* aS = A + (size_t)(m0 + srow)*K + scg*8;
  const u16* wS = W + (size_t)(n0 + srow)*K + scg*8;

  auto SG = [&](const u16* base, int regionOff, int sb, int i, int kk){
    gload16(base + (size_t)(i*64)*K + kk,
            lds + sb*32768 + regionOff + i*8192 + tid*16);
  };
  short8 af[2][2], af2[2][2], bf[2][2];
  auto LDA = [&](short8 (*dst)[2], char* bufA, int mbase){
    #pragma unroll
    for (int i = 0; i < 2; i++){
      const int r = wr*64 + (mbase + i)*16 + c16;
      const int rx = r & 7;
      dst[i][0] = *(const short8*)(bufA + r*128 + ((g ^ rx) << 4));
      dst[i][1] = *(const short8*)(bufA + r*128 + (((4 + g) ^ rx) << 4));
    }
  };
  auto LDB = [&](char* bufB){
    #pragma unroll
    for (int i = 0; i < 2; i++){
      const int r = wc*32 + i*16 + c16;
      const int rx = r & 7;
      bf[i][0] = *(const short8*)(bufB + r*128 + ((g ^ rx) << 4));
      bf[i][1] = *(const short8*)(bufB + r*128 + (((4 + g) ^ rx) << 4));
    }
  };

  const int NT = K >> 6;
  SG(wS, 16384, 0, 0, 0); SG(wS, 16384, 0, 1, 0);
  SG(aS, 0,     0, 0, 0); SG(aS, 0,     0, 1, 0);

  for (int t = 0; t < NT; ++t){
    const int b = t & 1, sb = b ^ 1;
    const int skk = (t+1) << 6;
    const bool st = (t+1 < NT);
    char* bufA = lds + b*32768;
    char* bufB = lds + b*32768 + 16384;

    if (st){ SG(wS, 16384, sb, 0, skk); SG(wS, 16384, sb, 1, skk); }
    if (st) asm volatile("s_waitcnt vmcnt(2)" ::: "memory");
    else    asm volatile("s_waitcnt vmcnt(0)" ::: "memory");
    HBAR;
    LDA(af, bufA, 0); LDB(bufB);
    if (st){ SG(aS, 0, sb, 0, skk); SG(aS, 0, sb, 1, skk); }
    asm volatile("s_waitcnt lgkmcnt(0)" ::: "memory"); SB0;
    __builtin_amdgcn_s_setprio(1);
    #pragma unroll
    for (int ks = 0; ks < 2; ks++)
      #pragma unroll
      for (int i = 0; i < 2; i++)
        #pragma unroll
        for (int j = 0; j < 2; j++)
          acc[i][j] = __builtin_amdgcn_mfma_f32_16x16x32_bf16(af[i][ks], bf[j][ks], acc[i][j], 0,0,0);
    __builtin_amdgcn_s_setprio(0);
    LDA(af2, bufA, 2);
    asm volatile("s_waitcnt lgkmcnt(0)" ::: "memory"); SB0;
    __builtin_amdgcn_s_setprio(1);
    #pragma unroll
    for (int ks = 0; ks < 2; ks++)
      #pragma unroll
      for (int i = 0; i < 2; i++)
        #pragma unroll
        for (int j = 0; j < 2; j++)
          acc[2+i][j] = __builtin_amdgcn_mfma_f32_16x16x32_bf16(af2[i][ks], bf[j][ks], acc[2+i][j], 0,0,0);
    __builtin_amdgcn_s_setprio(0);
    HBAR;
  }

  #pragma unroll
  for (int n = 0; n < 2; n++){
    const int col = n0 + wc*32 + n*16 + c16;
    const float bv = bias[col];
    #pragma unroll
    for (int m = 0; m < 4; m++){
      const int rbase = m0 + wr*64 + m*16 + g*4;
      #pragma unroll
      for (int r = 0; r < 4; r++){
        float v = acc[m][n][r] + bv;
        if (DO_GELU) v = 0.5f*v*(1.f + erff(v*0.70710678118654752f));
        if (DO_RES)  v += res[(size_t)(rbase + r)*N + col];
        if (OUT_F32) ((float*)Cout)[(size_t)(rbase + r)*N + col] = v;
        else         ((u16*)Cout)[(size_t)(rbase + r)*N + col] = f2b(v);
      }
    }
  }
}

// ---------------- Flash attention, HD=64, KVBLK=64 ---------------------------
template<int CAUSAL>
__global__ __launch_bounds__(256,4) void attn_k(
    const u16* __restrict__ Qb, int qB, int qS,
    const u16* __restrict__ Kb, int kB, int kS,
    const u16* __restrict__ Vb, int vB, int vS,
    u16* __restrict__ Ob, int oB, int oS, float scale)
{
  __shared__ char smem[32768];
  const int tid = threadIdx.x;
  const int lane = tid & 63, w = tid >> 6;
  const int g = lane >> 4, c16 = lane & 15;
  const int qt = blockIdx.x, bh = blockIdx.y;
  const int b = bh >> 4, h = bh & 15;
  const u16* Q  = Qb + b*qB + h*64;
  const u16* Kp = Kb + b*kB + h*64;
  const u16* Vp = Vb + b*vB + h*64;
  u16*       Op = Ob + b*oB + h*64;

  const int qrow = qt*64 + w*16 + c16;
  const short8 bq0 = *(const short8*)(Q + qrow*qS + g*8);
  const short8 bq1 = *(const short8*)(Q + qrow*qS + 32 + g*8);

  f32x4 o[4];
  #pragma unroll
  for (int d = 0; d < 4; d++) o[d] = (f32x4){0.f,0.f,0.f,0.f};
  float mrun = -__builtin_inff(), lrun = 0.f;

  const int srow = tid >> 3, schk = tid & 7;
  const u16* kSrc = Kp + (size_t)srow*kS + (schk ^ (srow & 7))*8;
  const u16* vSrc = Vp + (size_t)srow*vS + schk*8;
  const u32 vtr0 = lds_addr(smem) + 16384 + (8*g + (c16 >> 2))*128 + (c16 & 3)*8;

  auto STAGE = [&](int p, int j0){
    char* kb = smem + p*8192 + w*1024;
    char* vb = smem + 16384 + p*8192 + w*1024;
    gload16(kSrc + (size_t)j0*kS, kb);
    gload16(kSrc + (size_t)(j0+32)*kS, kb + 4096);
    gload16(vSrc + (size_t)j0*vS, vb);
    gload16(vSrc + (size_t)(j0+32)*vS, vb + 4096);
  };
  auto COMPUTE = [&](int p, int j0){
    char* Ks = smem + p*8192;
    f32x4 st[4];
    #pragma unroll
    for (int t = 0; t < 4; t++){
      const int row = t*16 + c16;
      const int rx = row & 7;
      const short8 ka0 = *(const short8*)(Ks + row*128 + ((g ^ rx) << 4));
      const short8 ka1 = *(const short8*)(Ks + row*128 + (((4 + g) ^ rx) << 4));
      f32x4 z = (f32x4){0.f,0.f,0.f,0.f};
      z = __builtin_amdgcn_mfma_f32_16x16x32_bf16(ka0, bq0, z, 0,0,0);
      z = __builtin_amdgcn_mfma_f32_16x16x32_bf16(ka1, bq1, z, 0,0,0);
      st[t] = z;
    }
    float mloc = -__builtin_inff();
    #pragma unroll
    for (int t = 0; t < 4; t++)
      #pragma unroll
      for (int r = 0; r < 4; r++){
        float sv = st[t][r]*scale;
        if (CAUSAL){ if (j0 + t*16 + g*4 + r > qrow) sv = -__builtin_inff(); }
        st[t][r] = sv;
        mloc = fmaxf(mloc, sv);
      }
    mloc = fmaxf(mloc, __shfl_xor(mloc, 16));
    mloc = fmaxf(mloc, __shfl_xor(mloc, 32));
    const float mnew = fmaxf(mrun, mloc);
    const float corr = __expf(mrun - mnew);
    float psum = 0.f;
    u32 pk[4][2];
    #pragma unroll
    for (int t = 0; t < 4; t++){
      const float p0 = __expf(st[t][0]-mnew), p1 = __expf(st[t][1]-mnew);
      const float p2 = __expf(st[t][2]-mnew), p3 = __expf(st[t][3]-mnew);
      psum += (p0+p1) + (p2+p3);
      pk[t][0] = pk2(p0,p1); pk[t][1] = pk2(p2,p3);
    }
    psum += __shfl_xor(psum, 16);
    psum += __shfl_xor(psum, 32);
    lrun = lrun*corr + psum;
    mrun = mnew;
    #pragma unroll
    for (int d = 0; d < 4; d++){
      o[d][0]*=corr; o[d][1]*=corr; o[d][2]*=corr; o[d][3]*=corr;
    }
    const int sl0 = c16 | (((g << 1)     & 3) << 4);
    const int sl1 = c16 | ((((g << 1)+1) & 3) << 4);
    const bool hi = g >= 2;
    union { short8 s; u32 u[4]; } pb, pb2;
    {
      const u32 a00 = (u32)__shfl((int)pk[0][0], sl0), a01 = (u32)__shfl((int)pk[0][1], sl0);
      const u32 a02 = (u32)__shfl((int)pk[0][0], sl1), a03 = (u32)__shfl((int)pk[0][1], sl1);
      const u32 a10 = (u32)__shfl((int)pk[1][0], sl0), a11 = (u32)__shfl((int)pk[1][1], sl0);
      const u32 a12 = (u32)__shfl((int)pk[1][0], sl1), a13 = (u32)__shfl((int)pk[1][1], sl1);
      pb.u[0] = hi ? a10 : a00;
      pb.u[1] = hi ? a11 : a01;
      pb.u[2] = hi ? a12 : a02;
      pb.u[3] = hi ? a13 : a03;
    }
    {
      const u32 a00 = (u32)__shfl((int)pk[2][0], sl0), a01 = (u32)__shfl((int)pk[2][1], sl0);
      const u32 a02 = (u32)__shfl((int)pk[2][0], sl1), a03 = (u32)__shfl((int)pk[2][1], sl1);
      const u32 a10 = (u32)__shfl((int)pk[3][0], sl0), a11 = (u32)__shfl((int)pk[3][1], sl0);
      const u32 a12 = (u32)__shfl((int)pk[3][0], sl1), a13 = (u32)__shfl((int)pk[3][1], sl1);
      pb2.u[0] = hi ? a10 : a00;
      pb2.u[1] = hi ? a11 : a01;
      pb2.u[2] = hi ? a12 : a02;
      pb2.u[3] = hi ? a13 : a03;
    }

    const u32 vtr = vtr0 + p*8192;
    u32x2 t00,t01,t10,t11,t20,t21,t30,t31;
    asm volatile("ds_read_b64_tr_b16 %0, %1 offset:0"   : "=v"(t00) : "v"(vtr));
    asm volatile("ds_read_b64_tr_b16 %0, %1 offset:512" : "=v"(t01) : "v"(vtr));
    asm volatile("ds_read_b64_tr_b16 %0, %1 offset:32"  : "=v"(t10) : "v"(vtr));
    asm volatile("ds_read_b64_tr_b16 %0, %1 offset:544" : "=v"(t11) : "v"(vtr));
    asm volatile("ds_read_b64_tr_b16 %0, %1 offset:64"  : "=v"(t20) : "v"(vtr));
    asm volatile("ds_read_b64_tr_b16 %0, %1 offset:576" : "=v"(t21) : "v"(vtr));
    asm volatile("ds_read_b64_tr_b16 %0, %1 offset:96"  : "=v"(t30) : "v"(vtr));
    asm volatile("ds_read_b64_tr_b16 %0, %1 offset:608" : "=v"(t31) : "v"(vtr));
    asm volatile("s_waitcnt lgkmcnt(0)" ::: "memory");
    __builtin_amdgcn_sched_barrier(0);
    {
      union { short8 s; u32x2 d[2]; } v0u, v1u, v2u, v3u;
      v0u.d[0]=t00; v0u.d[1]=t01;
      v1u.d[0]=t10; v1u.d[1]=t11;
      v2u.d[0]=t20; v2u.d[1]=t21;
      v3u.d[0]=t30; v3u.d[1]=t31;
      o[0] = __builtin_amdgcn_mfma_f32_16x16x32_bf16(v0u.s, pb.s, o[0], 0,0,0);
      o[1] = __builtin_amdgcn_mfma_f32_16x16x32_bf16(v1u.s, pb.s, o[1], 0,0,0);
      o[2] = __builtin_amdgcn_mfma_f32_16x16x32_bf16(v2u.s, pb.s, o[2], 0,0,0);
      o[3] = __builtin_amdgcn_mfma_f32_16x16x32_bf16(v3u.s, pb.s, o[3], 0,0,0);
    }
    asm volatile("ds_read_b64_tr_b16 %0, %1 offset:4096" : "=v"(t00) : "v"(vtr));
    asm volatile("ds_read_b64_tr_b16 %0, %1 offset:4608" : "=v"(t01) : "v"(vtr));
    asm volatile("ds_read_b64_tr_b16 %0, %1 offset:4128" : "=v"(t10) : "v"(vtr));
    asm volatile("ds_read_b64_tr_b16 %0, %1 offset:4640" : "=v"(t11) : "v"(vtr));
    asm volatile("ds_read_b64_tr_b16 %0, %1 offset:4160" : "=v"(t20) : "v"(vtr));
    asm volatile("ds_read_b64_tr_b16 %0, %1 offset:4672" : "=v"(t21) : "v"(vtr));
    asm volatile("ds_read_b64_tr_b16 %0, %1 offset:4192" : "=v"(t30) : "v"(vtr));
    asm volatile("ds_read_b64_tr_b16 %0, %1 offset:4704" : "=v"(t31) : "v"(vtr));
    asm volatile("s_waitcnt lgkmcnt(0)" ::: "memory");
    __builtin_amdgcn_sched_barrier(0);
    {
      union { short8 s; u32x2 d[2]; } v0u, v1u, v2u, v3u;
      v0u.d[0]=t00; v0u.d[1]=t01;
      v1u.d[0]=t10; v1u.d[1]=t11;
      v2u.d[0]=t20; v2u.d[1]=t21;
      v3u.d[0]=t30; v3u.d[1]=t31;
      o[0] = __builtin_amdgcn_mfma_f32_16x16x32_bf16(v0u.s, pb2.s, o[0], 0,0,0);
      o[1] = __builtin_amdgcn_mfma_f32_16x16x32_bf16(v1u.s, pb2.s, o[1], 0,0,0);
      o[2] = __builtin_amdgcn_mfma_f32_16x16x32_bf16(v2u.s, pb2.s, o[2], 0,0,0);
      o[3] = __builtin_amdgcn_mfma_f32_16x16x32_bf16(v3u.s, pb2.s, o[3], 0,0,0);
    }
  };

  const int nCh = CAUSAL ? (qt + 1) : 8;
  STAGE(0, 0);
  for (int jc = 0; jc < nCh - 1; ++jc){
    STAGE((jc+1) & 1, (jc+1)*64);
    asm volatile("s_waitcnt vmcnt(4)" ::: "memory");
    HBAR; SB0;
    COMPUTE(jc & 1, jc*64);
    SB0; HBAR;
  }
  asm volatile("s_waitcnt vmcnt(0)" ::: "memory");
  HBAR; SB0;
  COMPUTE((nCh-1) & 1, (nCh-1)*64);
  SB0; HBAR;

  const float inv = 1.f / lrun;
  char* Olds = smem;
  #pragma unroll
  for (int dd = 0; dd < 4; dd++){
    u32x2 val;
    val.x = pk2(o[dd][0]*inv, o[dd][1]*inv);
    val.y = pk2(o[dd][2]*inv, o[dd][3]*inv);
    const int row = w*16 + c16;
    const int off = 32*dd + 8*g;
    const int chunk = off >> 4, rem = off & 15;
    *(u32x2*)(Olds + row*128 + ((chunk ^ (row & 7)) << 4) + rem) = val;
  }
  __syncthreads();
  const int orow = tid >> 2, oc = tid & 3;
  #pragma unroll
  for (int i = 0; i < 2; i++){
    const int ch = oc*2 + i;
    const u32x4 vv = *(const u32x4*)(Olds + orow*128 + ((ch ^ (orow & 7)) << 4));
    *(u32x4*)(Op + (qt*64 + orow)*oS + ch*8) = vv;
  }
}

// ----------------------------------------------------------------------------
static inline int cvt_grid(int n8){ int g = (n8 + 255) / 256; return g > 2048 ? 2048 : g; }

extern "C" void kernel_launch(void* const* d_in, const int* in_sizes, int n_in,
                              void* d_out, int out_size, void* d_ws, size_t ws_size,
                              hipStream_t stream)
{
  (void)in_sizes; (void)n_in; (void)out_size; (void)ws_size;
  const float* src      = (const float*)d_in[0];
  const float* tgt      = (const float*)d_in[1];
  const float* e_qkv_w  = (const float*)d_in[2];
  const float* e_qkv_b  = (const float*)d_in[3];
  const float* e_out_w  = (const float*)d_in[4];
  const float* e_out_b  = (const float*)d_in[5];
  const float* e_ln1_g  = (const float*)d_in[6];
  const float* e_ln1_b  = (const float*)d_in[7];
  const float* e_fc1_w  = (const float*)d_in[8];
  const float* e_fc1_b  = (const float*)d_in[9];
  const float* e_fc2_w  = (const float*)d_in[10];
  const float* e_fc2_b  = (const float*)d_in[11];
  const float* e_ln2_g  = (const float*)d_in[12];
  const float* e_ln2_b  = (const float*)d_in[13];
  const float* e_nrm_g  = (const float*)d_in[14];
  const float* e_nrm_b  = (const float*)d_in[15];
  const float* dc_qkv_w = (const float*)d_in[16];
  const float* dc_qkv_b = (const float*)d_in[17];
  const float* dc_sout_w= (const float*)d_in[18];
  const float* dc_sout_b= (const float*)d_in[19];
  const float* dc_ln1_g = (const float*)d_in[20];
  const float* dc_ln1_b = (const float*)d_in[21];
  const float* dc_q_w   = (const float*)d_in[22];
  const float* dc_q_b   = (const float*)d_in[23];
  const float* dc_kv_w  = (const float*)d_in[24];
  const float* dc_kv_b  = (const float*)d_in[25];
  const float* dc_cout_w= (const float*)d_in[26];
  const float* dc_cout_b= (const float*)d_in[27];
  const float* dc_ln2_g = (const float*)d_in[28];
  const float* dc_ln2_b = (const float*)d_in[29];
  const float* dc_fc1_w = (const float*)d_in[30];
  const float* dc_fc1_b = (const float*)d_in[31];
  const float* dc_fc2_w = (const float*)d_in[32];
  const float* dc_fc2_b = (const float*)d_in[33];
  const float* dc_ln3_g = (const float*)d_in[34];
  const float* dc_ln3_b = (const float*)d_in[35];
  const float* dc_nrm_g = (const float*)d_in[36];
  const float* dc_nrm_b = (const float*)d_in[37];

  char* ws = (char*)d_ws;
  u16*  ln_out = (u16*)(ws);                    //  8 MB
  u16*  attn_o = (u16*)(ws + (8u<<20));         //  8 MB
  u16*  membuf = (u16*)(ws + (16u<<20));        //  8 MB
  float* xres  = (float*)(ws + (24u<<20));      // 16 MB
  u16*  region = (u16*)(ws + (40u<<20));        // 32 MB
  u16*  qkv   = region;
  u16*  hbuf  = region;
  u16*  qbuf  = region;
  u16*  wb    = (u16*)(ws + (72u<<20));         // 352 MB bf16 weights
  u16*  kvall = (u16*)(ws + (424ull<<20));      // 96 MB batched decoder KV

  const dim3 blk(256);
  const dim3 blk512(512);
  const int M = 4096;

  // ---------- upfront: convert ALL weights to bf16 (11 launches) ----------
  size_t woff = 0;
  auto CV = [&](const float* wsrc, size_t n)->u16* {
    u16* p = wb + woff; woff += n;
    cvt_k<<<cvt_grid((int)(n >> 3)), blk, 0, stream>>>(wsrc, p, (int)(n >> 3));
    return p;
  };
  u16* Weqkv = CV(e_qkv_w,  6ull*3072*1024);
  u16* Weout = CV(e_out_w,  6ull*1024*1024);
  u16* Wefc1 = CV(e_fc1_w,  6ull*4096*1024);
  u16* Wefc2 = CV(e_fc2_w,  6ull*4096*1024);
  u16* Wdqkv = CV(dc_qkv_w, 6ull*3072*1024);
  u16* Wdsout= CV(dc_sout_w,6ull*1024*1024);
  u16* Wdq   = CV(dc_q_w,   6ull*1024*1024);
  u16* Wdkv  = CV(dc_kv_w,  6ull*2048*1024);
  u16* Wdcout= CV(dc_cout_w,6ull*1024*1024);
  u16* Wdfc1 = CV(dc_fc1_w, 6ull*4096*1024);
  u16* Wdfc2 = CV(dc_fc2_w, 6ull*4096*1024);

  // ----------------- encoder -----------------
  for (int i = 0; i < 6; i++){
    const float* xin = i ? xres : src;
    ln_k<0><<<4096, blk, 0, stream>>>(xin, e_ln1_g + i*1024, e_ln1_b + i*1024, ln_out);
    gemm256_k<0><<<dim3(16, 12), blk512, 0, stream>>>(ln_out,
        Weqkv + (size_t)i*3145728, e_qkv_b + i*3072, qkv, M, 3072, 1024);
    attn_k<0><<<dim3(8,128), blk, 0, stream>>>(qkv, 3072, 24576,
        qkv+1024, 3072, 24576, qkv+2048, 3072, 24576, attn_o, 1024, 8192, 0.125f);
    gemm128p_k<0,1,1><<<dim3(8, 32), blk512, 0, stream>>>(attn_o,
        Weout + (size_t)i*1048576, e_out_b + i*1024, xin, xres, M, 1024, 1024);
    ln_k<0><<<4096, blk, 0, stream>>>(xres, e_ln2_g + i*1024, e_ln2_b + i*1024, ln_out);
    gemm256_k<1><<<dim3(16, 16), blk512, 0, stream>>>(ln_out,
        Wefc1 + (size_t)i*4194304, e_fc1_b + i*4096, hbuf, M, 4096, 1024);
    gemm128p_k<0,1,1><<<dim3(8, 32), blk512, 0, stream>>>(hbuf,
        Wefc2 + (size_t)i*4194304, e_fc2_b + i*1024, xres, xres, M, 1024, 4096);
  }
  ln_k<0><<<4096, blk, 0, stream>>>(xres, e_nrm_g, e_nrm_b, membuf);

  // batched decoder cross-attn KV: one GEMM over all 6 layers (N = 6*2048)
  gemm256_k<0><<<dim3(16, 48), blk512, 0, stream>>>(membuf,
      Wdkv, dc_kv_b, kvall, M, 12288, 1024);

  // ----------------- decoder -----------------
  for (int i = 0; i < 6; i++){
    const float* yin = i ? xres : tgt;
    ln_k<0><<<4096, blk, 0, stream>>>(yin, dc_ln1_g + i*1024, dc_ln1_b + i*1024, ln_out);
    gemm256_k<0><<<dim3(16, 12), blk512, 0, stream>>>(ln_out,
        Wdqkv + (size_t)i*3145728, dc_qkv_b + i*3072, qkv, M, 3072, 1024);
    attn_k<1><<<dim3(8,128), blk, 0, stream>>>(qkv, 3072, 24576,
        qkv+1024, 3072, 24576, qkv+2048, 3072, 24576, attn_o, 1024, 8192, 0.125f);
    gemm128p_k<0,1,1><<<dim3(8, 32), blk512, 0, stream>>>(attn_o,
        Wdsout + (size_t)i*1048576, dc_sout_b + i*1024, yin, xres, M, 1024, 1024);
    ln_k<0><<<4096, blk, 0, stream>>>(xres, dc_ln2_g + i*1024, dc_ln2_b + i*1024, ln_out);
    gemm128p_k<0,0,0><<<dim3(8, 32), blk512, 0, stream>>>(ln_out,
        Wdq + (size_t)i*1048576, dc_q_b + i*1024, nullptr, qbuf, M, 1024, 1024);
    attn_k<0><<<dim3(8,128), blk, 0, stream>>>(qbuf, 1024, 8192,
        kvall + i*2048, 12288, 98304, kvall + i*2048 + 1024, 12288, 98304,
        attn_o, 1024, 8192, 0.125f);
    gemm128p_k<0,1,1><<<dim3(8, 32), blk512, 0, stream>>>(attn_o,
        Wdcout + (size_t)i*1048576, dc_cout_b + i*1024, xres, xres, M, 1024, 1024);
    ln_k<0><<<4096, blk, 0, stream>>>(xres, dc_ln3_g + i*1024, dc_ln3_b + i*1024, ln_out);
    gemm256_k<1><<<dim3(16, 16), blk512, 0, stream>>>(ln_out,
        Wdfc1 + (size_t)i*4194304, dc_fc1_b + i*4096, hbuf, M, 4096, 1024);
    gemm128p_k<0,1,1><<<dim3(8, 32), blk512, 0, stream>>>(hbuf,
        Wdfc2 + (size_t)i*4194304, dc_fc2_b + i*1024, xres, xres, M, 1024, 4096);
  }
  ln_k<1><<<4096, blk, 0, stream>>>(xres, dc_nrm_g, dc_nrm_b, d_out);
}

// Round 18
// 3105.984 us; speedup vs baseline: 1.0238x; 1.0008x over previous
//
#include <hip/hip_runtime.h>

typedef __attribute__((ext_vector_type(4))) float f32x4;
typedef __attribute__((ext_vector_type(8))) short short8;
typedef unsigned int u32;
typedef unsigned short u16;
typedef __attribute__((ext_vector_type(2))) u32 u32x2;
typedef __attribute__((ext_vector_type(4))) u32 u32x4;

#define DEV __device__ __forceinline__
#define SB0  __builtin_amdgcn_sched_barrier(0)
#define HBAR asm volatile("s_barrier" ::: "memory")

DEV u16 f2b(float f){
  u32 u = __builtin_bit_cast(u32, f);
  u32 r = u + 0x7fffu + ((u >> 16) & 1u);
  return (u16)(r >> 16);
}
DEV u32 pk2(float a, float b){ return (u32)f2b(a) | ((u32)f2b(b) << 16); }

DEV void gload16(const void* g, void* l){
  __builtin_amdgcn_global_load_lds((const __attribute__((address_space(1))) void*)g,
                                   (__attribute__((address_space(3))) void*)l, 16, 0, 0);
}
DEV u32 lds_addr(void* p){
  return (u32)(unsigned long long)(__attribute__((address_space(3))) char*)p;
}

// ---------------- fp32 -> bf16 conversion (one launch per weight) ------------
__global__ __launch_bounds__(256) void cvt_k(const float* __restrict__ in,
                                             u16* __restrict__ out, int n8)
{
  int i = blockIdx.x*256 + threadIdx.x;
  const int stride = gridDim.x*256;
  for (; i < n8; i += stride){
    const float4 a = ((const float4*)in)[2*i];
    const float4 b = ((const float4*)in)[2*i+1];
    u32x4 r;
    r.x = pk2(a.x,a.y); r.y = pk2(a.z,a.w);
    r.z = pk2(b.x,b.y); r.w = pk2(b.z,b.w);
    ((u32x4*)out)[i] = r;
  }
}

// ---------------- LayerNorm --------------------------------------------------
template<int OUT_F32>
__global__ __launch_bounds__(256) void ln_k(const float* __restrict__ x,
    const float* __restrict__ gam, const float* __restrict__ bet,
    void* __restrict__ out)
{
  const int row = blockIdx.x, tid = threadIdx.x;
  const float4 v = ((const float4*)(x + row*1024))[tid];
  float s = (v.x + v.y) + (v.z + v.w);
  float q = (v.x*v.x + v.y*v.y) + (v.z*v.z + v.w*v.w);
  #pragma unroll
  for (int m = 1; m < 64; m <<= 1){ s += __shfl_xor(s, m); q += __shfl_xor(q, m); }
  __shared__ float ps[4], pq[4];
  if ((tid & 63) == 0){ ps[tid>>6] = s; pq[tid>>6] = q; }
  __syncthreads();
  s = (ps[0]+ps[1]) + (ps[2]+ps[3]);
  q = (pq[0]+pq[1]) + (pq[2]+pq[3]);
  const float mean = s * (1.f/1024.f);
  const float var  = q * (1.f/1024.f) - mean*mean;
  const float rstd = rsqrtf(var + 1e-5f);
  const float4 gg = ((const float4*)gam)[tid];
  const float4 bb = ((const float4*)bet)[tid];
  const float o0 = (v.x-mean)*rstd*gg.x + bb.x;
  const float o1 = (v.y-mean)*rstd*gg.y + bb.y;
  const float o2 = (v.z-mean)*rstd*gg.z + bb.z;
  const float o3 = (v.w-mean)*rstd*gg.w + bb.w;
  if (OUT_F32){
    float4 r; r.x=o0; r.y=o1; r.z=o2; r.w=o3;
    ((float4*)out)[row*256 + tid] = r;
  } else {
    u32x2 r; r.x = pk2(o0,o1); r.y = pk2(o2,o3);
    ((u32x2*)out)[row*256 + tid] = r;
  }
}

// ---------------- GEMM 256x256 8-wave, 4-phase pipelined (fat shapes) --------
// Supertiled block order (8-M-block panels = 4MB A-panel per XCD L2).
// Plain C++ LDS reads -> compiler emits dependency-exact lgkmcnt (no manual
// drain; manual lgkmcnt(0)+sched_barrier only needed for inline-asm reads).
// Epilogue: acc -> LDS bf16 tile -> fully coalesced 512B-row stores.
template<int DO_GELU>
__global__ __launch_bounds__(512,2) void gemm256_k(
    const u16* __restrict__ A, const u16* __restrict__ W,
    const float* __restrict__ bias, u16* __restrict__ Cout,
    int M, int N, int K)
{
  __shared__ char lds[131072];
  const int tid = threadIdx.x;
  const int lane = tid & 63, wid = tid >> 6;
  const int wr = wid >> 2, wc = wid & 3;
  const int g = lane >> 4, c16 = lane & 15;

  const u32 nwg = gridDim.x * gridDim.y;
  u32 flat = blockIdx.x + gridDim.x * blockIdx.y;
  {
    const u32 q = nwg >> 3, r = nwg & 7;
    const u32 xcd = flat & 7, idx = flat >> 3;
    flat = (xcd < r ? xcd*(q+1) : r*(q+1) + (xcd-r)*q) + idx;
  }
  const u32 span = 8u * gridDim.y;
  const int panel = (int)(flat / span);
  const int rem   = (int)(flat % span);
  const int m0 = (panel*8 + (rem & 7)) * 256;
  const int n0 = (rem >> 3) * 256;

  f32x4 acc[8][4];
  #pragma unroll
  for (int m = 0; m < 8; m++)
    #pragma unroll
    for (int n = 0; n < 4; n++) acc[m][n] = (f32x4){0.f,0.f,0.f,0.f};

  const int srow = tid >> 3, schk = tid & 7;
  const int scg = schk ^ (srow & 7);
  const u16* aS = A + (size_t)(m0 + srow)*K + scg*8;
  const u16* wS = W + (size_t)(n0 + srow)*K + scg*8;

  auto SG = [&](const u16* base, int regionOff, int sb, int half, int i, int kk){
    gload16(base + (size_t)(half*128 + i*64)*K + kk,
            lds + sb*65536 + regionOff + half*16384 + i*8192 + tid*16);
  };
  short8 af[4][2], bf[4][2];
  auto LDA4 = [&](char* bufA, int mbase){
    #pragma unroll
    for (int i = 0; i < 4; i++){
      const int r = (mbase + i)*16 + c16;
      const int rx = r & 7;
      af[i][0] = *(const short8*)(bufA + r*128 + ((g ^ rx) << 4));
      af[i][1] = *(const short8*)(bufA + r*128 + (((4 + g) ^ rx) << 4));
    }
  };
  auto LDB2 = [&](char* bufB, int nbase){
    #pragma unroll
    for (int i = 0; i < 2; i++){
      const int r = (wc & 1)*64 + (nbase + i)*16 + c16;
      const int rx = r & 7;
      bf[nbase+i][0] = *(const short8*)(bufB + r*128 + ((g ^ rx) << 4));
      bf[nbase+i][1] = *(const short8*)(bufB + r*128 + (((4 + g) ^ rx) << 4));
    }
  };

  const int NT = K >> 6;
  SG(wS, 32768, 0, 0, 0, 0); SG(wS, 32768, 0, 0, 1, 0);
  SG(wS, 32768, 0, 1, 0, 0); SG(wS, 32768, 0, 1, 1, 0);
  SG(aS, 0,     0, 0, 0, 0); SG(aS, 0,     0, 0, 1, 0);
  SG(aS, 0,     0, 1, 0, 0); SG(aS, 0,     0, 1, 1, 0);
  asm volatile("s_waitcnt vmcnt(1)" ::: "memory");
  HBAR;

  for (int t = 0; t < NT; ++t){
    const int b = t & 1, sb = b ^ 1;
    const int skk = (t+1) << 6;
    const bool st = (t+1 < NT);
    char* bufA = lds + b*65536 + wr*16384;
    char* bufB = lds + b*65536 + 32768 + (wc >> 1)*16384;

    LDA4(bufA, 0); LDB2(bufB, 0);
    if (st){ SG(wS, 32768, sb, 0, 0, skk); SG(wS, 32768, sb, 0, 1, skk); }
    HBAR;
    __builtin_amdgcn_s_setprio(1);
    #pragma unroll
    for (int ks = 0; ks < 2; ks++)
      #pragma unroll
      for (int i = 0; i < 4; i++)
        #pragma unroll
        for (int j = 0; j < 2; j++)
          acc[i][j] = __builtin_amdgcn_mfma_f32_16x16x32_bf16(af[i][ks], bf[j][ks], acc[i][j], 0,0,0);
    __builtin_amdgcn_s_setprio(0);
    LDB2(bufB, 2);
    if (st){ SG(wS, 32768, sb, 1, 0, skk); SG(wS, 32768, sb, 1, 1, skk); }
    HBAR;
    __builtin_amdgcn_s_setprio(1);
    #pragma unroll
    for (int ks = 0; ks < 2; ks++)
      #pragma unroll
      for (int i = 0; i < 4; i++)
        #pragma unroll
        for (int j = 2; j < 4; j++)
          acc[i][j] = __builtin_amdgcn_mfma_f32_16x16x32_bf16(af[i][ks], bf[j][ks], acc[i][j], 0,0,0);
    __builtin_amdgcn_s_setprio(0);
    if (st) asm volatile("s_waitcnt vmcnt(4)" ::: "memory");
    else    asm volatile("s_waitcnt vmcnt(0)" ::: "memory");
    HBAR;
    LDA4(bufA, 4);
    if (st){ SG(aS, 0, sb, 0, 0, skk); SG(aS, 0, sb, 0, 1, skk); }
    __builtin_amdgcn_s_setprio(1);
    #pragma unroll
    for (int ks = 0; ks < 2; ks++)
      #pragma unroll
      for (int i = 0; i < 4; i++)
        #pragma unroll
        for (int j = 0; j < 2; j++)
          acc[4+i][j] = __builtin_amdgcn_mfma_f32_16x16x32_bf16(af[i][ks], bf[j][ks], acc[4+i][j], 0,0,0);
    __builtin_amdgcn_s_setprio(0);
    if (st){ SG(aS, 0, sb, 1, 0, skk); SG(aS, 0, sb, 1, 1, skk); }
    HBAR;
    __builtin_amdgcn_s_setprio(1);
    #pragma unroll
    for (int ks = 0; ks < 2; ks++)
      #pragma unroll
      for (int i = 0; i < 4; i++)
        #pragma unroll
        for (int j = 2; j < 4; j++)
          acc[4+i][j] = __builtin_amdgcn_mfma_f32_16x16x32_bf16(af[i][ks], bf[j][ks], acc[4+i][j], 0,0,0);
    __builtin_amdgcn_s_setprio(0);
    if (st) asm volatile("s_waitcnt vmcnt(1)" ::: "memory");
    HBAR;
  }
  // after final HBAR all waves are done with K-loop LDS reads; LDS is free.

  // ---- epilogue phase 1: acc (+bias,+GELU) -> LDS bf16 tile [256][512B] ----
  #pragma unroll
  for (int n = 0; n < 4; n++){
    const int col = wc*64 + n*16 + c16;
    const float bv = bias[n0 + col];
    #pragma unroll
    for (int m = 0; m < 8; m++){
      const int rbase = wr*128 + m*16 + g*4;
      #pragma unroll
      for (int r = 0; r < 4; r++){
        float v = acc[m][n][r] + bv;
        if (DO_GELU) v = 0.5f*v*(1.f + erff(v*0.70710678118654752f));
        const int row = rbase + r;
        const int byte = col*2;
        const int ch = byte >> 4, rem2 = byte & 15;
        *(u16*)(lds + row*512 + ((ch ^ (row & 31)) << 4) + rem2) = f2b(v);
      }
    }
  }
  HBAR;
  // ---- epilogue phase 2: coalesced sweep, 512B per row, dwordx4 stores ----
  #pragma unroll
  for (int it = 0; it < 16; ++it){
    const int idx = it*512 + tid;
    const int row = idx >> 5;
    const int ch  = idx & 31;
    const u32x4 v = *(const u32x4*)(lds + row*512 + ((ch ^ (row & 31)) << 4));
    *(u32x4*)(Cout + (size_t)(m0 + row)*N + n0 + ch*8) = v;
  }
}

// ---------------- GEMM 128x128 8-wave, 2-phase pipelined (narrow-N) ----------
template<int DO_GELU, int DO_RES, int OUT_F32>
__global__ __launch_bounds__(512,2) void gemm128p_k(
    const u16* __restrict__ A, const u16* __restrict__ W,
    const float* __restrict__ bias, const float* __restrict__ res,
    void* __restrict__ Cout, int M, int N, int K)
{
  __shared__ char lds[65536];
  const int tid = threadIdx.x;
  const int lane = tid & 63, wid = tid >> 6;
  const int wr = wid >> 2, wc = wid & 3;
  const int g = lane >> 4, c16 = lane & 15;

  const u32 nwg = gridDim.x * gridDim.y;
  u32 flat = blockIdx.x + gridDim.x * blockIdx.y;
  {
    const u32 q = nwg >> 3, r = nwg & 7;
    const u32 xcd = flat & 7, idx = flat >> 3;
    flat = (xcd < r ? xcd*(q+1) : r*(q+1) + (xcd-r)*q) + idx;
  }
  const int n0 = (int)(flat % gridDim.x) * 128;   // N fastest
  const int m0 = (int)(flat / gridDim.x) * 128;

  f32x4 acc[4][2];
  #pragma unroll
  for (int m = 0; m < 4; m++)
    #pragma unroll
    for (int n = 0; n < 2; n++) acc[m][n] = (f32x4){0.f,0.f,0.f,0.f};

  const int srow = tid >> 3, schk = tid & 7;
  const int scg = schk ^ (srow & 7);
  const u16* aS = A + (size_t)(m0 + srow)*K + scg*8;
  const u16* wS = W + (size_t)(n0 + srow)*K + scg*8;

  auto SG = [&](const u16* base, int regionOff, int sb, int i, int kk){
    gload16(base + (size_t)(i*64)*K + kk,
            lds + sb*32768 + regionOff + i*8192 + tid*16);
  };
  short8 af[2][2], af2[2][2], bf[2][2];
  auto LDA = [&](short8 (*dst)[2], char* bufA, int mbase){
    #pragma unroll
    for (int i = 0; i < 2; i++){
      const int r = wr*64 + (mbase + i)*16 + c16;
      const int rx = r & 7;
      dst[i][0] = *(const short8*)(bufA + r*128 + ((g ^ rx) << 4));
      dst[i][1] = *(const short8*)(bufA + r*128 + (((4 + g) ^ rx) << 4));
    }
  };
  auto LDB = [&](char* bufB){
    #pragma unroll
    for (int i = 0; i < 2; i++){
      const int r = wc*32 + i*16 + c16;
      const int rx = r & 7;
      bf[i][0] = *(const short8*)(bufB + r*128 + ((g ^ rx) << 4));
      bf[i][1] = *(const short8*)(bufB + r*128 + (((4 + g) ^ rx) << 4));
    }
  };

  const int NT = K >> 6;
  SG(wS, 16384, 0, 0, 0); SG(wS, 16384, 0, 1, 0);
  SG(aS, 0,     0, 0, 0); SG(aS, 0,     0, 1, 0);

  for (int t = 0; t < NT; ++t){
    const int b = t & 1, sb = b ^ 1;
    const int skk = (t+1) << 6;
    const bool st = (t+1 < NT);
    char* bufA = lds + b*32768;
    char* bufB = lds + b*32768 + 16384;

    if (st){ SG(wS, 16384, sb, 0, skk); SG(wS, 16384, sb, 1, skk); }
    if (st) asm volatile("s_waitcnt vmcnt(2)" ::: "memory");
    else    asm volatile("s_waitcnt vmcnt(0)" ::: "memory");
    HBAR;
    LDA(af, bufA, 0); LDB(bufB);
    if (st){ SG(aS, 0, sb, 0, skk); SG(aS, 0, sb, 1, skk); }
    __builtin_amdgcn_s_setprio(1);
    #pragma unroll
    for (int ks = 0; ks < 2; ks++)
      #pragma unroll
      for (int i = 0; i < 2; i++)
        #pragma unroll
        for (int j = 0; j < 2; j++)
          acc[i][j] = __builtin_amdgcn_mfma_f32_16x16x32_bf16(af[i][ks], bf[j][ks], acc[i][j], 0,0,0);
    __builtin_amdgcn_s_setprio(0);
    LDA(af2, bufA, 2);
    __builtin_amdgcn_s_setprio(1);
    #pragma unroll
    for (int ks = 0; ks < 2; ks++)
      #pragma unroll
      for (int i = 0; i < 2; i++)
        #pragma unroll
        for (int j = 0; j < 2; j++)
          acc[2+i][j] = __builtin_amdgcn_mfma_f32_16x16x32_bf16(af2[i][ks], bf[j][ks], acc[2+i][j], 0,0,0);
    __builtin_amdgcn_s_setprio(0);
    HBAR;
  }

  #pragma unroll
  for (int n = 0; n < 2; n++){
    const int col = n0 + wc*32 + n*16 + c16;
    const float bv = bias[col];
    #pragma unroll
    for (int m = 0; m < 4; m++){
      const int rbase = m0 + wr*64 + m*16 + g*4;
      #pragma unroll
      for (int r = 0; r < 4; r++){
        float v = acc[m][n][r] + bv;
        if (DO_GELU) v = 0.5f*v*(1.f + erff(v*0.70710678118654752f));
        if (DO_RES)  v += res[(size_t)(rbase + r)*N + col];
        if (OUT_F32) ((float*)Cout)[(size_t)(rbase + r)*N + col] = v;
        else         ((u16*)Cout)[(size_t)(rbase + r)*N + col] = f2b(v);
      }
    }
  }
}

// ---------------- Flash attention, HD=64, KVBLK=64 ---------------------------
// (inline-asm tr-reads keep their lgkmcnt(0)+sched_barrier fences: rule #18)
template<int CAUSAL>
__global__ __launch_bounds__(256,4) void attn_k(
    const u16* __restrict__ Qb, int qB, int qS,
    const u16* __restrict__ Kb, int kB, int kS,
    const u16* __restrict__ Vb, int vB, int vS,
    u16* __restrict__ Ob, int oB, int oS, float scale)
{
  __shared__ char smem[32768];
  const int tid = threadIdx.x;
  const int lane = tid & 63, w = tid >> 6;
  const int g = lane >> 4, c16 = lane & 15;
  const int qt = blockIdx.x, bh = blockIdx.y;
  const int b = bh >> 4, h = bh & 15;
  const u16* Q  = Qb + b*qB + h*64;
  const u16* Kp = Kb + b*kB + h*64;
  const u16* Vp = Vb + b*vB + h*64;
  u16*       Op = Ob + b*oB + h*64;

  const int qrow = qt*64 + w*16 + c16;
  const short8 bq0 = *(const short8*)(Q + qrow*qS + g*8);
  const short8 bq1 = *(const short8*)(Q + qrow*qS + 32 + g*8);

  f32x4 o[4];
  #pragma unroll
  for (int d = 0; d < 4; d++) o[d] = (f32x4){0.f,0.f,0.f,0.f};
  float mrun = -__builtin_inff(), lrun = 0.f;

  const int srow = tid >> 3, schk = tid & 7;
  const u16* kSrc = Kp + (size_t)srow*kS + (schk ^ (srow & 7))*8;
  const u16* vSrc = Vp + (size_t)srow*vS + schk*8;
  const u32 vtr0 = lds_addr(smem) + 16384 + (8*g + (c16 >> 2))*128 + (c16 & 3)*8;

  auto STAGE = [&](int p, int j0){
    char* kb = smem + p*8192 + w*1024;
    char* vb = smem + 16384 + p*8192 + w*1024;
    gload16(kSrc + (size_t)j0*kS, kb);
    gload16(kSrc + (size_t)(j0+32)*kS, kb + 4096);
    gload16(vSrc + (size_t)j0*vS, vb);
    gload16(vSrc + (size_t)(j0+32)*vS, vb + 4096);
  };
  auto COMPUTE = [&](int p, int j0){
    char* Ks = smem + p*8192;
    f32x4 st[4];
    #pragma unroll
    for (int t = 0; t < 4; t++){
      const int row = t*16 + c16;
      const int rx = row & 7;
      const short8 ka0 = *(const short8*)(Ks + row*128 + ((g ^ rx) << 4));
      const short8 ka1 = *(const short8*)(Ks + row*128 + (((4 + g) ^ rx) << 4));
      f32x4 z = (f32x4){0.f,0.f,0.f,0.f};
      z = __builtin_amdgcn_mfma_f32_16x16x32_bf16(ka0, bq0, z, 0,0,0);
      z = __builtin_amdgcn_mfma_f32_16x16x32_bf16(ka1, bq1, z, 0,0,0);
      st[t] = z;
    }
    float mloc = -__builtin_inff();
    #pragma unroll
    for (int t = 0; t < 4; t++)
      #pragma unroll
      for (int r = 0; r < 4; r++){
        float sv = st[t][r]*scale;
        if (CAUSAL){ if (j0 + t*16 + g*4 + r > qrow) sv = -__builtin_inff(); }
        st[t][r] = sv;
        mloc = fmaxf(mloc, sv);
      }
    mloc = fmaxf(mloc, __shfl_xor(mloc, 16));
    mloc = fmaxf(mloc, __shfl_xor(mloc, 32));
    const float mnew = fmaxf(mrun, mloc);
    const float corr = __expf(mrun - mnew);
    float psum = 0.f;
    u32 pk[4][2];
    #pragma unroll
    for (int t = 0; t < 4; t++){
      const float p0 = __expf(st[t][0]-mnew), p1 = __expf(st[t][1]-mnew);
      const float p2 = __expf(st[t][2]-mnew), p3 = __expf(st[t][3]-mnew);
      psum += (p0+p1) + (p2+p3);
      pk[t][0] = pk2(p0,p1); pk[t][1] = pk2(p2,p3);
    }
    psum += __shfl_xor(psum, 16);
    psum += __shfl_xor(psum, 32);
    lrun = lrun*corr + psum;
    mrun = mnew;
    #pragma unroll
    for (int d = 0; d < 4; d++){
      o[d][0]*=corr; o[d][1]*=corr; o[d][2]*=corr; o[d][3]*=corr;
    }
    const int sl0 = c16 | (((g << 1)     & 3) << 4);
    const int sl1 = c16 | ((((g << 1)+1) & 3) << 4);
    const bool hi = g >= 2;
    union { short8 s; u32 u[4]; } pb, pb2;
    {
      const u32 a00 = (u32)__shfl((int)pk[0][0], sl0), a01 = (u32)__shfl((int)pk[0][1], sl0);
      const u32 a02 = (u32)__shfl((int)pk[0][0], sl1), a03 = (u32)__shfl((int)pk[0][1], sl1);
      const u32 a10 = (u32)__shfl((int)pk[1][0], sl0), a11 = (u32)__shfl((int)pk[1][1], sl0);
      const u32 a12 = (u32)__shfl((int)pk[1][0], sl1), a13 = (u32)__shfl((int)pk[1][1], sl1);
      pb.u[0] = hi ? a10 : a00;
      pb.u[1] = hi ? a11 : a01;
      pb.u[2] = hi ? a12 : a02;
      pb.u[3] = hi ? a13 : a03;
    }
    {
      const u32 a00 = (u32)__shfl((int)pk[2][0], sl0), a01 = (u32)__shfl((int)pk[2][1], sl0);
      const u32 a02 = (u32)__shfl((int)pk[2][0], sl1), a03 = (u32)__shfl((int)pk[2][1], sl1);
      const u32 a10 = (u32)__shfl((int)pk[3][0], sl0), a11 = (u32)__shfl((int)pk[3][1], sl0);
      const u32 a12 = (u32)__shfl((int)pk[3][0], sl1), a13 = (u32)__shfl((int)pk[3][1], sl1);
      pb2.u[0] = hi ? a10 : a00;
      pb2.u[1] = hi ? a11 : a01;
      pb2.u[2] = hi ? a12 : a02;
      pb2.u[3] = hi ? a13 : a03;
    }

    const u32 vtr = vtr0 + p*8192;
    u32x2 t00,t01,t10,t11,t20,t21,t30,t31;
    asm volatile("ds_read_b64_tr_b16 %0, %1 offset:0"   : "=v"(t00) : "v"(vtr));
    asm volatile("ds_read_b64_tr_b16 %0, %1 offset:512" : "=v"(t01) : "v"(vtr));
    asm volatile("ds_read_b64_tr_b16 %0, %1 offset:32"  : "=v"(t10) : "v"(vtr));
    asm volatile("ds_read_b64_tr_b16 %0, %1 offset:544" : "=v"(t11) : "v"(vtr));
    asm volatile("ds_read_b64_tr_b16 %0, %1 offset:64"  : "=v"(t20) : "v"(vtr));
    asm volatile("ds_read_b64_tr_b16 %0, %1 offset:576" : "=v"(t21) : "v"(vtr));
    asm volatile("ds_read_b64_tr_b16 %0, %1 offset:96"  : "=v"(t30) : "v"(vtr));
    asm volatile("ds_read_b64_tr_b16 %0, %1 offset:608" : "=v"(t31) : "v"(vtr));
    asm volatile("s_waitcnt lgkmcnt(0)" ::: "memory");
    __builtin_amdgcn_sched_barrier(0);
    {
      union { short8 s; u32x2 d[2]; } v0u, v1u, v2u, v3u;
      v0u.d[0]=t00; v0u.d[1]=t01;
      v1u.d[0]=t10; v1u.d[1]=t11;
      v2u.d[0]=t20; v2u.d[1]=t21;
      v3u.d[0]=t30; v3u.d[1]=t31;
      o[0] = __builtin_amdgcn_mfma_f32_16x16x32_bf16(v0u.s, pb.s, o[0], 0,0,0);
      o[1] = __builtin_amdgcn_mfma_f32_16x16x32_bf16(v1u.s, pb.s, o[1], 0,0,0);
      o[2] = __builtin_amdgcn_mfma_f32_16x16x32_bf16(v2u.s, pb.s, o[2], 0,0,0);
      o[3] = __builtin_amdgcn_mfma_f32_16x16x32_bf16(v3u.s, pb.s, o[3], 0,0,0);
    }
    asm volatile("ds_read_b64_tr_b16 %0, %1 offset:4096" : "=v"(t00) : "v"(vtr));
    asm volatile("ds_read_b64_tr_b16 %0, %1 offset:4608" : "=v"(t01) : "v"(vtr));
    asm volatile("ds_read_b64_tr_b16 %0, %1 offset:4128" : "=v"(t10) : "v"(vtr));
    asm volatile("ds_read_b64_tr_b16 %0, %1 offset:4640" : "=v"(t11) : "v"(vtr));
    asm volatile("ds_read_b64_tr_b16 %0, %1 offset:4160" : "=v"(t20) : "v"(vtr));
    asm volatile("ds_read_b64_tr_b16 %0, %1 offset:4672" : "=v"(t21) : "v"(vtr));
    asm volatile("ds_read_b64_tr_b16 %0, %1 offset:4192" : "=v"(t30) : "v"(vtr));
    asm volatile("ds_read_b64_tr_b16 %0, %1 offset:4704" : "=v"(t31) : "v"(vtr));
    asm volatile("s_waitcnt lgkmcnt(0)" ::: "memory");
    __builtin_amdgcn_sched_barrier(0);
    {
      union { short8 s; u32x2 d[2]; } v0u, v1u, v2u, v3u;
      v0u.d[0]=t00; v0u.d[1]=t01;
      v1u.d[0]=t10; v1u.d[1]=t11;
      v2u.d[0]=t20; v2u.d[1]=t21;
      v3u.d[0]=t30; v3u.d[1]=t31;
      o[0] = __builtin_amdgcn_mfma_f32_16x16x32_bf16(v0u.s, pb2.s, o[0], 0,0,0);
      o[1] = __builtin_amdgcn_mfma_f32_16x16x32_bf16(v1u.s, pb2.s, o[1], 0,0,0);
      o[2] = __builtin_amdgcn_mfma_f32_16x16x32_bf16(v2u.s, pb2.s, o[2], 0,0,0);
      o[3] = __builtin_amdgcn_mfma_f32_16x16x32_bf16(v3u.s, pb2.s, o[3], 0,0,0);
    }
  };

  const int nCh = CAUSAL ? (qt + 1) : 8;
  STAGE(0, 0);
  for (int jc = 0; jc < nCh - 1; ++jc){
    STAGE((jc+1) & 1, (jc+1)*64);
    asm volatile("s_waitcnt vmcnt(4)" ::: "memory");
    HBAR; SB0;
    COMPUTE(jc & 1, jc*64);
    SB0; HBAR;
  }
  asm volatile("s_waitcnt vmcnt(0)" ::: "memory");
  HBAR; SB0;
  COMPUTE((nCh-1) & 1, (nCh-1)*64);
  SB0; HBAR;

  const float inv = 1.f / lrun;
  char* Olds = smem;
  #pragma unroll
  for (int dd = 0; dd < 4; dd++){
    u32x2 val;
    val.x = pk2(o[dd][0]*inv, o[dd][1]*inv);
    val.y = pk2(o[dd][2]*inv, o[dd][3]*inv);
    const int row = w*16 + c16;
    const int off = 32*dd + 8*g;
    const int chunk = off >> 4, rem = off & 15;
    *(u32x2*)(Olds + row*128 + ((chunk ^ (row & 7)) << 4) + rem) = val;
  }
  __syncthreads();
  const int orow = tid >> 2, oc = tid & 3;
  #pragma unroll
  for (int i = 0; i < 2; i++){
    const int ch = oc*2 + i;
    const u32x4 vv = *(const u32x4*)(Olds + orow*128 + ((ch ^ (orow & 7)) << 4));
    *(u32x4*)(Op + (qt*64 + orow)*oS + ch*8) = vv;
  }
}

// ----------------------------------------------------------------------------
static inline int cvt_grid(int n8){ int g = (n8 + 255) / 256; return g > 2048 ? 2048 : g; }

extern "C" void kernel_launch(void* const* d_in, const int* in_sizes, int n_in,
                              void* d_out, int out_size, void* d_ws, size_t ws_size,
                              hipStream_t stream)
{
  (void)in_sizes; (void)n_in; (void)out_size; (void)ws_size;
  const float* src      = (const float*)d_in[0];
  const float* tgt      = (const float*)d_in[1];
  const float* e_qkv_w  = (const float*)d_in[2];
  const float* e_qkv_b  = (const float*)d_in[3];
  const float* e_out_w  = (const float*)d_in[4];
  const float* e_out_b  = (const float*)d_in[5];
  const float* e_ln1_g  = (const float*)d_in[6];
  const float* e_ln1_b  = (const float*)d_in[7];
  const float* e_fc1_w  = (const float*)d_in[8];
  const float* e_fc1_b  = (const float*)d_in[9];
  const float* e_fc2_w  = (const float*)d_in[10];
  const float* e_fc2_b  = (const float*)d_in[11];
  const float* e_ln2_g  = (const float*)d_in[12];
  const float* e_ln2_b  = (const float*)d_in[13];
  const float* e_nrm_g  = (const float*)d_in[14];
  const float* e_nrm_b  = (const float*)d_in[15];
  const float* dc_qkv_w = (const float*)d_in[16];
  const float* dc_qkv_b = (const float*)d_in[17];
  const float* dc_sout_w= (const float*)d_in[18];
  const float* dc_sout_b= (const float*)d_in[19];
  const float* dc_ln1_g = (const float*)d_in[20];
  const float* dc_ln1_b = (const float*)d_in[21];
  const float* dc_q_w   = (const float*)d_in[22];
  const float* dc_q_b   = (const float*)d_in[23];
  const float* dc_kv_w  = (const float*)d_in[24];
  const float* dc_kv_b  = (const float*)d_in[25];
  const float* dc_cout_w= (const float*)d_in[26];
  const float* dc_cout_b= (const float*)d_in[27];
  const float* dc_ln2_g = (const float*)d_in[28];
  const float* dc_ln2_b = (const float*)d_in[29];
  const float* dc_fc1_w = (const float*)d_in[30];
  const float* dc_fc1_b = (const float*)d_in[31];
  const float* dc_fc2_w = (const float*)d_in[32];
  const float* dc_fc2_b = (const float*)d_in[33];
  const float* dc_ln3_g = (const float*)d_in[34];
  const float* dc_ln3_b = (const float*)d_in[35];
  const float* dc_nrm_g = (const float*)d_in[36];
  const float* dc_nrm_b = (const float*)d_in[37];

  char* ws = (char*)d_ws;
  u16*  ln_out = (u16*)(ws);                    //  8 MB
  u16*  attn_o = (u16*)(ws + (8u<<20));         //  8 MB
  u16*  membuf = (u16*)(ws + (16u<<20));        //  8 MB
  float* xres  = (float*)(ws + (24u<<20));      // 16 MB
  u16*  region = (u16*)(ws + (40u<<20));        // 32 MB
  u16*  qkv   = region;
  u16*  hbuf  = region;
  u16*  qbuf  = region;
  u16*  wb    = (u16*)(ws + (72u<<20));         // 352 MB bf16 weights
  u16*  kvall = (u16*)(ws + (424ull<<20));      // 96 MB batched decoder KV

  const dim3 blk(256);
  const dim3 blk512(512);
  const int M = 4096;

  // ---------- upfront: convert ALL weights to bf16 (11 launches) ----------
  size_t woff = 0;
  auto CV = [&](const float* wsrc, size_t n)->u16* {
    u16* p = wb + woff; woff += n;
    cvt_k<<<cvt_grid((int)(n >> 3)), blk, 0, stream>>>(wsrc, p, (int)(n >> 3));
    return p;
  };
  u16* Weqkv = CV(e_qkv_w,  6ull*3072*1024);
  u16* Weout = CV(e_out_w,  6ull*1024*1024);
  u16* Wefc1 = CV(e_fc1_w,  6ull*4096*1024);
  u16* Wefc2 = CV(e_fc2_w,  6ull*4096*1024);
  u16* Wdqkv = CV(dc_qkv_w, 6ull*3072*1024);
  u16* Wdsout= CV(dc_sout_w,6ull*1024*1024);
  u16* Wdq   = CV(dc_q_w,   6ull*1024*1024);
  u16* Wdkv  = CV(dc_kv_w,  6ull*2048*1024);
  u16* Wdcout= CV(dc_cout_w,6ull*1024*1024);
  u16* Wdfc1 = CV(dc_fc1_w, 6ull*4096*1024);
  u16* Wdfc2 = CV(dc_fc2_w, 6ull*4096*1024);

  // ----------------- encoder -----------------
  for (int i = 0; i < 6; i++){
    const float* xin = i ? xres : src;
    ln_k<0><<<4096, blk, 0, stream>>>(xin, e_ln1_g + i*1024, e_ln1_b + i*1024, ln_out);
    gemm256_k<0><<<dim3(16, 12), blk512, 0, stream>>>(ln_out,
        Weqkv + (size_t)i*3145728, e_qkv_b + i*3072, qkv, M, 3072, 1024);
    attn_k<0><<<dim3(8,128), blk, 0, stream>>>(qkv, 3072, 24576,
        qkv+1024, 3072, 24576, qkv+2048, 3072, 24576, attn_o, 1024, 8192, 0.125f);
    gemm128p_k<0,1,1><<<dim3(8, 32), blk512, 0, stream>>>(attn_o,
        Weout + (size_t)i*1048576, e_out_b + i*1024, xin, xres, M, 1024, 1024);
    ln_k<0><<<4096, blk, 0, stream>>>(xres, e_ln2_g + i*1024, e_ln2_b + i*1024, ln_out);
    gemm256_k<1><<<dim3(16, 16), blk512, 0, stream>>>(ln_out,
        Wefc1 + (size_t)i*4194304, e_fc1_b + i*4096, hbuf, M, 4096, 1024);
    gemm128p_k<0,1,1><<<dim3(8, 32), blk512, 0, stream>>>(hbuf,
        Wefc2 + (size_t)i*4194304, e_fc2_b + i*1024, xres, xres, M, 1024, 4096);
  }
  ln_k<0><<<4096, blk, 0, stream>>>(xres, e_nrm_g, e_nrm_b, membuf);

  // batched decoder cross-attn KV: one GEMM over all 6 layers (N = 6*2048)
  gemm256_k<0><<<dim3(16, 48), blk512, 0, stream>>>(membuf,
      Wdkv, dc_kv_b, kvall, M, 12288, 1024);

  // ----------------- decoder -----------------
  for (int i = 0; i < 6; i++){
    const float* yin = i ? xres : tgt;
    ln_k<0><<<4096, blk, 0, stream>>>(yin, dc_ln1_g + i*1024, dc_ln1_b + i*1024, ln_out);
    gemm256_k<0><<<dim3(16, 12), blk512, 0, stream>>>(ln_out,
        Wdqkv + (size_t)i*3145728, dc_qkv_b + i*3072, qkv, M, 3072, 1024);
    attn_k<1><<<dim3(8,128), blk, 0, stream>>>(qkv, 3072, 24576,
        qkv+1024, 3072, 24576, qkv+2048, 3072, 24576, attn_o, 1024, 8192, 0.125f);
    gemm128p_k<0,1,1><<<dim3(8, 32), blk512, 0, stream>>>(attn_o,
        Wdsout + (size_t)i*1048576, dc_sout_b + i*1024, yin, xres, M, 1024, 1024);
    ln_k<0><<<4096, blk, 0, stream>>>(xres, dc_ln2_g + i*1024, dc_ln2_b + i*1024, ln_out);
    gemm128p_k<0,0,0><<<dim3(8, 32), blk512, 0, stream>>>(ln_out,
        Wdq + (size_t)i*1048576, dc_q_b + i*1024, nullptr, qbuf, M, 1024, 1024);
    attn_k<0><<<dim3(8,128), blk, 0, stream>>>(qbuf, 1024, 8192,
        kvall + i*2048, 12288, 98304, kvall + i*2048 + 1024, 12288, 98304,
        attn_o, 1024, 8192, 0.125f);
    gemm128p_k<0,1,1><<<dim3(8, 32), blk512, 0, stream>>>(attn_o,
        Wdcout + (size_t)i*1048576, dc_cout_b + i*1024, xres, xres, M, 1024, 1024);
    ln_k<0><<<4096, blk, 0, stream>>>(xres, dc_ln3_g + i*1024, dc_ln3_b + i*1024, ln_out);
    gemm256_k<1><<<dim3(16, 16), blk512, 0, stream>>>(ln_out,
        Wdfc1 + (size_t)i*4194304, dc_fc1_b + i*4096, hbuf, M, 4096, 1024);
    gemm128p_k<0,1,1><<<dim3(8, 32), blk512, 0, stream>>>(hbuf,
        Wdfc2 + (size_t)i*4194304, dc_fc2_b + i*1024, xres, xres, M, 1024, 4096);
  }
  ln_k<1><<<4096, blk, 0, stream>>>(xres, dc_nrm_g, dc_nrm_b, d_out);
}

// Round 19
// 3086.472 us; speedup vs baseline: 1.0303x; 1.0063x over previous
//
#include <hip/hip_runtime.h>

typedef __attribute__((ext_vector_type(4))) float f32x4;
typedef __attribute__((ext_vector_type(8))) short short8;
typedef unsigned int u32;
typedef unsigned short u16;
typedef __attribute__((ext_vector_type(2))) u32 u32x2;
typedef __attribute__((ext_vector_type(4))) u32 u32x4;

#define DEV __device__ __forceinline__
#define SB0  __builtin_amdgcn_sched_barrier(0)
#define HBAR asm volatile("s_barrier" ::: "memory")

DEV u16 f2b(float f){
  u32 u = __builtin_bit_cast(u32, f);
  u32 r = u + 0x7fffu + ((u >> 16) & 1u);
  return (u16)(r >> 16);
}
DEV u32 pk2(float a, float b){ return (u32)f2b(a) | ((u32)f2b(b) << 16); }

DEV void gload16(const void* g, void* l){
  __builtin_amdgcn_global_load_lds((const __attribute__((address_space(1))) void*)g,
                                   (__attribute__((address_space(3))) void*)l, 16, 0, 0);
}
DEV u32 lds_addr(void* p){
  return (u32)(unsigned long long)(__attribute__((address_space(3))) char*)p;
}

// ---------------- fp32 -> bf16 conversion (one launch per weight) ------------
__global__ __launch_bounds__(256) void cvt_k(const float* __restrict__ in,
                                             u16* __restrict__ out, int n8)
{
  int i = blockIdx.x*256 + threadIdx.x;
  const int stride = gridDim.x*256;
  for (; i < n8; i += stride){
    const float4 a = ((const float4*)in)[2*i];
    const float4 b = ((const float4*)in)[2*i+1];
    u32x4 r;
    r.x = pk2(a.x,a.y); r.y = pk2(a.z,a.w);
    r.z = pk2(b.x,b.y); r.w = pk2(b.z,b.w);
    ((u32x4*)out)[i] = r;
  }
}

// ---------------- LayerNorm --------------------------------------------------
template<int OUT_F32>
__global__ __launch_bounds__(256) void ln_k(const float* __restrict__ x,
    const float* __restrict__ gam, const float* __restrict__ bet,
    void* __restrict__ out)
{
  const int row = blockIdx.x, tid = threadIdx.x;
  const float4 v = ((const float4*)(x + row*1024))[tid];
  float s = (v.x + v.y) + (v.z + v.w);
  float q = (v.x*v.x + v.y*v.y) + (v.z*v.z + v.w*v.w);
  #pragma unroll
  for (int m = 1; m < 64; m <<= 1){ s += __shfl_xor(s, m); q += __shfl_xor(q, m); }
  __shared__ float ps[4], pq[4];
  if ((tid & 63) == 0){ ps[tid>>6] = s; pq[tid>>6] = q; }
  __syncthreads();
  s = (ps[0]+ps[1]) + (ps[2]+ps[3]);
  q = (pq[0]+pq[1]) + (pq[2]+pq[3]);
  const float mean = s * (1.f/1024.f);
  const float var  = q * (1.f/1024.f) - mean*mean;
  const float rstd = rsqrtf(var + 1e-5f);
  const float4 gg = ((const float4*)gam)[tid];
  const float4 bb = ((const float4*)bet)[tid];
  const float o0 = (v.x-mean)*rstd*gg.x + bb.x;
  const float o1 = (v.y-mean)*rstd*gg.y + bb.y;
  const float o2 = (v.z-mean)*rstd*gg.z + bb.z;
  const float o3 = (v.w-mean)*rstd*gg.w + bb.w;
  if (OUT_F32){
    float4 r; r.x=o0; r.y=o1; r.z=o2; r.w=o3;
    ((float4*)out)[row*256 + tid] = r;
  } else {
    u32x2 r; r.x = pk2(o0,o1); r.y = pk2(o2,o3);
    ((u32x2*)out)[row*256 + tid] = r;
  }
}

// ---------------- GEMM 256x256 8-wave, 4-phase pipelined (fat shapes) --------
// Supertiled block order (8-M-block panels = 4MB A-panel per XCD L2).
// A staged BY ROUND (r0 both halves, then r1 both): boundary wait relaxes to
// vmcnt(2) (one extra load in flight over each K-tile boundary); mid vmcnt(4)
// drains exactly the r1 pair ph2 needs.
// Epilogue: acc -> LDS bf16 tile -> fully coalesced 512B-row stores.
template<int DO_GELU>
__global__ __launch_bounds__(512,2) void gemm256_k(
    const u16* __restrict__ A, const u16* __restrict__ W,
    const float* __restrict__ bias, u16* __restrict__ Cout,
    int M, int N, int K)
{
  __shared__ char lds[131072];
  const int tid = threadIdx.x;
  const int lane = tid & 63, wid = tid >> 6;
  const int wr = wid >> 2, wc = wid & 3;
  const int g = lane >> 4, c16 = lane & 15;

  const u32 nwg = gridDim.x * gridDim.y;
  u32 flat = blockIdx.x + gridDim.x * blockIdx.y;
  {
    const u32 q = nwg >> 3, r = nwg & 7;
    const u32 xcd = flat & 7, idx = flat >> 3;
    flat = (xcd < r ? xcd*(q+1) : r*(q+1) + (xcd-r)*q) + idx;
  }
  const u32 span = 8u * gridDim.y;
  const int panel = (int)(flat / span);
  const int rem   = (int)(flat % span);
  const int m0 = (panel*8 + (rem & 7)) * 256;
  const int n0 = (rem >> 3) * 256;

  f32x4 acc[8][4];
  #pragma unroll
  for (int m = 0; m < 8; m++)
    #pragma unroll
    for (int n = 0; n < 4; n++) acc[m][n] = (f32x4){0.f,0.f,0.f,0.f};

  const int srow = tid >> 3, schk = tid & 7;
  const int scg = schk ^ (srow & 7);
  const u16* aS = A + (size_t)(m0 + srow)*K + scg*8;
  const u16* wS = W + (size_t)(n0 + srow)*K + scg*8;

  auto SG = [&](const u16* base, int regionOff, int sb, int half, int i, int kk){
    gload16(base + (size_t)(half*128 + i*64)*K + kk,
            lds + sb*65536 + regionOff + half*16384 + i*8192 + tid*16);
  };
  short8 af[4][2], bf[4][2];
  auto LDA4 = [&](char* bufA, int mbase){
    #pragma unroll
    for (int i = 0; i < 4; i++){
      const int r = (mbase + i)*16 + c16;
      const int rx = r & 7;
      af[i][0] = *(const short8*)(bufA + r*128 + ((g ^ rx) << 4));
      af[i][1] = *(const short8*)(bufA + r*128 + (((4 + g) ^ rx) << 4));
    }
  };
  auto LDB2 = [&](char* bufB, int nbase){
    #pragma unroll
    for (int i = 0; i < 2; i++){
      const int r = (wc & 1)*64 + (nbase + i)*16 + c16;
      const int rx = r & 7;
      bf[nbase+i][0] = *(const short8*)(bufB + r*128 + ((g ^ rx) << 4));
      bf[nbase+i][1] = *(const short8*)(bufB + r*128 + (((4 + g) ^ rx) << 4));
    }
  };

  const int NT = K >> 6;
  // prologue: B (both halves), then A by ROUND (r0 both halves, r1 both)
  SG(wS, 32768, 0, 0, 0, 0); SG(wS, 32768, 0, 0, 1, 0);
  SG(wS, 32768, 0, 1, 0, 0); SG(wS, 32768, 0, 1, 1, 0);
  SG(aS, 0,     0, 0, 0, 0); SG(aS, 0,     0, 1, 0, 0);
  SG(aS, 0,     0, 0, 1, 0); SG(aS, 0,     0, 1, 1, 0);
  asm volatile("s_waitcnt vmcnt(2)" ::: "memory");
  HBAR;

  for (int t = 0; t < NT; ++t){
    const int b = t & 1, sb = b ^ 1;
    const int skk = (t+1) << 6;
    const bool st = (t+1 < NT);
    char* bufA = lds + b*65536 + wr*16384;
    char* bufB = lds + b*65536 + 32768 + (wc >> 1)*16384;

    LDA4(bufA, 0); LDB2(bufB, 0);
    if (st){ SG(wS, 32768, sb, 0, 0, skk); SG(wS, 32768, sb, 0, 1, skk); }
    HBAR;
    __builtin_amdgcn_s_setprio(1);
    #pragma unroll
    for (int ks = 0; ks < 2; ks++)
      #pragma unroll
      for (int i = 0; i < 4; i++)
        #pragma unroll
        for (int j = 0; j < 2; j++)
          acc[i][j] = __builtin_amdgcn_mfma_f32_16x16x32_bf16(af[i][ks], bf[j][ks], acc[i][j], 0,0,0);
    __builtin_amdgcn_s_setprio(0);
    LDB2(bufB, 2);
    if (st){ SG(wS, 32768, sb, 1, 0, skk); SG(wS, 32768, sb, 1, 1, skk); }
    HBAR;
    __builtin_amdgcn_s_setprio(1);
    #pragma unroll
    for (int ks = 0; ks < 2; ks++)
      #pragma unroll
      for (int i = 0; i < 4; i++)
        #pragma unroll
        for (int j = 2; j < 4; j++)
          acc[i][j] = __builtin_amdgcn_mfma_f32_16x16x32_bf16(af[i][ks], bf[j][ks], acc[i][j], 0,0,0);
    __builtin_amdgcn_s_setprio(0);
    if (st) asm volatile("s_waitcnt vmcnt(4)" ::: "memory");
    else    asm volatile("s_waitcnt vmcnt(0)" ::: "memory");
    HBAR;
    LDA4(bufA, 4);
    if (st){ SG(aS, 0, sb, 0, 0, skk); SG(aS, 0, sb, 1, 0, skk); }  // A r0, both halves
    __builtin_amdgcn_s_setprio(1);
    #pragma unroll
    for (int ks = 0; ks < 2; ks++)
      #pragma unroll
      for (int i = 0; i < 4; i++)
        #pragma unroll
        for (int j = 0; j < 2; j++)
          acc[4+i][j] = __builtin_amdgcn_mfma_f32_16x16x32_bf16(af[i][ks], bf[j][ks], acc[4+i][j], 0,0,0);
    __builtin_amdgcn_s_setprio(0);
    if (st){ SG(aS, 0, sb, 0, 1, skk); SG(aS, 0, sb, 1, 1, skk); }  // A r1, both halves
    HBAR;
    __builtin_amdgcn_s_setprio(1);
    #pragma unroll
    for (int ks = 0; ks < 2; ks++)
      #pragma unroll
      for (int i = 0; i < 4; i++)
        #pragma unroll
        for (int j = 2; j < 4; j++)
          acc[4+i][j] = __builtin_amdgcn_mfma_f32_16x16x32_bf16(af[i][ks], bf[j][ks], acc[4+i][j], 0,0,0);
    __builtin_amdgcn_s_setprio(0);
    if (st) asm volatile("s_waitcnt vmcnt(2)" ::: "memory");
    HBAR;
  }
  // after final HBAR all waves are done with K-loop LDS reads; LDS is free.

  // ---- epilogue phase 1: acc (+bias,+GELU) -> LDS bf16 tile [256][512B] ----
  #pragma unroll
  for (int n = 0; n < 4; n++){
    const int col = wc*64 + n*16 + c16;
    const float bv = bias[n0 + col];
    #pragma unroll
    for (int m = 0; m < 8; m++){
      const int rbase = wr*128 + m*16 + g*4;
      #pragma unroll
      for (int r = 0; r < 4; r++){
        float v = acc[m][n][r] + bv;
        if (DO_GELU) v = 0.5f*v*(1.f + erff(v*0.70710678118654752f));
        const int row = rbase + r;
        const int byte = col*2;
        const int ch = byte >> 4, rem2 = byte & 15;
        *(u16*)(lds + row*512 + ((ch ^ (row & 31)) << 4) + rem2) = f2b(v);
      }
    }
  }
  HBAR;
  // ---- epilogue phase 2: coalesced sweep, 512B per row, dwordx4 stores ----
  #pragma unroll
  for (int it = 0; it < 16; ++it){
    const int idx = it*512 + tid;
    const int row = idx >> 5;
    const int ch  = idx & 31;
    const u32x4 v = *(const u32x4*)(lds + row*512 + ((ch ^ (row & 31)) << 4));
    *(u32x4*)(Cout + (size_t)(m0 + row)*N + n0 + ch*8) = v;
  }
}

// ---------------- GEMM 128x128 8-wave, 2-phase pipelined (narrow-N) ----------
template<int DO_GELU, int DO_RES, int OUT_F32>
__global__ __launch_bounds__(512,2) void gemm128p_k(
    const u16* __restrict__ A, const u16* __restrict__ W,
    const float* __restrict__ bias, const float* __restrict__ res,
    void* __restrict__ Cout, int M, int N, int K)
{
  __shared__ char lds[65536];
  const int tid = threadIdx.x;
  const int lane = tid & 63, wid = tid >> 6;
  const int wr = wid >> 2, wc = wid & 3;
  const int g = lane >> 4, c16 = lane & 15;

  const u32 nwg = gridDim.x * gridDim.y;
  u32 flat = blockIdx.x + gridDim.x * blockIdx.y;
  {
    const u32 q = nwg >> 3, r = nwg & 7;
    const u32 xcd = flat & 7, idx = flat >> 3;
    flat = (xcd < r ? xcd*(q+1) : r*(q+1) + (xcd-r)*q) + idx;
  }
  const int n0 = (int)(flat % gridDim.x) * 128;   // N fastest
  const int m0 = (int)(flat / gridDim.x) * 128;

  f32x4 acc[4][2];
  #pragma unroll
  for (int m = 0; m < 4; m++)
    #pragma unroll
    for (int n = 0; n < 2; n++) acc[m][n] = (f32x4){0.f,0.f,0.f,0.f};

  const int srow = tid >> 3, schk = tid & 7;
  const int scg = schk ^ (srow & 7);
  const u16* aS = A + (size_t)(m0 + srow)*K + scg*8;
  const u16* wS = W + (size_t)(n0 + srow)*K + scg*8;

  auto SG = [&](const u16* base, int regionOff, int sb, int i, int kk){
    gload16(base + (size_t)(i*64)*K + kk,
            lds + sb*32768 + regionOff + i*8192 + tid*16);
  };
  short8 af[2][2], af2[2][2], bf[2][2];
  auto LDA = [&](short8 (*dst)[2], char* bufA, int mbase){
    #pragma unroll
    for (int i = 0; i < 2; i++){
      const int r = wr*64 + (mbase + i)*16 + c16;
      const int rx = r & 7;
      dst[i][0] = *(const short8*)(bufA + r*128 + ((g ^ rx) << 4));
      dst[i][1] = *(const short8*)(bufA + r*128 + (((4 + g) ^ rx) << 4));
    }
  };
  auto LDB = [&](char* bufB){
    #pragma unroll
    for (int i = 0; i < 2; i++){
      const int r = wc*32 + i*16 + c16;
      const int rx = r & 7;
      bf[i][0] = *(const short8*)(bufB + r*128 + ((g ^ rx) << 4));
      bf[i][1] = *(const short8*)(bufB + r*128 + (((4 + g) ^ rx) << 4));
    }
  };

  const int NT = K >> 6;
  SG(wS, 16384, 0, 0, 0); SG(wS, 16384, 0, 1, 0);
  SG(aS, 0,     0, 0, 0); SG(aS, 0,     0, 1, 0);

  for (int t = 0; t < NT; ++t){
    const int b = t & 1, sb = b ^ 1;
    const int skk = (t+1) << 6;
    const bool st = (t+1 < NT);
    char* bufA = lds + b*32768;
    char* bufB = lds + b*32768 + 16384;

    if (st){ SG(wS, 16384, sb, 0, skk); SG(wS, 16384, sb, 1, skk); }
    if (st) asm volatile("s_waitcnt vmcnt(2)" ::: "memory");
    else    asm volatile("s_waitcnt vmcnt(0)" ::: "memory");
    HBAR;
    LDA(af, bufA, 0); LDB(bufB);
    if (st){ SG(aS, 0, sb, 0, skk); SG(aS, 0, sb, 1, skk); }
    __builtin_amdgcn_s_setprio(1);
    #pragma unroll
    for (int ks = 0; ks < 2; ks++)
      #pragma unroll
      for (int i = 0; i < 2; i++)
        #pragma unroll
        for (int j = 0; j < 2; j++)
          acc[i][j] = __builtin_amdgcn_mfma_f32_16x16x32_bf16(af[i][ks], bf[j][ks], acc[i][j], 0,0,0);
    __builtin_amdgcn_s_setprio(0);
    LDA(af2, bufA, 2);
    __builtin_amdgcn_s_setprio(1);
    #pragma unroll
    for (int ks = 0; ks < 2; ks++)
      #pragma unroll
      for (int i = 0; i < 2; i++)
        #pragma unroll
        for (int j = 0; j < 2; j++)
          acc[2+i][j] = __builtin_amdgcn_mfma_f32_16x16x32_bf16(af2[i][ks], bf[j][ks], acc[2+i][j], 0,0,0);
    __builtin_amdgcn_s_setprio(0);
    HBAR;
  }

  #pragma unroll
  for (int n = 0; n < 2; n++){
    const int col = n0 + wc*32 + n*16 + c16;
    const float bv = bias[col];
    #pragma unroll
    for (int m = 0; m < 4; m++){
      const int rbase = m0 + wr*64 + m*16 + g*4;
      #pragma unroll
      for (int r = 0; r < 4; r++){
        float v = acc[m][n][r] + bv;
        if (DO_GELU) v = 0.5f*v*(1.f + erff(v*0.70710678118654752f));
        if (DO_RES)  v += res[(size_t)(rbase + r)*N + col];
        if (OUT_F32) ((float*)Cout)[(size_t)(rbase + r)*N + col] = v;
        else         ((u16*)Cout)[(size_t)(rbase + r)*N + col] = f2b(v);
      }
    }
  }
}

// ---------------- Flash attention, HD=64, KVBLK=64 ---------------------------
template<int CAUSAL>
__global__ __launch_bounds__(256,4) void attn_k(
    const u16* __restrict__ Qb, int qB, int qS,
    const u16* __restrict__ Kb, int kB, int kS,
    const u16* __restrict__ Vb, int vB, int vS,
    u16* __restrict__ Ob, int oB, int oS, float scale)
{
  __shared__ char smem[32768];
  const int tid = threadIdx.x;
  const int lane = tid & 63, w = tid >> 6;
  const int g = lane >> 4, c16 = lane & 15;
  const int qt = blockIdx.x, bh = blockIdx.y;
  const int b = bh >> 4, h = bh & 15;
  const u16* Q  = Qb + b*qB + h*64;
  const u16* Kp = Kb + b*kB + h*64;
  const u16* Vp = Vb + b*vB + h*64;
  u16*       Op = Ob + b*oB + h*64;

  const int qrow = qt*64 + w*16 + c16;
  const short8 bq0 = *(const short8*)(Q + qrow*qS + g*8);
  const short8 bq1 = *(const short8*)(Q + qrow*qS + 32 + g*8);

  f32x4 o[4];
  #pragma unroll
  for (int d = 0; d < 4; d++) o[d] = (f32x4){0.f,0.f,0.f,0.f};
  float mrun = -__builtin_inff(), lrun = 0.f;

  const int srow = tid >> 3, schk = tid & 7;
  const u16* kSrc = Kp + (size_t)srow*kS + (schk ^ (srow & 7))*8;
  const u16* vSrc = Vp + (size_t)srow*vS + schk*8;
  const u32 vtr0 = lds_addr(smem) + 16384 + (8*g + (c16 >> 2))*128 + (c16 & 3)*8;

  auto STAGE = [&](int p, int j0){
    char* kb = smem + p*8192 + w*1024;
    char* vb = smem + 16384 + p*8192 + w*1024;
    gload16(kSrc + (size_t)j0*kS, kb);
    gload16(kSrc + (size_t)(j0+32)*kS, kb + 4096);
    gload16(vSrc + (size_t)j0*vS, vb);
    gload16(vSrc + (size_t)(j0+32)*vS, vb + 4096);
  };
  auto COMPUTE = [&](int p, int j0){
    char* Ks = smem + p*8192;
    f32x4 st[4];
    #pragma unroll
    for (int t = 0; t < 4; t++){
      const int row = t*16 + c16;
      const int rx = row & 7;
      const short8 ka0 = *(const short8*)(Ks + row*128 + ((g ^ rx) << 4));
      const short8 ka1 = *(const short8*)(Ks + row*128 + (((4 + g) ^ rx) << 4));
      f32x4 z = (f32x4){0.f,0.f,0.f,0.f};
      z = __builtin_amdgcn_mfma_f32_16x16x32_bf16(ka0, bq0, z, 0,0,0);
      z = __builtin_amdgcn_mfma_f32_16x16x32_bf16(ka1, bq1, z, 0,0,0);
      st[t] = z;
    }
    float mloc = -__builtin_inff();
    #pragma unroll
    for (int t = 0; t < 4; t++)
      #pragma unroll
      for (int r = 0; r < 4; r++){
        float sv = st[t][r]*scale;
        if (CAUSAL){ if (j0 + t*16 + g*4 + r > qrow) sv = -__builtin_inff(); }
        st[t][r] = sv;
        mloc = fmaxf(mloc, sv);
      }
    mloc = fmaxf(mloc, __shfl_xor(mloc, 16));
    mloc = fmaxf(mloc, __shfl_xor(mloc, 32));
    const float mnew = fmaxf(mrun, mloc);
    const float corr = __expf(mrun - mnew);
    float psum = 0.f;
    u32 pk[4][2];
    #pragma unroll
    for (int t = 0; t < 4; t++){
      const float p0 = __expf(st[t][0]-mnew), p1 = __expf(st[t][1]-mnew);
      const float p2 = __expf(st[t][2]-mnew), p3 = __expf(st[t][3]-mnew);
      psum += (p0+p1) + (p2+p3);
      pk[t][0] = pk2(p0,p1); pk[t][1] = pk2(p2,p3);
    }
    psum += __shfl_xor(psum, 16);
    psum += __shfl_xor(psum, 32);
    lrun = lrun*corr + psum;
    mrun = mnew;
    #pragma unroll
    for (int d = 0; d < 4; d++){
      o[d][0]*=corr; o[d][1]*=corr; o[d][2]*=corr; o[d][3]*=corr;
    }
    const int sl0 = c16 | (((g << 1)     & 3) << 4);
    const int sl1 = c16 | ((((g << 1)+1) & 3) << 4);
    const bool hi = g >= 2;
    union { short8 s; u32 u[4]; } pb, pb2;
    {
      const u32 a00 = (u32)__shfl((int)pk[0][0], sl0), a01 = (u32)__shfl((int)pk[0][1], sl0);
      const u32 a02 = (u32)__shfl((int)pk[0][0], sl1), a03 = (u32)__shfl((int)pk[0][1], sl1);
      const u32 a10 = (u32)__shfl((int)pk[1][0], sl0), a11 = (u32)__shfl((int)pk[1][1], sl0);
      const u32 a12 = (u32)__shfl((int)pk[1][0], sl1), a13 = (u32)__shfl((int)pk[1][1], sl1);
      pb.u[0] = hi ? a10 : a00;
      pb.u[1] = hi ? a11 : a01;
      pb.u[2] = hi ? a12 : a02;
      pb.u[3] = hi ? a13 : a03;
    }
    {
      const u32 a00 = (u32)__shfl((int)pk[2][0], sl0), a01 = (u32)__shfl((int)pk[2][1], sl0);
      const u32 a02 = (u32)__shfl((int)pk[2][0], sl1), a03 = (u32)__shfl((int)pk[2][1], sl1);
      const u32 a10 = (u32)__shfl((int)pk[3][0], sl0), a11 = (u32)__shfl((int)pk[3][1], sl0);
      const u32 a12 = (u32)__shfl((int)pk[3][0], sl1), a13 = (u32)__shfl((int)pk[3][1], sl1);
      pb2.u[0] = hi ? a10 : a00;
      pb2.u[1] = hi ? a11 : a01;
      pb2.u[2] = hi ? a12 : a02;
      pb2.u[3] = hi ? a13 : a03;
    }

    const u32 vtr = vtr0 + p*8192;
    u32x2 t00,t01,t10,t11,t20,t21,t30,t31;
    asm volatile("ds_read_b64_tr_b16 %0, %1 offset:0"   : "=v"(t00) : "v"(vtr));
    asm volatile("ds_read_b64_tr_b16 %0, %1 offset:512" : "=v"(t01) : "v"(vtr));
    asm volatile("ds_read_b64_tr_b16 %0, %1 offset:32"  : "=v"(t10) : "v"(vtr));
    asm volatile("ds_read_b64_tr_b16 %0, %1 offset:544" : "=v"(t11) : "v"(vtr));
    asm volatile("ds_read_b64_tr_b16 %0, %1 offset:64"  : "=v"(t20) : "v"(vtr));
    asm volatile("ds_read_b64_tr_b16 %0, %1 offset:576" : "=v"(t21) : "v"(vtr));
    asm volatile("ds_read_b64_tr_b16 %0, %1 offset:96"  : "=v"(t30) : "v"(vtr));
    asm volatile("ds_read_b64_tr_b16 %0, %1 offset:608" : "=v"(t31) : "v"(vtr));
    asm volatile("s_waitcnt lgkmcnt(0)" ::: "memory");
    __builtin_amdgcn_sched_barrier(0);
    {
      union { short8 s; u32x2 d[2]; } v0u, v1u, v2u, v3u;
      v0u.d[0]=t00; v0u.d[1]=t01;
      v1u.d[0]=t10; v1u.d[1]=t11;
      v2u.d[0]=t20; v2u.d[1]=t21;
      v3u.d[0]=t30; v3u.d[1]=t31;
      o[0] = __builtin_amdgcn_mfma_f32_16x16x32_bf16(v0u.s, pb.s, o[0], 0,0,0);
      o[1] = __builtin_amdgcn_mfma_f32_16x16x32_bf16(v1u.s, pb.s, o[1], 0,0,0);
      o[2] = __builtin_amdgcn_mfma_f32_16x16x32_bf16(v2u.s, pb.s, o[2], 0,0,0);
      o[3] = __builtin_amdgcn_mfma_f32_16x16x32_bf16(v3u.s, pb.s, o[3], 0,0,0);
    }
    asm volatile("ds_read_b64_tr_b16 %0, %1 offset:4096" : "=v"(t00) : "v"(vtr));
    asm volatile("ds_read_b64_tr_b16 %0, %1 offset:4608" : "=v"(t01) : "v"(vtr));
    asm volatile("ds_read_b64_tr_b16 %0, %1 offset:4128" : "=v"(t10) : "v"(vtr));
    asm volatile("ds_read_b64_tr_b16 %0, %1 offset:4640" : "=v"(t11) : "v"(vtr));
    asm volatile("ds_read_b64_tr_b16 %0, %1 offset:4160" : "=v"(t20) : "v"(vtr));
    asm volatile("ds_read_b64_tr_b16 %0, %1 offset:4672" : "=v"(t21) : "v"(vtr));
    asm volatile("ds_read_b64_tr_b16 %0, %1 offset:4192" : "=v"(t30) : "v"(vtr));
    asm volatile("ds_read_b64_tr_b16 %0, %1 offset:4704" : "=v"(t31) : "v"(vtr));
    asm volatile("s_waitcnt lgkmcnt(0)" ::: "memory");
    __builtin_amdgcn_sched_barrier(0);
    {
      union { short8 s; u32x2 d[2]; } v0u, v1u, v2u, v3u;
      v0u.d[0]=t00; v0u.d[1]=t01;
      v1u.d[0]=t10; v1u.d[1]=t11;
      v2u.d[0]=t20; v2u.d[1]=t21;
      v3u.d[0]=t30; v3u.d[1]=t31;
      o[0] = __builtin_amdgcn_mfma_f32_16x16x32_bf16(v0u.s, pb2.s, o[0], 0,0,0);
      o[1] = __builtin_amdgcn_mfma_f32_16x16x32_bf16(v1u.s, pb2.s, o[1], 0,0,0);
      o[2] = __builtin_amdgcn_mfma_f32_16x16x32_bf16(v2u.s, pb2.s, o[2], 0,0,0);
      o[3] = __builtin_amdgcn_mfma_f32_16x16x32_bf16(v3u.s, pb2.s, o[3], 0,0,0);
    }
  };

  const int nCh = CAUSAL ? (qt + 1) : 8;
  STAGE(0, 0);
  for (int jc = 0; jc < nCh - 1; ++jc){
    STAGE((jc+1) & 1, (jc+1)*64);
    asm volatile("s_waitcnt vmcnt(4)" ::: "memory");
    HBAR; SB0;
    COMPUTE(jc & 1, jc*64);
    SB0; HBAR;
  }
  asm volatile("s_waitcnt vmcnt(0)" ::: "memory");
  HBAR; SB0;
  COMPUTE((nCh-1) & 1, (nCh-1)*64);
  SB0; HBAR;

  const float inv = 1.f / lrun;
  char* Olds = smem;
  #pragma unroll
  for (int dd = 0; dd < 4; dd++){
    u32x2 val;
    val.x = pk2(o[dd][0]*inv, o[dd][1]*inv);
    val.y = pk2(o[dd][2]*inv, o[dd][3]*inv);
    const int row = w*16 + c16;
    const int off = 32*dd + 8*g;
    const int chunk = off >> 4, rem = off & 15;
    *(u32x2*)(Olds + row*128 + ((chunk ^ (row & 7)) << 4) + rem) = val;
  }
  __syncthreads();
  const int orow = tid >> 2, oc = tid & 3;
  #pragma unroll
  for (int i = 0; i < 2; i++){
    const int ch = oc*2 + i;
    const u32x4 vv = *(const u32x4*)(Olds + orow*128 + ((ch ^ (orow & 7)) << 4));
    *(u32x4*)(Op + (qt*64 + orow)*oS + ch*8) = vv;
  }
}

// ----------------------------------------------------------------------------
static inline int cvt_grid(int n8){ int g = (n8 + 255) / 256; return g > 2048 ? 2048 : g; }

extern "C" void kernel_launch(void* const* d_in, const int* in_sizes, int n_in,
                              void* d_out, int out_size, void* d_ws, size_t ws_size,
                              hipStream_t stream)
{
  (void)in_sizes; (void)n_in; (void)out_size; (void)ws_size;
  const float* src      = (const float*)d_in[0];
  const float* tgt      = (const float*)d_in[1];
  const float* e_qkv_w  = (const float*)d_in[2];
  const float* e_qkv_b  = (const float*)d_in[3];
  const float* e_out_w  = (const float*)d_in[4];
  const float* e_out_b  = (const float*)d_in[5];
  const float* e_ln1_g  = (const float*)d_in[6];
  const float* e_ln1_b  = (const float*)d_in[7];
  const float* e_fc1_w  = (const float*)d_in[8];
  const float* e_fc1_b  = (const float*)d_in[9];
  const float* e_fc2_w  = (const float*)d_in[10];
  const float* e_fc2_b  = (const float*)d_in[11];
  const float* e_ln2_g  = (const float*)d_in[12];
  const float* e_ln2_b  = (const float*)d_in[13];
  const float* e_nrm_g  = (const float*)d_in[14];
  const float* e_nrm_b  = (const float*)d_in[15];
  const float* dc_qkv_w = (const float*)d_in[16];
  const float* dc_qkv_b = (const float*)d_in[17];
  const float* dc_sout_w= (const float*)d_in[18];
  const float* dc_sout_b= (const float*)d_in[19];
  const float* dc_ln1_g = (const float*)d_in[20];
  const float* dc_ln1_b = (const float*)d_in[21];
  const float* dc_q_w   = (const float*)d_in[22];
  const float* dc_q_b   = (const float*)d_in[23];
  const float* dc_kv_w  = (const float*)d_in[24];
  const float* dc_kv_b  = (const float*)d_in[25];
  const float* dc_cout_w= (const float*)d_in[26];
  const float* dc_cout_b= (const float*)d_in[27];
  const float* dc_ln2_g = (const float*)d_in[28];
  const float* dc_ln2_b = (const float*)d_in[29];
  const float* dc_fc1_w = (const float*)d_in[30];
  const float* dc_fc1_b = (const float*)d_in[31];
  const float* dc_fc2_w = (const float*)d_in[32];
  const float* dc_fc2_b = (const float*)d_in[33];
  const float* dc_ln3_g = (const float*)d_in[34];
  const float* dc_ln3_b = (const float*)d_in[35];
  const float* dc_nrm_g = (const float*)d_in[36];
  const float* dc_nrm_b = (const float*)d_in[37];

  char* ws = (char*)d_ws;
  u16*  ln_out = (u16*)(ws);                    //  8 MB
  u16*  attn_o = (u16*)(ws + (8u<<20));         //  8 MB
  u16*  membuf = (u16*)(ws + (16u<<20));        //  8 MB
  float* xres  = (float*)(ws + (24u<<20));      // 16 MB
  u16*  region = (u16*)(ws + (40u<<20));        // 32 MB
  u16*  qkv   = region;
  u16*  hbuf  = region;
  u16*  qbuf  = region;
  u16*  wb    = (u16*)(ws + (72u<<20));         // 352 MB bf16 weights
  u16*  kvall = (u16*)(ws + (424ull<<20));      // 96 MB batched decoder KV

  const dim3 blk(256);
  const dim3 blk512(512);
  const int M = 4096;

  // ---------- upfront: convert ALL weights to bf16 (11 launches) ----------
  size_t woff = 0;
  auto CV = [&](const float* wsrc, size_t n)->u16* {
    u16* p = wb + woff; woff += n;
    cvt_k<<<cvt_grid((int)(n >> 3)), blk, 0, stream>>>(wsrc, p, (int)(n >> 3));
    return p;
  };
  u16* Weqkv = CV(e_qkv_w,  6ull*3072*1024);
  u16* Weout = CV(e_out_w,  6ull*1024*1024);
  u16* Wefc1 = CV(e_fc1_w,  6ull*4096*1024);
  u16* Wefc2 = CV(e_fc2_w,  6ull*4096*1024);
  u16* Wdqkv = CV(dc_qkv_w, 6ull*3072*1024);
  u16* Wdsout= CV(dc_sout_w,6ull*1024*1024);
  u16* Wdq   = CV(dc_q_w,   6ull*1024*1024);
  u16* Wdkv  = CV(dc_kv_w,  6ull*2048*1024);
  u16* Wdcout= CV(dc_cout_w,6ull*1024*1024);
  u16* Wdfc1 = CV(dc_fc1_w, 6ull*4096*1024);
  u16* Wdfc2 = CV(dc_fc2_w, 6ull*4096*1024);

  // ----------------- encoder -----------------
  for (int i = 0; i < 6; i++){
    const float* xin = i ? xres : src;
    ln_k<0><<<4096, blk, 0, stream>>>(xin, e_ln1_g + i*1024, e_ln1_b + i*1024, ln_out);
    gemm256_k<0><<<dim3(16, 12), blk512, 0, stream>>>(ln_out,
        Weqkv + (size_t)i*3145728, e_qkv_b + i*3072, qkv, M, 3072, 1024);
    attn_k<0><<<dim3(8,128), blk, 0, stream>>>(qkv, 3072, 24576,
        qkv+1024, 3072, 24576, qkv+2048, 3072, 24576, attn_o, 1024, 8192, 0.125f);
    gemm128p_k<0,1,1><<<dim3(8, 32), blk512, 0, stream>>>(attn_o,
        Weout + (size_t)i*1048576, e_out_b + i*1024, xin, xres, M, 1024, 1024);
    ln_k<0><<<4096, blk, 0, stream>>>(xres, e_ln2_g + i*1024, e_ln2_b + i*1024, ln_out);
    gemm256_k<1><<<dim3(16, 16), blk512, 0, stream>>>(ln_out,
        Wefc1 + (size_t)i*4194304, e_fc1_b + i*4096, hbuf, M, 4096, 1024);
    gemm128p_k<0,1,1><<<dim3(8, 32), blk512, 0, stream>>>(hbuf,
        Wefc2 + (size_t)i*4194304, e_fc2_b + i*1024, xres, xres, M, 1024, 4096);
  }
  ln_k<0><<<4096, blk, 0, stream>>>(xres, e_nrm_g, e_nrm_b, membuf);

  // batched decoder cross-attn KV: one GEMM over all 6 layers (N = 6*2048)
  gemm256_k<0><<<dim3(16, 48), blk512, 0, stream>>>(membuf,
      Wdkv, dc_kv_b, kvall, M, 12288, 1024);

  // ----------------- decoder -----------------
  for (int i = 0; i < 6; i++){
    const float* yin = i ? xres : tgt;
    ln_k<0><<<4096, blk, 0, stream>>>(yin, dc_ln1_g + i*1024, dc_ln1_b + i*1024, ln_out);
    gemm256_k<0><<<dim3(16, 12), blk512, 0, stream>>>(ln_out,
        Wdqkv + (size_t)i*3145728, dc_qkv_b + i*3072, qkv, M, 3072, 1024);
    attn_k<1><<<dim3(8,128), blk, 0, stream>>>(qkv, 3072, 24576,
        qkv+1024, 3072, 24576, qkv+2048, 3072, 24576, attn_o, 1024, 8192, 0.125f);
    gemm128p_k<0,1,1><<<dim3(8, 32), blk512, 0, stream>>>(attn_o,
        Wdsout + (size_t)i*1048576, dc_sout_b + i*1024, yin, xres, M, 1024, 1024);
    ln_k<0><<<4096, blk, 0, stream>>>(xres, dc_ln2_g + i*1024, dc_ln2_b + i*1024, ln_out);
    gemm128p_k<0,0,0><<<dim3(8, 32), blk512, 0, stream>>>(ln_out,
        Wdq + (size_t)i*1048576, dc_q_b + i*1024, nullptr, qbuf, M, 1024, 1024);
    attn_k<0><<<dim3(8,128), blk, 0, stream>>>(qbuf, 1024, 8192,
        kvall + i*2048, 12288, 98304, kvall + i*2048 + 1024, 12288, 98304,
        attn_o, 1024, 8192, 0.125f);
    gemm128p_k<0,1,1><<<dim3(8, 32), blk512, 0, stream>>>(attn_o,
        Wdcout + (size_t)i*1048576, dc_cout_b + i*1024, xres, xres, M, 1024, 1024);
    ln_k<0><<<4096, blk, 0, stream>>>(xres, dc_ln3_g + i*1024, dc_ln3_b + i*1024, ln_out);
    gemm256_k<1><<<dim3(16, 16), blk512, 0, stream>>>(ln_out,
        Wdfc1 + (size_t)i*4194304, dc_fc1_b + i*4096, hbuf, M, 4096, 1024);
    gemm128p_k<0,1,1><<<dim3(8, 32), blk512, 0, stream>>>(hbuf,
        Wdfc2 + (size_t)i*4194304, dc_fc2_b + i*1024, xres, xres, M, 1024, 4096);
  }
  ln_k<1><<<4096, blk, 0, stream>>>(xres, dc_nrm_g, dc_nrm_b, d_out);
}